// Round 8
// baseline (584.258 us; speedup 1.0000x reference)
//
#include <hip/hip_runtime.h>
#include <hip/hip_bf16.h>

#define NN 20000
#define EE 160000

typedef __attribute__((ext_vector_type(8))) short bf16x8;
typedef __attribute__((ext_vector_type(4))) float f32x4;

__device__ __forceinline__ unsigned short f2bf(float f) {
    unsigned int u = __float_as_uint(f);
    u += 0x7FFFu + ((u >> 16) & 1);   // RNE
    return (unsigned short)(u >> 16);
}
__device__ __forceinline__ float bf2f(short s) {
    return __uint_as_float(((unsigned int)(unsigned short)s) << 16);
}
__device__ __forceinline__ bf16x8 pack8(float4 a, float4 b) {
    bf16x8 r;
    r[0] = (short)f2bf(a.x); r[1] = (short)f2bf(a.y);
    r[2] = (short)f2bf(a.z); r[3] = (short)f2bf(a.w);
    r[4] = (short)f2bf(b.x); r[5] = (short)f2bf(b.y);
    r[6] = (short)f2bf(b.z); r[7] = (short)f2bf(b.w);
    return r;
}

#define SH_STRIDE 136
#define SW_STRIDE 56
// edge64 kernel strides (LDS = 33792 + 18432 + 1024 = 53248 B -> 3 blocks/CU)
#define SH64 132
#define SW64 72

// barrier that does NOT drain vmcnt (gathers stay in flight)
__device__ __forceinline__ void bar_lgkm() {
    asm volatile("s_waitcnt lgkmcnt(0)\n\ts_barrier" ::: "memory");
}

__device__ __forceinline__ void mfma_sweep_lds(f32x4 (&acc)[2][8], bf16x8 a0, bf16x8 a1,
                                               const short* sWb, int lm, int lq)
{
#pragma unroll
    for (int ct = 0; ct < 8; ++ct) {
        bf16x8 b = *(const bf16x8*)(sWb + (ct * 16 + lm) * SW_STRIDE + lq * 8);
        acc[0][ct] = __builtin_amdgcn_mfma_f32_16x16x32_bf16(a0, b, acc[0][ct], 0, 0, 0);
        acc[1][ct] = __builtin_amdgcn_mfma_f32_16x16x32_bf16(a1, b, acc[1][ct], 0, 0, 0);
    }
}

__device__ __forceinline__ void mfma_sweep64(f32x4 (&acc)[2][8], bf16x8 a0, bf16x8 a1,
                                             const short* sWb, int colOff, int lm)
{
#pragma unroll
    for (int ct = 0; ct < 8; ++ct) {
        bf16x8 b = *(const bf16x8*)(sWb + (ct * 16 + lm) * SW64 + colOff);
        acc[0][ct] = __builtin_amdgcn_mfma_f32_16x16x32_bf16(a0, b, acc[0][ct], 0, 0, 0);
        acc[1][ct] = __builtin_amdgcn_mfma_f32_16x16x32_bf16(a1, b, acc[1][ct], 0, 0, 0);
    }
}

// N-split sweep: one wave covers 4 col-tiles (ch selects which half of N=128)
__device__ __forceinline__ void mfma_sweepNS(f32x4 (&acc)[4], bf16x8 a,
                                             const short* sWb, int ch, int colOff, int lm)
{
#pragma unroll
    for (int i = 0; i < 4; ++i) {
        int ct = ch * 4 + i;
        bf16x8 b = *(const bf16x8*)(sWb + (ct * 16 + lm) * SW64 + colOff);
        acc[i] = __builtin_amdgcn_mfma_f32_16x16x32_bf16(a, b, acc[i], 0, 0, 0);
    }
}

// W-chunk pipeline (32-k chunks, enc_e): load regs early / ds_write later.
struct WStageE { bf16x8 v[2]; };
__device__ __forceinline__ void wloadE(WStageE& ws, const short* __restrict__ Wt,
                                       int Kpad, int k0, int tid)
{
    int r = tid >> 1, h = tid & 1;
    const short* src = Wt + (size_t)r * Kpad + k0 + h * 16;
    ws.v[0] = *(const bf16x8*)src;
    ws.v[1] = *(const bf16x8*)(src + 8);
}
__device__ __forceinline__ void wstoreE(const WStageE& ws, short* __restrict__ sW, int tid)
{
    int r = tid >> 1, h = tid & 1;
    short* dst = sW + r * SW_STRIDE + h * 16;
    *(bf16x8*)dst       = ws.v[0];
    *(bf16x8*)(dst + 8) = ws.v[1];
}

// 64-k W stage (NT=256): 128 rows x 64 k, 4 bf16x8/thread
struct WStage64 { bf16x8 v[4]; };
__device__ __forceinline__ void wload64(WStage64& ws, const short* __restrict__ Wt,
                                        int Kpad, int k0, int tid)
{
#pragma unroll
    for (int j = 0; j < 4; ++j) {
        int i = tid + j * 256;
        int r = i >> 3, h = i & 7;
        ws.v[j] = *(const bf16x8*)(Wt + (size_t)r * Kpad + k0 + h * 8);
    }
}
__device__ __forceinline__ void wstore64(const WStage64& ws, short* __restrict__ sW, int tid)
{
#pragma unroll
    for (int j = 0; j < 4; ++j) {
        int i = tid + j * 256;
        int r = i >> 3, h = i & 7;
        *(bf16x8*)(sW + r * SW64 + h * 8) = ws.v[j];
    }
}

__device__ __forceinline__ void zero_acc(f32x4 (&acc)[2][8]) {
#pragma unroll
    for (int i = 0; i < 2; ++i)
#pragma unroll
        for (int j = 0; j < 8; ++j) acc[i][j] = (f32x4)(0.f);
}

__device__ __forceinline__ void park(const f32x4 (&acc)[2][8], const float* __restrict__ bias,
                                     short* __restrict__ sH, int w32, int lm, int lq)
{
#pragma unroll
    for (int ct = 0; ct < 8; ++ct) {
        float bb = bias[ct * 16 + lm];
#pragma unroll
        for (int rt = 0; rt < 2; ++rt) {
            int rbase = w32 + rt * 16 + lq * 4;
#pragma unroll
            for (int reg = 0; reg < 4; ++reg) {
                float v = fmaxf(acc[rt][ct][reg] + bb, 0.f);
                sH[(rbase + reg) * SH_STRIDE + ct * 16 + lm] = (short)f2bf(v);
            }
        }
    }
}

// N-split park: 16 rows x 64 cols (this wave's half)
__device__ __forceinline__ void parkNS(const f32x4 (&acc)[4], const float* __restrict__ bias,
                                       short* __restrict__ sH, int g16, int ch, int lm, int lq)
{
#pragma unroll
    for (int i = 0; i < 4; ++i) {
        int ct = ch * 4 + i;
        float bb = bias[ct * 16 + lm];
#pragma unroll
        for (int reg = 0; reg < 4; ++reg) {
            float v = fmaxf(acc[i][reg] + bb, 0.f);
            sH[(g16 + lq * 4 + reg) * SH_STRIDE + ct * 16 + lm] = (short)f2bf(v);
        }
    }
}

__device__ __forceinline__ void park64(const f32x4 (&acc)[2][8], const float* __restrict__ bias,
                                       short* __restrict__ sH, int w32, int lm, int lq)
{
#pragma unroll
    for (int ct = 0; ct < 8; ++ct) {
        float bb = bias[ct * 16 + lm];
#pragma unroll
        for (int rt = 0; rt < 2; ++rt) {
            int rbase = w32 + rt * 16 + lq * 4;
#pragma unroll
            for (int reg = 0; reg < 4; ++reg) {
                float v = fmaxf(acc[rt][ct][reg] + bb, 0.f);
                sH[(rbase + reg) * SH64 + ct * 16 + lm] = (short)f2bf(v);
            }
        }
    }
}

// N-split 64-k fragment (node core): this lane's row, k [c*64, c*64+64).
struct FragNS {
    bf16x8 a0, a1;
    float4 f0, f1, f2, f3;
    int isF;
};
__device__ __forceinline__ void load_fragNS(FragNS& fr, int c,
    const short* __restrict__ nfb, const float* __restrict__ aggf, int r0m, int lq)
{
    fr.isF = 0;
    if (c >= 2) {
        const float* p = aggf + (size_t)r0m * 128 + (c - 2) * 64 + lq * 8;
        fr.f0 = *(const float4*)p;        fr.f1 = *(const float4*)(p + 4);
        fr.f2 = *(const float4*)(p + 32); fr.f3 = *(const float4*)(p + 36);
        fr.isF = 1;
    } else {
        const short* p = nfb + (size_t)r0m * 128 + c * 64 + lq * 8;
        fr.a0 = *(const bf16x8*)p;
        fr.a1 = *(const bf16x8*)(p + 32);
    }
}

// 64-k fragment (edge): [0]=r0 h0, [1]=r1 h0, [2]=r0 h1, [3]=r1 h1
struct Frag64 { bf16x8 a[4]; };

__device__ __forceinline__ void load_frag64(Frag64& fr, int c,
    const short* __restrict__ nfb, const short* __restrict__ efHi,
    int iS0, int iS1, int iR0, int iR1, size_t eO0, size_t eO1, int lq)
{
    int kb = (c & 1) * 64 + lq * 8;
    int seg = c >> 1;
    const short *base0, *base1;
    if (seg == 0)      { base0 = nfb + (size_t)iS0 * 128; base1 = nfb + (size_t)iS1 * 128; }
    else if (seg == 1) { base0 = nfb + (size_t)iR0 * 128; base1 = nfb + (size_t)iR1 * 128; }
    else               { base0 = efHi + eO0;              base1 = efHi + eO1; }
    fr.a[0] = *(const bf16x8*)(base0 + kb);
    fr.a[1] = *(const bf16x8*)(base1 + kb);
    fr.a[2] = *(const bf16x8*)(base0 + kb + 32);
    fr.a[3] = *(const bf16x8*)(base1 + kb + 32);
}

// ---------------------------------------------------------------------------
// Edge MLP kernel — UNCHANGED round-6 body (proven; latency floor ~71us).
// ef master is a single bf16 array. RESID=1: ef += new_ef (bf16 RMW).
// ---------------------------------------------------------------------------
template<int RESID>
__global__ __launch_bounds__(256) void gnn_edge64(
    const short* __restrict__ Wt0,
    const short* __restrict__ Wt1, const short* __restrict__ Wt2,
    const float* __restrict__ b0, const float* __restrict__ b1, const float* __restrict__ b2,
    const float* __restrict__ g, const float* __restrict__ be,
    const short* __restrict__ nfb,
    short* __restrict__ efHi,
    const int* __restrict__ eList,
    const int* __restrict__ senders, const int* __restrict__ receivers,
    float* __restrict__ aggOut)
{
    __shared__ short sH[128 * SH64];
    __shared__ short sW[128 * SW64];
    __shared__ int sRcv[128], sSnd[128];
    const int tid = threadIdx.x;
    const int lane = tid & 63;
    const int w = tid >> 6;
    const int lm = lane & 15;
    const int lq = lane >> 4;
    const int w32 = w * 32;
    const int m0 = blockIdx.x * 128;

    if (tid < 128) {
        int slot = m0 + tid;                       // grid exact: slot < E
        int e = eList ? eList[slot] : slot;
        sRcv[tid] = receivers[e];
        sSnd[tid] = senders[e];
    }
    bar_lgkm();

    f32x4 acc[2][8];
    zero_acc(acc);

    const int s0 = w32 + 2 * lm, s1 = s0 + 1;
    const int iS0 = sSnd[s0], iS1 = sSnd[s1];
    const int iR0 = sRcv[s0], iR1 = sRcv[s1];
    const size_t eO0 = (size_t)(m0 + s0) * 128;
    const size_t eO1 = (size_t)(m0 + s1) * 128;

    // -------- layer 0: K=384 in 6 chunks of 64 --------
    {
        WStage64 ws, wsn;
        Frag64 cur, nxt;
        wload64(ws, Wt0, 384, 0, tid);
        load_frag64(cur, 0, nfb, efHi, iS0, iS1, iR0, iR1, eO0, eO1, lq);
#pragma unroll
        for (int c = 0; c < 6; ++c) {
            if (c + 1 < 6) {
                wload64(wsn, Wt0, 384, (c + 1) * 64, tid);
                load_frag64(nxt, c + 1, nfb, efHi, iS0, iS1, iR0, iR1, eO0, eO1, lq);
            }
            bar_lgkm();
            wstore64(ws, sW, tid);
            bar_lgkm();
            mfma_sweep64(acc, cur.a[0], cur.a[1], sW, lq * 8, lm);
            mfma_sweep64(acc, cur.a[2], cur.a[3], sW, 32 + lq * 8, lm);
            ws = wsn; cur = nxt;
        }
    }
    bar_lgkm();
    park64(acc, b0, sH, w32, lm, lq);

    // -------- layer 1: 2 chunks of 64 --------
    zero_acc(acc);
    {
        WStage64 ws, wsn;
        wload64(ws, Wt1, 128, 0, tid);
#pragma unroll
        for (int c = 0; c < 2; ++c) {
            if (c == 0) wload64(wsn, Wt1, 128, 64, tid);
            bf16x8 a0h0 = *(const bf16x8*)&sH[(w32 + lm) * SH64 + c * 64 + lq * 8];
            bf16x8 a1h0 = *(const bf16x8*)&sH[(w32 + 16 + lm) * SH64 + c * 64 + lq * 8];
            bf16x8 a0h1 = *(const bf16x8*)&sH[(w32 + lm) * SH64 + c * 64 + 32 + lq * 8];
            bf16x8 a1h1 = *(const bf16x8*)&sH[(w32 + 16 + lm) * SH64 + c * 64 + 32 + lq * 8];
            bar_lgkm();
            wstore64(ws, sW, tid);
            bar_lgkm();
            mfma_sweep64(acc, a0h0, a1h0, sW, lq * 8, lm);
            mfma_sweep64(acc, a0h1, a1h1, sW, 32 + lq * 8, lm);
            ws = wsn;
        }
    }
    bar_lgkm();
    park64(acc, b1, sH, w32, lm, lq);

    // -------- layer 2: 2 chunks of 64 --------
    zero_acc(acc);
    {
        WStage64 ws, wsn;
        wload64(ws, Wt2, 128, 0, tid);
#pragma unroll
        for (int c = 0; c < 2; ++c) {
            if (c == 0) wload64(wsn, Wt2, 128, 64, tid);
            bf16x8 a0h0 = *(const bf16x8*)&sH[(w32 + lm) * SH64 + c * 64 + lq * 8];
            bf16x8 a1h0 = *(const bf16x8*)&sH[(w32 + 16 + lm) * SH64 + c * 64 + lq * 8];
            bf16x8 a0h1 = *(const bf16x8*)&sH[(w32 + lm) * SH64 + c * 64 + 32 + lq * 8];
            bf16x8 a1h1 = *(const bf16x8*)&sH[(w32 + 16 + lm) * SH64 + c * 64 + 32 + lq * 8];
            bar_lgkm();
            wstore64(ws, sW, tid);
            bar_lgkm();
            mfma_sweep64(acc, a0h0, a1h0, sW, lq * 8, lm);
            mfma_sweep64(acc, a0h1, a1h1, sW, 32 + lq * 8, lm);
            ws = wsn;
        }
    }

    // -------- epilogue: LN + (RESID ? bf16 ef RMW) + merged-run atomics
    float g_[8], be_[8], b2_[8];
#pragma unroll
    for (int ct = 0; ct < 8; ++ct) {
        g_[ct] = g[ct * 16 + lm]; be_[ct] = be[ct * 16 + lm]; b2_[ct] = b2[ct * 16 + lm];
    }
    float run[8];
    int curRcv = -1;
#pragma unroll
    for (int j = 0; j < 8; ++j) {
        int rt = j & 1, reg = j >> 1;
        int rloc = w32 + lq * 8 + j;
        float v[8];
        float s = 0.f;
#pragma unroll
        for (int ct = 0; ct < 8; ++ct) { v[ct] = acc[rt][ct][reg] + b2_[ct]; s += v[ct]; }
        s += __shfl_xor(s, 1); s += __shfl_xor(s, 2);
        s += __shfl_xor(s, 4); s += __shfl_xor(s, 8);
        float mu = s * (1.f / 128.f);
        float q = 0.f;
#pragma unroll
        for (int ct = 0; ct < 8; ++ct) { v[ct] -= mu; q += v[ct] * v[ct]; }
        q += __shfl_xor(q, 1); q += __shfl_xor(q, 2);
        q += __shfl_xor(q, 4); q += __shfl_xor(q, 8);
        float rs = rsqrtf(q * (1.f / 128.f) + 1e-5f);
        int rcv = sRcv[rloc];
        float o[8];
#pragma unroll
        for (int ct = 0; ct < 8; ++ct) {
            o[ct] = v[ct] * rs * g_[ct] + be_[ct];
            if (RESID) {
                size_t gi = (size_t)(m0 + rloc) * 128 + ct * 16 + lm;
                float x = bf2f(efHi[gi]) + o[ct];
                efHi[gi] = (short)f2bf(x);
            }
        }
        if (rcv != curRcv) {
            if (curRcv >= 0) {
#pragma unroll
                for (int ct = 0; ct < 8; ++ct)
                    atomicAdd(aggOut + (size_t)curRcv * 128 + ct * 16 + lm, run[ct]);
            }
            curRcv = rcv;
#pragma unroll
            for (int ct = 0; ct < 8; ++ct) run[ct] = o[ct];
        } else {
#pragma unroll
            for (int ct = 0; ct < 8; ++ct) run[ct] += o[ct];
        }
    }
    if (curRcv >= 0) {
#pragma unroll
        for (int ct = 0; ct < 8; ++ct)
            atomicAdd(aggOut + (size_t)curRcv * 128 + ct * 16 + lm, run[ct]);
    }
}

// ---------------------------------------------------------------------------
// N-split body (device fn, pointer-based LDS). MODE 0: enc_n. MODE 2: node
// (resid nf/nfbf write + agg zero). MODE 4: node s=2 fused with decoder —
// parks post-resid LN output (bf16, identical bits to what nfbf held) to LDS
// and runs dec L0/L1/tail in-kernel; writes nothing but decOut.
// LDS layout: sH 8704 B | sW 18432 B | sX 256 B | sY 256 B = 27648 B.
// ---------------------------------------------------------------------------
template<int MODE>
__device__ __forceinline__ void ns_body(char* smem, int bid,
    const short* __restrict__ Wt0, const short* __restrict__ Wt1, const short* __restrict__ Wt2,
    const float* __restrict__ b0, const float* __restrict__ b1, const float* __restrict__ b2,
    const float* __restrict__ g, const float* __restrict__ be,
    const float* __restrict__ A0f, int K0,
    const short* __restrict__ nfb, const float* __restrict__ aggf,
    float* __restrict__ outF, short* __restrict__ outB,
    float* __restrict__ aggOut, float* __restrict__ decOut,
    const short* __restrict__ Wd0, const short* __restrict__ Wd1,
    const float* __restrict__ dW2f,
    const float* __restrict__ db0, const float* __restrict__ db1,
    const float* __restrict__ db2,
    int M, int resid)
{
    short* sH = (short*)smem;                      // 32 * SH_STRIDE
    short* sW = (short*)(smem + 8704);             // 128 * SW64
    float* sX = (float*)(smem + 8704 + 18432);     // 64
    float* sY = sX + 64;                           // 64
    const int tid = threadIdx.x;
    const int lane = tid & 63;
    const int w = tid >> 6;
    const int gidx = w >> 1;
    const int ch = w & 1;
    const int lm = lane & 15;
    const int lq = lane >> 4;
    const int g16 = gidx * 16;
    const int m0 = bid * 32;
    const int r0m = min(m0 + g16 + lm, M - 1);

    f32x4 acc[4];
#pragma unroll
    for (int i = 0; i < 4; ++i) acc[i] = (f32x4)(0.f);

    // -------- layer 0 --------
    if (MODE == 0) {
#pragma unroll
        for (int i = 0; i < 4; ++i) {
            int flat = tid + i * 256;
            int r = flat >> 5, k = flat & 31;
            int row = m0 + r;
            float v = (k < K0 && row < M) ? A0f[(size_t)row * K0 + k] : 0.f;
            sH[r * SH_STRIDE + k] = (short)f2bf(v);
        }
        {
            const short* src = Wt0 + (size_t)(tid >> 1) * 32 + (tid & 1) * 16;
            bf16x8 w0 = *(const bf16x8*)src;
            bf16x8 w1 = *(const bf16x8*)(src + 8);
            bar_lgkm();
            short* dst = sW + (tid >> 1) * SW64 + (tid & 1) * 16;
            *(bf16x8*)dst       = w0;
            *(bf16x8*)(dst + 8) = w1;
            bar_lgkm();
        }
        bf16x8 a0 = *(const bf16x8*)&sH[(g16 + lm) * SH_STRIDE + lq * 8];
        mfma_sweepNS(acc, a0, sW, ch, lq * 8, lm);
    } else {
        // node core: K=256 in 4 chunks of 64 (nfbf bf16, then agg fp32)
        WStage64 ws, wsn;
        FragNS cur, nxt;
        wload64(ws, Wt0, 256, 0, tid);
        load_fragNS(cur, 0, nfb, aggf, r0m, lq);
#pragma unroll
        for (int c = 0; c < 4; ++c) {
            if (c + 1 < 4) {
                wload64(wsn, Wt0, 256, (c + 1) * 64, tid);
                load_fragNS(nxt, c + 1, nfb, aggf, r0m, lq);
            }
            bar_lgkm();
            wstore64(ws, sW, tid);
            bar_lgkm();
            bf16x8 u0, u1;
            if (cur.isF) { u0 = pack8(cur.f0, cur.f1); u1 = pack8(cur.f2, cur.f3); }
            else         { u0 = cur.a0;                u1 = cur.a1; }
            mfma_sweepNS(acc, u0, sW, ch, lq * 8, lm);
            mfma_sweepNS(acc, u1, sW, ch, 32 + lq * 8, lm);
            ws = wsn; cur = nxt;
        }
    }
    bar_lgkm();
    parkNS(acc, b0, sH, g16, ch, lm, lq);
    bar_lgkm();

    // node MODE 2: zero this block's agg rows (all reads consumed above)
    if (MODE == 2 && aggOut) {
#pragma unroll
        for (int i = 0; i < 4; ++i) {
            int idx = tid + i * 256;
            int r = idx >> 5, c4 = idx & 31;
            int row = m0 + r;
            if (row < M)
                *(float4*)(aggOut + (size_t)row * 128 + c4 * 4) = make_float4(0.f, 0.f, 0.f, 0.f);
        }
    }

    // -------- layer 1: K=128, 2 chunks of 64 --------
#pragma unroll
    for (int i = 0; i < 4; ++i) acc[i] = (f32x4)(0.f);
    {
        WStage64 ws, wsn;
        wload64(ws, Wt1, 128, 0, tid);
#pragma unroll
        for (int c = 0; c < 2; ++c) {
            if (c == 0) wload64(wsn, Wt1, 128, 64, tid);
            bf16x8 a0 = *(const bf16x8*)&sH[(g16 + lm) * SH_STRIDE + c * 64 + lq * 8];
            bf16x8 a1 = *(const bf16x8*)&sH[(g16 + lm) * SH_STRIDE + c * 64 + 32 + lq * 8];
            bar_lgkm();
            wstore64(ws, sW, tid);
            bar_lgkm();
            mfma_sweepNS(acc, a0, sW, ch, lq * 8, lm);
            mfma_sweepNS(acc, a1, sW, ch, 32 + lq * 8, lm);
            ws = wsn;
        }
    }
    bar_lgkm();
    parkNS(acc, b1, sH, g16, ch, lm, lq);
    bar_lgkm();

    // -------- layer 2: K=128, 2 chunks of 64 --------
#pragma unroll
    for (int i = 0; i < 4; ++i) acc[i] = (f32x4)(0.f);
    {
        WStage64 ws, wsn;
        wload64(ws, Wt2, 128, 0, tid);
#pragma unroll
        for (int c = 0; c < 2; ++c) {
            if (c == 0) wload64(wsn, Wt2, 128, 64, tid);
            bf16x8 a0 = *(const bf16x8*)&sH[(g16 + lm) * SH_STRIDE + c * 64 + lq * 8];
            bf16x8 a1 = *(const bf16x8*)&sH[(g16 + lm) * SH_STRIDE + c * 64 + 32 + lq * 8];
            bar_lgkm();
            wstore64(ws, sW, tid);
            bar_lgkm();
            mfma_sweepNS(acc, a0, sW, ch, lq * 8, lm);
            mfma_sweepNS(acc, a1, sW, ch, 32 + lq * 8, lm);
            ws = wsn;
        }
    }

    // -------- epilogue: LN with cross-wave partial exchange --------
    float g_[4], be_[4], b2_[4];
#pragma unroll
    for (int i = 0; i < 4; ++i) {
        int ct = ch * 4 + i;
        g_[i] = g[ct * 16 + lm]; be_[i] = be[ct * 16 + lm]; b2_[i] = b2[ct * 16 + lm];
    }
    float v[4][4], mu[4], rs_[4];
#pragma unroll
    for (int reg = 0; reg < 4; ++reg) {
        float s = 0.f;
#pragma unroll
        for (int i = 0; i < 4; ++i) { v[i][reg] = acc[i][reg] + b2_[i]; s += v[i][reg]; }
        s += __shfl_xor(s, 1); s += __shfl_xor(s, 2);
        s += __shfl_xor(s, 4); s += __shfl_xor(s, 8);
        if (lm == 0) sX[ch * 32 + g16 + lq * 4 + reg] = s;
    }
    bar_lgkm();
#pragma unroll
    for (int reg = 0; reg < 4; ++reg)
        mu[reg] = (sX[g16 + lq * 4 + reg] + sX[32 + g16 + lq * 4 + reg]) * (1.f / 128.f);
#pragma unroll
    for (int reg = 0; reg < 4; ++reg) {
        float q = 0.f;
#pragma unroll
        for (int i = 0; i < 4; ++i) { v[i][reg] -= mu[reg]; q += v[i][reg] * v[i][reg]; }
        q += __shfl_xor(q, 1); q += __shfl_xor(q, 2);
        q += __shfl_xor(q, 4); q += __shfl_xor(q, 8);
        if (lm == 0) sY[ch * 32 + g16 + lq * 4 + reg] = q;
    }
    bar_lgkm();
#pragma unroll
    for (int reg = 0; reg < 4; ++reg)
        rs_[reg] = rsqrtf((sY[g16 + lq * 4 + reg] + sY[32 + g16 + lq * 4 + reg]) * (1.f / 128.f) + 1e-5f);

    if (MODE == 4) {
        // fused: park ns = nf + o (bf16 — identical bits to old nfbf) into sH
#pragma unroll
        for (int reg = 0; reg < 4; ++reg) {
            int row = m0 + g16 + lq * 4 + reg;
#pragma unroll
            for (int i = 0; i < 4; ++i) {
                float o = v[i][reg] * rs_[reg] * g_[i] + be_[i];
                size_t gi = (size_t)row * 128 + (size_t)(ch * 4 + i) * 16 + lm;
                float ns = outF[gi] + o;
                sH[(g16 + lq * 4 + reg) * SH_STRIDE + (ch * 4 + i) * 16 + lm] = (short)f2bf(ns);
            }
        }
        bar_lgkm();    // parked ns visible to both col-half waves

        // ---- dec L0: K=128 from sH, W=Wd0, bias db0 ----
#pragma unroll
        for (int i = 0; i < 4; ++i) acc[i] = (f32x4)(0.f);
        {
            WStage64 ws, wsn;
            wload64(ws, Wd0, 128, 0, tid);
#pragma unroll
            for (int c = 0; c < 2; ++c) {
                if (c == 0) wload64(wsn, Wd0, 128, 64, tid);
                bf16x8 a0 = *(const bf16x8*)&sH[(g16 + lm) * SH_STRIDE + c * 64 + lq * 8];
                bf16x8 a1 = *(const bf16x8*)&sH[(g16 + lm) * SH_STRIDE + c * 64 + 32 + lq * 8];
                bar_lgkm();
                wstore64(ws, sW, tid);
                bar_lgkm();
                mfma_sweepNS(acc, a0, sW, ch, lq * 8, lm);
                mfma_sweepNS(acc, a1, sW, ch, 32 + lq * 8, lm);
                ws = wsn;
            }
        }
        bar_lgkm();
        parkNS(acc, db0, sH, g16, ch, lm, lq);
        bar_lgkm();

        // ---- dec L1: W=Wd1, bias db1 ----
#pragma unroll
        for (int i = 0; i < 4; ++i) acc[i] = (f32x4)(0.f);
        {
            WStage64 ws, wsn;
            wload64(ws, Wd1, 128, 0, tid);
#pragma unroll
            for (int c = 0; c < 2; ++c) {
                if (c == 0) wload64(wsn, Wd1, 128, 64, tid);
                bf16x8 a0 = *(const bf16x8*)&sH[(g16 + lm) * SH_STRIDE + c * 64 + lq * 8];
                bf16x8 a1 = *(const bf16x8*)&sH[(g16 + lm) * SH_STRIDE + c * 64 + 32 + lq * 8];
                bar_lgkm();
                wstore64(ws, sW, tid);
                bar_lgkm();
                mfma_sweepNS(acc, a0, sW, ch, lq * 8, lm);
                mfma_sweepNS(acc, a1, sW, ch, 32 + lq * 8, lm);
                ws = wsn;
            }
        }
        bar_lgkm();
        parkNS(acc, db1, sH, g16, ch, lm, lq);
        bar_lgkm();

        // ---- dec tail: 128 -> 3, fp32 weights dW2f ----
        if (tid < 96) {
            int r = tid / 3, o = tid - r * 3;
            int row = m0 + r;
            if (row < M) {
                float s = db2[o];
#pragma unroll
                for (int kk = 0; kk < 16; ++kk) {
                    bf16x8 h8 = *(const bf16x8*)&sH[r * SH_STRIDE + kk * 8];
#pragma unroll
                    for (int j = 0; j < 8; ++j)
                        s += bf2f(h8[j]) * dW2f[(kk * 8 + j) * 3 + o];
                }
                decOut[(size_t)row * 3 + o] = s;
            }
        }
        return;
    }

    // MODE 0 / MODE 2: write out
#pragma unroll
    for (int reg = 0; reg < 4; ++reg) {
        int row = m0 + g16 + lq * 4 + reg;
        if (row < M) {
#pragma unroll
            for (int i = 0; i < 4; ++i) {
                float o = v[i][reg] * rs_[reg] * g_[i] + be_[i];
                size_t gi = (size_t)row * 128 + (size_t)(ch * 4 + i) * 16 + lm;
                if (resid) {
                    float ns = outF[gi] + o;
                    outF[gi] = ns;
                    if (outB) outB[gi] = (short)f2bf(ns);
                } else {
                    outF[gi] = o;
                    if (outB) outB[gi] = (short)f2bf(o);
                }
            }
        }
    }
}

// ---------------------------------------------------------------------------
// Edge-encoder body (device fn) — the old gnn_mlp<4,0,1> specialized:
// 256 threads, 4 waves x 32 rows, K0=7 staged to 32, bf16 ef write.
// LDS layout: sH 34816 B | sW 14336 B = 49152 B.
// ---------------------------------------------------------------------------
__device__ __forceinline__ void ence_body(char* smem, int bid,
    const short* __restrict__ Wt0, const short* __restrict__ Wt1, const short* __restrict__ Wt2,
    const float* __restrict__ b0, const float* __restrict__ b1, const float* __restrict__ b2,
    const float* __restrict__ g, const float* __restrict__ be,
    const float* __restrict__ A0f, int K0,
    const int* __restrict__ eList,
    short* __restrict__ outB, int M)
{
    short* sH = (short*)smem;                 // 4*32*SH_STRIDE
    short* sW = (short*)(smem + 34816);       // 128*SW_STRIDE
    const int tid = threadIdx.x;
    const int lane = tid & 63;
    const int w = tid >> 6;
    const int lm = lane & 15;
    const int lq = lane >> 4;
    const int w32 = w * 32;
    const int m0 = bid * 128;

    f32x4 acc[2][8];
    zero_acc(acc);

    // -------- layer 0: stage input (K0 -> 32) + single 32-k chunk --------
#pragma unroll
    for (int i = 0; i < 16; ++i) {
        int flat = lane + i * 64;
        int r = flat >> 5, k = flat & 31;
        int row = m0 + w32 + r;
        float v = 0.f;
        if (k < K0 && row < M) {
            int src = eList ? eList[row] : row;
            v = A0f[(size_t)src * K0 + k];
        }
        sH[(w32 + r) * SH_STRIDE + k] = (short)f2bf(v);
    }
    {
        WStageE ws;
        wloadE(ws, Wt0, 32, 0, tid);
        bf16x8 a0 = *(const bf16x8*)&sH[(w32 + lm) * SH_STRIDE + lq * 8];
        bf16x8 a1 = *(const bf16x8*)&sH[(w32 + 16 + lm) * SH_STRIDE + lq * 8];
        bar_lgkm();
        wstoreE(ws, sW, tid);
        bar_lgkm();
        mfma_sweep_lds(acc, a0, a1, sW, lm, lq);
    }
    bar_lgkm();
    park(acc, b0, sH, w32, lm, lq);

    // -------- layer 1 --------
    zero_acc(acc);
    {
        WStageE ws, wsn;
        wloadE(ws, Wt1, 128, 0, tid);
#pragma unroll
        for (int c = 0; c < 4; ++c) {
            if (c + 1 < 4) wloadE(wsn, Wt1, 128, (c + 1) * 32, tid);
            bf16x8 a0 = *(const bf16x8*)&sH[(w32 + lm) * SH_STRIDE + c * 32 + lq * 8];
            bf16x8 a1 = *(const bf16x8*)&sH[(w32 + 16 + lm) * SH_STRIDE + c * 32 + lq * 8];
            bar_lgkm();
            wstoreE(ws, sW, tid);
            bar_lgkm();
            mfma_sweep_lds(acc, a0, a1, sW, lm, lq);
            ws = wsn;
        }
    }
    bar_lgkm();
    park(acc, b1, sH, w32, lm, lq);

    // -------- layer 2 --------
    zero_acc(acc);
    {
        WStageE ws, wsn;
        wloadE(ws, Wt2, 128, 0, tid);
#pragma unroll
        for (int c = 0; c < 4; ++c) {
            if (c + 1 < 4) wloadE(wsn, Wt2, 128, (c + 1) * 32, tid);
            bf16x8 a0 = *(const bf16x8*)&sH[(w32 + lm) * SH_STRIDE + c * 32 + lq * 8];
            bf16x8 a1 = *(const bf16x8*)&sH[(w32 + 16 + lm) * SH_STRIDE + c * 32 + lq * 8];
            bar_lgkm();
            wstoreE(ws, sW, tid);
            bar_lgkm();
            mfma_sweep_lds(acc, a0, a1, sW, lm, lq);
            ws = wsn;
        }
    }

    // -------- epilogue: LN + bf16 write --------
    float g_[8], be_[8], b2_[8];
#pragma unroll
    for (int ct = 0; ct < 8; ++ct) {
        g_[ct] = g[ct * 16 + lm]; be_[ct] = be[ct * 16 + lm]; b2_[ct] = b2[ct * 16 + lm];
    }
#pragma unroll
    for (int rt = 0; rt < 2; ++rt) {
#pragma unroll
        for (int reg = 0; reg < 4; ++reg) {
            int row = m0 + w32 + rt * 16 + lq * 4 + reg;
            float vv[8];
            float s = 0.f;
#pragma unroll
            for (int ct = 0; ct < 8; ++ct) { vv[ct] = acc[rt][ct][reg] + b2_[ct]; s += vv[ct]; }
            s += __shfl_xor(s, 1); s += __shfl_xor(s, 2);
            s += __shfl_xor(s, 4); s += __shfl_xor(s, 8);
            float mu = s * (1.f / 128.f);
            float q = 0.f;
#pragma unroll
            for (int ct = 0; ct < 8; ++ct) { vv[ct] -= mu; q += vv[ct] * vv[ct]; }
            q += __shfl_xor(q, 1); q += __shfl_xor(q, 2);
            q += __shfl_xor(q, 4); q += __shfl_xor(q, 8);
            float rs = rsqrtf(q * (1.f / 128.f) + 1e-5f);
            if (row < M) {
#pragma unroll
                for (int ct = 0; ct < 8; ++ct) {
                    float o = vv[ct] * rs * g_[ct] + be_[ct];
                    outB[(size_t)row * 128 + ct * 16 + lm] = (short)f2bf(o);
                }
            }
        }
    }
}

// ---------------------------------------------------------------------------
// Merged encoder launch: blocks [0, NN/32) run enc_n, the rest run enc_e.
// Both populations are independent and latency-bound -> co-scheduling hides
// the smaller under the larger.
// ---------------------------------------------------------------------------
__global__ __launch_bounds__(256) void gnn_enc_both(
    const short* __restrict__ nW0, const short* __restrict__ nW1, const short* __restrict__ nW2,
    const float* __restrict__ nb0, const float* __restrict__ nb1, const float* __restrict__ nb2,
    const float* __restrict__ ng, const float* __restrict__ nbe,
    const float* __restrict__ node_x, int nK0,
    float* __restrict__ nf, short* __restrict__ nfbf, int NM,
    const short* __restrict__ eW0, const short* __restrict__ eW1, const short* __restrict__ eW2,
    const float* __restrict__ eb0, const float* __restrict__ eb1, const float* __restrict__ eb2,
    const float* __restrict__ eg, const float* __restrict__ ebe,
    const float* __restrict__ edge_x, int eK0,
    const int* __restrict__ eList, short* __restrict__ efB, int EM)
{
    __shared__ __align__(16) char smem[49152];
    if ((int)blockIdx.x < NN / 32) {
        ns_body<0>(smem, blockIdx.x, nW0, nW1, nW2, nb0, nb1, nb2, ng, nbe,
                   node_x, nK0, nullptr, nullptr, nf, nfbf, nullptr, nullptr,
                   nullptr, nullptr, nullptr, nullptr, nullptr, nullptr, NM, 0);
    } else {
        ence_body(smem, blockIdx.x - NN / 32, eW0, eW1, eW2, eb0, eb1, eb2, eg, ebe,
                  edge_x, eK0, eList, efB, EM);
    }
}

__global__ __launch_bounds__(256) void gnn_nodeNS(
    const short* __restrict__ Wt0, const short* __restrict__ Wt1, const short* __restrict__ Wt2,
    const float* __restrict__ b0, const float* __restrict__ b1, const float* __restrict__ b2,
    const float* __restrict__ g, const float* __restrict__ be,
    const short* __restrict__ nfb, const float* __restrict__ aggf,
    float* __restrict__ outF, short* __restrict__ outB, float* __restrict__ aggOut, int M)
{
    __shared__ __align__(16) char smem[27648];
    ns_body<2>(smem, blockIdx.x, Wt0, Wt1, Wt2, b0, b1, b2, g, be,
               nullptr, 0, nfb, aggf, outF, outB, aggOut, nullptr,
               nullptr, nullptr, nullptr, nullptr, nullptr, nullptr, M, 1);
}

__global__ __launch_bounds__(256) void gnn_node_dec(
    const short* __restrict__ Wt0, const short* __restrict__ Wt1, const short* __restrict__ Wt2,
    const float* __restrict__ b0, const float* __restrict__ b1, const float* __restrict__ b2,
    const float* __restrict__ g, const float* __restrict__ be,
    const short* __restrict__ nfb, const float* __restrict__ aggf,
    float* __restrict__ nfF,
    const short* __restrict__ Wd0, const short* __restrict__ Wd1,
    const float* __restrict__ dW2f,
    const float* __restrict__ db0, const float* __restrict__ db1,
    const float* __restrict__ db2,
    float* __restrict__ decOut, int M)
{
    __shared__ __align__(16) char smem[27648];
    ns_body<4>(smem, blockIdx.x, Wt0, Wt1, Wt2, b0, b1, b2, g, be,
               nullptr, 0, nfb, aggf, nfF, nullptr, nullptr, decOut,
               Wd0, Wd1, dW2f, db0, db1, db2, M, 1);
}

// ---------------------------------------------------------------------------
__global__ void zero_i(int* __restrict__ p, int n)
{
    int i = blockIdx.x * 256 + threadIdx.x;
    if (i < n) p[i] = 0;
}
__global__ void csr_count(const int* __restrict__ recv, int* __restrict__ cnt, int E)
{
    int i = blockIdx.x * 256 + threadIdx.x;
    if (i < E) atomicAdd(&cnt[recv[i]], 1);
}
__global__ __launch_bounds__(256) void csr_scan(const int* __restrict__ cnt,
                                                int* __restrict__ cursor, int N)
{
    __shared__ int ssum[257];
    const int tid = threadIdx.x;
    const int per = (N + 255) / 256;
    const int lo = tid * per, hi = min(lo + per, N);
    int s = 0;
    for (int i = lo; i < hi; ++i) s += cnt[i];
    ssum[tid] = s;
    __syncthreads();
    if (tid == 0) {
        int run = 0;
        for (int i = 0; i < 256; ++i) { int t = ssum[i]; ssum[i] = run; run += t; }
        ssum[256] = run;
    }
    __syncthreads();
    int run = ssum[tid];
    for (int i = lo; i < hi; ++i) { int c = cnt[i]; cursor[i] = run; run += c; }
}
__global__ void csr_fill(const int* __restrict__ recv, int* __restrict__ cursor,
                         int* __restrict__ eList, int E)
{
    int i = blockIdx.x * 256 + threadIdx.x;
    if (i < E) {
        int pos = atomicAdd(&cursor[recv[i]], 1);
        eList[pos] = i;
    }
}

// ---------------------------------------------------------------------------
struct WtPrep { const float* src; int K; int Kpad; int dstOff; };
struct WtPrepAll { WtPrep m[26]; };

__global__ void wt_prep_kernel(WtPrepAll all, short* __restrict__ dst)
{
    const WtPrep p = all.m[blockIdx.y];
    int total = 128 * p.Kpad;
    int idx = blockIdx.x * 256 + threadIdx.x;
    if (idx >= total) return;
    int n = idx / p.Kpad, k = idx - n * p.Kpad;
    float v = (k < p.K) ? p.src[(size_t)k * 128 + n] : 0.f;
    dst[p.dstOff + idx] = (short)f2bf(v);
}

__global__ void zero_kernel(float4* __restrict__ p, long n4)
{
    long i = (long)blockIdx.x * blockDim.x + threadIdx.x;
    if (i < n4) p[i] = make_float4(0.f, 0.f, 0.f, 0.f);
}

// ---------------------------------------------------------------------------
extern "C" void kernel_launch(void* const* d_in, const int* in_sizes, int n_in,
                              void* d_out, int out_size, void* d_ws, size_t ws_size,
                              hipStream_t stream)
{
    const float* node_x   = (const float*)d_in[0];
    const float* edge_x   = (const float*)d_in[1];
    const float* enc_n_W0 = (const float*)d_in[2];
    const float* enc_n_b0 = (const float*)d_in[3];
    const float* enc_n_W1 = (const float*)d_in[4];
    const float* enc_n_b1 = (const float*)d_in[5];
    const float* enc_n_W2 = (const float*)d_in[6];
    const float* enc_n_b2 = (const float*)d_in[7];
    const float* enc_n_g  = (const float*)d_in[8];
    const float* enc_n_be = (const float*)d_in[9];
    const float* enc_e_W0 = (const float*)d_in[10];
    const float* enc_e_b0 = (const float*)d_in[11];
    const float* enc_e_W1 = (const float*)d_in[12];
    const float* enc_e_b1 = (const float*)d_in[13];
    const float* enc_e_W2 = (const float*)d_in[14];
    const float* enc_e_b2 = (const float*)d_in[15];
    const float* enc_e_g  = (const float*)d_in[16];
    const float* enc_e_be = (const float*)d_in[17];
    const float* gnb_e_W0 = (const float*)d_in[18];
    const float* gnb_e_b0 = (const float*)d_in[19];
    const float* gnb_e_W1 = (const float*)d_in[20];
    const float* gnb_e_b1 = (const float*)d_in[21];
    const float* gnb_e_W2 = (const float*)d_in[22];
    const float* gnb_e_b2 = (const float*)d_in[23];
    const float* gnb_e_g  = (const float*)d_in[24];
    const float* gnb_e_be = (const float*)d_in[25];
    const float* gnb_n_W0 = (const float*)d_in[26];
    const float* gnb_n_b0 = (const float*)d_in[27];
    const float* gnb_n_W1 = (const float*)d_in[28];
    const float* gnb_n_b1 = (const float*)d_in[29];
    const float* gnb_n_W2 = (const float*)d_in[30];
    const float* gnb_n_b2 = (const float*)d_in[31];
    const float* gnb_n_g  = (const float*)d_in[32];
    const float* gnb_n_be = (const float*)d_in[33];
    const float* dec_W0   = (const float*)d_in[34];
    const float* dec_b0   = (const float*)d_in[35];
    const float* dec_W1   = (const float*)d_in[36];
    const float* dec_b1   = (const float*)d_in[37];
    const float* dec_W2   = (const float*)d_in[38];
    const float* dec_b2   = (const float*)d_in[39];
    const int*   senders  = (const int*)d_in[40];
    const int*   receivers= (const int*)d_in[41];
    float* out = (float*)d_out;

    const int N = NN, E = EE;
    const int WT_TOTAL = (32 + 128 + 128 + 32 + 128 + 128 + 3 * (384 + 128 + 128 + 256 + 128 + 128)
                          + 128 + 128) * 128;

    // ---- workspace layout (efLo removed in round 6) ----
    float* nf   = (float*)d_ws;                      // N*128 f32
    float* agg  = nf + (size_t)N * 128;              // N*128 f32
    short* efHi = (short*)(agg + (size_t)N * 128);   // E*128 bf16 (slot order)
    short* nfbf = efHi + (size_t)E * 128;            // N*128 bf16
    short* wt   = nfbf + (size_t)N * 128;            // WT_TOTAL bf16
    int*   eList = (int*)(wt + WT_TOTAL);            // E ints
    size_t need_sorted = (size_t)((char*)(eList + E) - (char*)d_ws);
    int* cnt    = (int*)agg;                          // transient overlay on agg
    int* cursor = cnt + N;

    const bool useSorted = (ws_size >= need_sorted);
    const int* eL = useSorted ? eList : nullptr;

    WtPrepAll tbl;
    int nMat = 0, off = 0;
    int o_encn[3], o_ence[3], o_ge0[3], o_ge1[3], o_ge2[3], o_gn0[3], o_gn1[3], o_gn2[3], o_dec[2];
    auto add = [&](const float* src, int K, int Kpad) {
        tbl.m[nMat].src = src; tbl.m[nMat].K = K; tbl.m[nMat].Kpad = Kpad;
        tbl.m[nMat].dstOff = off;
        int r = off; off += 128 * Kpad; ++nMat; return r;
    };
    o_encn[0] = add(enc_n_W0, 12, 32);
    o_encn[1] = add(enc_n_W1, 128, 128);
    o_encn[2] = add(enc_n_W2, 128, 128);
    o_ence[0] = add(enc_e_W0, 7, 32);
    o_ence[1] = add(enc_e_W1, 128, 128);
    o_ence[2] = add(enc_e_W2, 128, 128);
    for (int s = 0; s < 3; ++s) {
        o_ge0[s] = add(gnb_e_W0 + (size_t)s * 384 * 128, 384, 384);
        o_ge1[s] = add(gnb_e_W1 + (size_t)s * 128 * 128, 128, 128);
        o_ge2[s] = add(gnb_e_W2 + (size_t)s * 128 * 128, 128, 128);
        o_gn0[s] = add(gnb_n_W0 + (size_t)s * 256 * 128, 256, 256);
        o_gn1[s] = add(gnb_n_W1 + (size_t)s * 128 * 128, 128, 128);
        o_gn2[s] = add(gnb_n_W2 + (size_t)s * 128 * 128, 128, 128);
    }
    o_dec[0] = add(dec_W0, 128, 128);
    o_dec[1] = add(dec_W1, 128, 128);

    wt_prep_kernel<<<dim3(192, 26), 256, 0, stream>>>(tbl, wt);

    if (useSorted) {
        zero_i<<<dim3((N + 255) / 256), 256, 0, stream>>>(cnt, N);
        csr_count<<<dim3((E + 255) / 256), 256, 0, stream>>>(receivers, cnt, E);
        csr_scan<<<dim3(1), 256, 0, stream>>>(cnt, cursor, N);
        csr_fill<<<dim3((E + 255) / 256), 256, 0, stream>>>(receivers, cursor, eList, E);
    }
    // zero agg once (after csr: cnt/cursor overlay agg); steps re-zero in node kernel
    zero_kernel<<<dim3((N * 32 + 255) / 256), 256, 0, stream>>>((float4*)agg, (long)N * 32);

    const dim3 gE(E / 128);                 // edge kernels: 1250 blocks x 256 thr
    const dim3 gNS(N / 32);                 // node kernels: 625 blocks x 256 thr

    // ---- merged encoders (enc_n 625 blocks || enc_e 1250 blocks) ----
    gnn_enc_both<<<dim3(N / 32 + E / 128), 256, 0, stream>>>(
        wt + o_encn[0], wt + o_encn[1], wt + o_encn[2],
        enc_n_b0, enc_n_b1, enc_n_b2, enc_n_g, enc_n_be,
        node_x, 12, nf, nfbf, N,
        wt + o_ence[0], wt + o_ence[1], wt + o_ence[2],
        enc_e_b0, enc_e_b1, enc_e_b2, enc_e_g, enc_e_be,
        edge_x, 7, eL, efHi, E);

    // ---- 3 message-passing steps; node s=2 fused with decoder ----
    for (int s = 0; s < 3; ++s) {
        const float* eb0 = gnb_e_b0 + (size_t)s * 128;
        const float* eb1 = gnb_e_b1 + (size_t)s * 128;
        const float* eb2 = gnb_e_b2 + (size_t)s * 128;
        const float* eg  = gnb_e_g  + (size_t)s * 128;
        const float* ebe = gnb_e_be + (size_t)s * 128;
        const float* nb0 = gnb_n_b0 + (size_t)s * 128;
        const float* nb1 = gnb_n_b1 + (size_t)s * 128;
        const float* nb2 = gnb_n_b2 + (size_t)s * 128;
        const float* ng  = gnb_n_g  + (size_t)s * 128;
        const float* nbe = gnb_n_be + (size_t)s * 128;

        if (s < 2) {
            gnn_edge64<1><<<gE, 256, 0, stream>>>(wt + o_ge0[s], wt + o_ge1[s], wt + o_ge2[s],
                eb0, eb1, eb2, eg, ebe,
                nfbf, efHi, eL, senders, receivers, agg);
            gnn_nodeNS<<<gNS, 256, 0, stream>>>(wt + o_gn0[s], wt + o_gn1[s], wt + o_gn2[s],
                nb0, nb1, nb2, ng, nbe,
                nfbf, agg, nf, nfbf, agg, N);
        } else {
            gnn_edge64<0><<<gE, 256, 0, stream>>>(wt + o_ge0[s], wt + o_ge1[s], wt + o_ge2[s],
                eb0, eb1, eb2, eg, ebe,
                nfbf, efHi, eL, senders, receivers, agg);
            gnn_node_dec<<<gNS, 256, 0, stream>>>(wt + o_gn0[s], wt + o_gn1[s], wt + o_gn2[s],
                nb0, nb1, nb2, ng, nbe,
                nfbf, agg, nf,
                wt + o_dec[0], wt + o_dec[1], dec_W2,
                dec_b0, dec_b1, dec_b2,
                out, N);
        }
    }
}

// Round 9
// 526.801 us; speedup vs baseline: 1.1091x; 1.1091x over previous
//
#include <hip/hip_runtime.h>
#include <hip/hip_bf16.h>

#define NN 20000
#define EE 160000

typedef __attribute__((ext_vector_type(8))) short bf16x8;
typedef __attribute__((ext_vector_type(4))) float f32x4;

__device__ __forceinline__ unsigned short f2bf(float f) {
    unsigned int u = __float_as_uint(f);
    u += 0x7FFFu + ((u >> 16) & 1);   // RNE
    return (unsigned short)(u >> 16);
}
__device__ __forceinline__ float bf2f(short s) {
    return __uint_as_float(((unsigned int)(unsigned short)s) << 16);
}
__device__ __forceinline__ bf16x8 pack8(float4 a, float4 b) {
    bf16x8 r;
    r[0] = (short)f2bf(a.x); r[1] = (short)f2bf(a.y);
    r[2] = (short)f2bf(a.z); r[3] = (short)f2bf(a.w);
    r[4] = (short)f2bf(b.x); r[5] = (short)f2bf(b.y);
    r[6] = (short)f2bf(b.z); r[7] = (short)f2bf(b.w);
    return r;
}

#define SH_STRIDE 136
#define SW_STRIDE 56
// edge64 kernel strides (LDS = 33792 + 18432 + 1024 = 53248 B -> 3 blocks/CU)
#define SH64 132
#define SW64 72

// barrier that does NOT drain vmcnt (gathers stay in flight)
__device__ __forceinline__ void bar_lgkm() {
    asm volatile("s_waitcnt lgkmcnt(0)\n\ts_barrier" ::: "memory");
}

__device__ __forceinline__ void mfma_sweep_lds(f32x4 (&acc)[2][8], bf16x8 a0, bf16x8 a1,
                                               const short* sWb, int lm, int lq)
{
#pragma unroll
    for (int ct = 0; ct < 8; ++ct) {
        bf16x8 b = *(const bf16x8*)(sWb + (ct * 16 + lm) * SW_STRIDE + lq * 8);
        acc[0][ct] = __builtin_amdgcn_mfma_f32_16x16x32_bf16(a0, b, acc[0][ct], 0, 0, 0);
        acc[1][ct] = __builtin_amdgcn_mfma_f32_16x16x32_bf16(a1, b, acc[1][ct], 0, 0, 0);
    }
}

__device__ __forceinline__ void mfma_sweep64(f32x4 (&acc)[2][8], bf16x8 a0, bf16x8 a1,
                                             const short* sWb, int colOff, int lm)
{
#pragma unroll
    for (int ct = 0; ct < 8; ++ct) {
        bf16x8 b = *(const bf16x8*)(sWb + (ct * 16 + lm) * SW64 + colOff);
        acc[0][ct] = __builtin_amdgcn_mfma_f32_16x16x32_bf16(a0, b, acc[0][ct], 0, 0, 0);
        acc[1][ct] = __builtin_amdgcn_mfma_f32_16x16x32_bf16(a1, b, acc[1][ct], 0, 0, 0);
    }
}

// N-split sweep: one wave covers 4 col-tiles (ch selects which half of N=128)
__device__ __forceinline__ void mfma_sweepNS(f32x4 (&acc)[4], bf16x8 a,
                                             const short* sWb, int ch, int colOff, int lm)
{
#pragma unroll
    for (int i = 0; i < 4; ++i) {
        int ct = ch * 4 + i;
        bf16x8 b = *(const bf16x8*)(sWb + (ct * 16 + lm) * SW64 + colOff);
        acc[i] = __builtin_amdgcn_mfma_f32_16x16x32_bf16(a, b, acc[i], 0, 0, 0);
    }
}

// W-chunk pipeline (32-k chunks, enc_e): load regs early / ds_write later.
struct WStageE { bf16x8 v[2]; };
__device__ __forceinline__ void wloadE(WStageE& ws, const short* __restrict__ Wt,
                                       int Kpad, int k0, int tid)
{
    int r = tid >> 1, h = tid & 1;
    const short* src = Wt + (size_t)r * Kpad + k0 + h * 16;
    ws.v[0] = *(const bf16x8*)src;
    ws.v[1] = *(const bf16x8*)(src + 8);
}
__device__ __forceinline__ void wstoreE(const WStageE& ws, short* __restrict__ sW, int tid)
{
    int r = tid >> 1, h = tid & 1;
    short* dst = sW + r * SW_STRIDE + h * 16;
    *(bf16x8*)dst       = ws.v[0];
    *(bf16x8*)(dst + 8) = ws.v[1];
}

// 64-k W stage (NT=256): 128 rows x 64 k, 4 bf16x8/thread
struct WStage64 { bf16x8 v[4]; };
__device__ __forceinline__ void wload64(WStage64& ws, const short* __restrict__ Wt,
                                        int Kpad, int k0, int tid)
{
#pragma unroll
    for (int j = 0; j < 4; ++j) {
        int i = tid + j * 256;
        int r = i >> 3, h = i & 7;
        ws.v[j] = *(const bf16x8*)(Wt + (size_t)r * Kpad + k0 + h * 8);
    }
}
__device__ __forceinline__ void wstore64(const WStage64& ws, short* __restrict__ sW, int tid)
{
#pragma unroll
    for (int j = 0; j < 4; ++j) {
        int i = tid + j * 256;
        int r = i >> 3, h = i & 7;
        *(bf16x8*)(sW + r * SW64 + h * 8) = ws.v[j];
    }
}

__device__ __forceinline__ void zero_acc(f32x4 (&acc)[2][8]) {
#pragma unroll
    for (int i = 0; i < 2; ++i)
#pragma unroll
        for (int j = 0; j < 8; ++j) acc[i][j] = (f32x4)(0.f);
}

__device__ __forceinline__ void park(const f32x4 (&acc)[2][8], const float* __restrict__ bias,
                                     short* __restrict__ sH, int w32, int lm, int lq)
{
#pragma unroll
    for (int ct = 0; ct < 8; ++ct) {
        float bb = bias[ct * 16 + lm];
#pragma unroll
        for (int rt = 0; rt < 2; ++rt) {
            int rbase = w32 + rt * 16 + lq * 4;
#pragma unroll
            for (int reg = 0; reg < 4; ++reg) {
                float v = fmaxf(acc[rt][ct][reg] + bb, 0.f);
                sH[(rbase + reg) * SH_STRIDE + ct * 16 + lm] = (short)f2bf(v);
            }
        }
    }
}

// N-split park: 16 rows x 64 cols (this wave's half)
__device__ __forceinline__ void parkNS(const f32x4 (&acc)[4], const float* __restrict__ bias,
                                       short* __restrict__ sH, int g16, int ch, int lm, int lq)
{
#pragma unroll
    for (int i = 0; i < 4; ++i) {
        int ct = ch * 4 + i;
        float bb = bias[ct * 16 + lm];
#pragma unroll
        for (int reg = 0; reg < 4; ++reg) {
            float v = fmaxf(acc[i][reg] + bb, 0.f);
            sH[(g16 + lq * 4 + reg) * SH_STRIDE + ct * 16 + lm] = (short)f2bf(v);
        }
    }
}

__device__ __forceinline__ void park64(const f32x4 (&acc)[2][8], const float* __restrict__ bias,
                                       short* __restrict__ sH, int w32, int lm, int lq)
{
#pragma unroll
    for (int ct = 0; ct < 8; ++ct) {
        float bb = bias[ct * 16 + lm];
#pragma unroll
        for (int rt = 0; rt < 2; ++rt) {
            int rbase = w32 + rt * 16 + lq * 4;
#pragma unroll
            for (int reg = 0; reg < 4; ++reg) {
                float v = fmaxf(acc[rt][ct][reg] + bb, 0.f);
                sH[(rbase + reg) * SH64 + ct * 16 + lm] = (short)f2bf(v);
            }
        }
    }
}

// N-split 64-k fragment (node core): this lane's row, k [c*64, c*64+64).
struct FragNS {
    bf16x8 a0, a1;
    float4 f0, f1, f2, f3;
    int isF;
};
__device__ __forceinline__ void load_fragNS(FragNS& fr, int c,
    const short* __restrict__ nfb, const float* __restrict__ aggf, int r0m, int lq)
{
    fr.isF = 0;
    if (c >= 2) {
        const float* p = aggf + (size_t)r0m * 128 + (c - 2) * 64 + lq * 8;
        fr.f0 = *(const float4*)p;        fr.f1 = *(const float4*)(p + 4);
        fr.f2 = *(const float4*)(p + 32); fr.f3 = *(const float4*)(p + 36);
        fr.isF = 1;
    } else {
        const short* p = nfb + (size_t)r0m * 128 + c * 64 + lq * 8;
        fr.a0 = *(const bf16x8*)p;
        fr.a1 = *(const bf16x8*)(p + 32);
    }
}

// 64-k fragment (edge): [0]=r0 h0, [1]=r1 h0, [2]=r0 h1, [3]=r1 h1
struct Frag64 { bf16x8 a[4]; };

__device__ __forceinline__ void load_frag64(Frag64& fr, int c,
    const short* __restrict__ nfb, const short* __restrict__ efHi,
    int iS0, int iS1, int iR0, int iR1, size_t eO0, size_t eO1, int lq)
{
    int kb = (c & 1) * 64 + lq * 8;
    int seg = c >> 1;
    const short *base0, *base1;
    if (seg == 0)      { base0 = nfb + (size_t)iS0 * 128; base1 = nfb + (size_t)iS1 * 128; }
    else if (seg == 1) { base0 = nfb + (size_t)iR0 * 128; base1 = nfb + (size_t)iR1 * 128; }
    else               { base0 = efHi + eO0;              base1 = efHi + eO1; }
    fr.a[0] = *(const bf16x8*)(base0 + kb);
    fr.a[1] = *(const bf16x8*)(base1 + kb);
    fr.a[2] = *(const bf16x8*)(base0 + kb + 32);
    fr.a[3] = *(const bf16x8*)(base1 + kb + 32);
}

// ---------------------------------------------------------------------------
// Edge MLP kernel — UNCHANGED round-6 body (proven; latency floor ~71us).
// ef master is a single bf16 array. RESID=1: ef += new_ef (bf16 RMW).
// ---------------------------------------------------------------------------
template<int RESID>
__global__ __launch_bounds__(256) void gnn_edge64(
    const short* __restrict__ Wt0,
    const short* __restrict__ Wt1, const short* __restrict__ Wt2,
    const float* __restrict__ b0, const float* __restrict__ b1, const float* __restrict__ b2,
    const float* __restrict__ g, const float* __restrict__ be,
    const short* __restrict__ nfb,
    short* __restrict__ efHi,
    const int* __restrict__ eList,
    const int* __restrict__ senders, const int* __restrict__ receivers,
    float* __restrict__ aggOut)
{
    __shared__ short sH[128 * SH64];
    __shared__ short sW[128 * SW64];
    __shared__ int sRcv[128], sSnd[128];
    const int tid = threadIdx.x;
    const int lane = tid & 63;
    const int w = tid >> 6;
    const int lm = lane & 15;
    const int lq = lane >> 4;
    const int w32 = w * 32;
    const int m0 = blockIdx.x * 128;

    if (tid < 128) {
        int slot = m0 + tid;                       // grid exact: slot < E
        int e = eList ? eList[slot] : slot;
        sRcv[tid] = receivers[e];
        sSnd[tid] = senders[e];
    }
    bar_lgkm();

    f32x4 acc[2][8];
    zero_acc(acc);

    const int s0 = w32 + 2 * lm, s1 = s0 + 1;
    const int iS0 = sSnd[s0], iS1 = sSnd[s1];
    const int iR0 = sRcv[s0], iR1 = sRcv[s1];
    const size_t eO0 = (size_t)(m0 + s0) * 128;
    const size_t eO1 = (size_t)(m0 + s1) * 128;

    // -------- layer 0: K=384 in 6 chunks of 64 --------
    {
        WStage64 ws, wsn;
        Frag64 cur, nxt;
        wload64(ws, Wt0, 384, 0, tid);
        load_frag64(cur, 0, nfb, efHi, iS0, iS1, iR0, iR1, eO0, eO1, lq);
#pragma unroll
        for (int c = 0; c < 6; ++c) {
            if (c + 1 < 6) {
                wload64(wsn, Wt0, 384, (c + 1) * 64, tid);
                load_frag64(nxt, c + 1, nfb, efHi, iS0, iS1, iR0, iR1, eO0, eO1, lq);
            }
            bar_lgkm();
            wstore64(ws, sW, tid);
            bar_lgkm();
            mfma_sweep64(acc, cur.a[0], cur.a[1], sW, lq * 8, lm);
            mfma_sweep64(acc, cur.a[2], cur.a[3], sW, 32 + lq * 8, lm);
            ws = wsn; cur = nxt;
        }
    }
    bar_lgkm();
    park64(acc, b0, sH, w32, lm, lq);

    // -------- layer 1: 2 chunks of 64 --------
    zero_acc(acc);
    {
        WStage64 ws, wsn;
        wload64(ws, Wt1, 128, 0, tid);
#pragma unroll
        for (int c = 0; c < 2; ++c) {
            if (c == 0) wload64(wsn, Wt1, 128, 64, tid);
            bf16x8 a0h0 = *(const bf16x8*)&sH[(w32 + lm) * SH64 + c * 64 + lq * 8];
            bf16x8 a1h0 = *(const bf16x8*)&sH[(w32 + 16 + lm) * SH64 + c * 64 + lq * 8];
            bf16x8 a0h1 = *(const bf16x8*)&sH[(w32 + lm) * SH64 + c * 64 + 32 + lq * 8];
            bf16x8 a1h1 = *(const bf16x8*)&sH[(w32 + 16 + lm) * SH64 + c * 64 + 32 + lq * 8];
            bar_lgkm();
            wstore64(ws, sW, tid);
            bar_lgkm();
            mfma_sweep64(acc, a0h0, a1h0, sW, lq * 8, lm);
            mfma_sweep64(acc, a0h1, a1h1, sW, 32 + lq * 8, lm);
            ws = wsn;
        }
    }
    bar_lgkm();
    park64(acc, b1, sH, w32, lm, lq);

    // -------- layer 2: 2 chunks of 64 --------
    zero_acc(acc);
    {
        WStage64 ws, wsn;
        wload64(ws, Wt2, 128, 0, tid);
#pragma unroll
        for (int c = 0; c < 2; ++c) {
            if (c == 0) wload64(wsn, Wt2, 128, 64, tid);
            bf16x8 a0h0 = *(const bf16x8*)&sH[(w32 + lm) * SH64 + c * 64 + lq * 8];
            bf16x8 a1h0 = *(const bf16x8*)&sH[(w32 + 16 + lm) * SH64 + c * 64 + lq * 8];
            bf16x8 a0h1 = *(const bf16x8*)&sH[(w32 + lm) * SH64 + c * 64 + 32 + lq * 8];
            bf16x8 a1h1 = *(const bf16x8*)&sH[(w32 + 16 + lm) * SH64 + c * 64 + 32 + lq * 8];
            bar_lgkm();
            wstore64(ws, sW, tid);
            bar_lgkm();
            mfma_sweep64(acc, a0h0, a1h0, sW, lq * 8, lm);
            mfma_sweep64(acc, a0h1, a1h1, sW, 32 + lq * 8, lm);
            ws = wsn;
        }
    }

    // -------- epilogue: LN + (RESID ? bf16 ef RMW) + merged-run atomics
    float g_[8], be_[8], b2_[8];
#pragma unroll
    for (int ct = 0; ct < 8; ++ct) {
        g_[ct] = g[ct * 16 + lm]; be_[ct] = be[ct * 16 + lm]; b2_[ct] = b2[ct * 16 + lm];
    }
    float run[8];
    int curRcv = -1;
#pragma unroll
    for (int j = 0; j < 8; ++j) {
        int rt = j & 1, reg = j >> 1;
        int rloc = w32 + lq * 8 + j;
        float v[8];
        float s = 0.f;
#pragma unroll
        for (int ct = 0; ct < 8; ++ct) { v[ct] = acc[rt][ct][reg] + b2_[ct]; s += v[ct]; }
        s += __shfl_xor(s, 1); s += __shfl_xor(s, 2);
        s += __shfl_xor(s, 4); s += __shfl_xor(s, 8);
        float mu = s * (1.f / 128.f);
        float q = 0.f;
#pragma unroll
        for (int ct = 0; ct < 8; ++ct) { v[ct] -= mu; q += v[ct] * v[ct]; }
        q += __shfl_xor(q, 1); q += __shfl_xor(q, 2);
        q += __shfl_xor(q, 4); q += __shfl_xor(q, 8);
        float rs = rsqrtf(q * (1.f / 128.f) + 1e-5f);
        int rcv = sRcv[rloc];
        float o[8];
#pragma unroll
        for (int ct = 0; ct < 8; ++ct) {
            o[ct] = v[ct] * rs * g_[ct] + be_[ct];
            if (RESID) {
                size_t gi = (size_t)(m0 + rloc) * 128 + ct * 16 + lm;
                float x = bf2f(efHi[gi]) + o[ct];
                efHi[gi] = (short)f2bf(x);
            }
        }
        if (rcv != curRcv) {
            if (curRcv >= 0) {
#pragma unroll
                for (int ct = 0; ct < 8; ++ct)
                    atomicAdd(aggOut + (size_t)curRcv * 128 + ct * 16 + lm, run[ct]);
            }
            curRcv = rcv;
#pragma unroll
            for (int ct = 0; ct < 8; ++ct) run[ct] = o[ct];
        } else {
#pragma unroll
            for (int ct = 0; ct < 8; ++ct) run[ct] += o[ct];
        }
    }
    if (curRcv >= 0) {
#pragma unroll
        for (int ct = 0; ct < 8; ++ct)
            atomicAdd(aggOut + (size_t)curRcv * 128 + ct * 16 + lm, run[ct]);
    }
}

// ---------------------------------------------------------------------------
// N-split body (device fn, pointer-based LDS). MODE 0: enc_n. MODE 2: node
// (resid nf/nfbf write + agg zero). MODE 4: node s=2 fused with decoder —
// parks post-resid LN output (bf16, identical bits to what nfbf held) to LDS
// and runs dec L0/L1/tail in-kernel; writes nothing but decOut.
// LDS layout: sH 8704 B | sW 18432 B | sX 256 B | sY 256 B = 27648 B.
// ---------------------------------------------------------------------------
template<int MODE>
__device__ __forceinline__ void ns_body(char* smem, int bid,
    const short* __restrict__ Wt0, const short* __restrict__ Wt1, const short* __restrict__ Wt2,
    const float* __restrict__ b0, const float* __restrict__ b1, const float* __restrict__ b2,
    const float* __restrict__ g, const float* __restrict__ be,
    const float* __restrict__ A0f, int K0,
    const short* __restrict__ nfb, const float* __restrict__ aggf,
    float* __restrict__ outF, short* __restrict__ outB,
    float* __restrict__ aggOut, float* __restrict__ decOut,
    const short* __restrict__ Wd0, const short* __restrict__ Wd1,
    const float* __restrict__ dW2f,
    const float* __restrict__ db0, const float* __restrict__ db1,
    const float* __restrict__ db2,
    int M, int resid)
{
    short* sH = (short*)smem;                      // 32 * SH_STRIDE
    short* sW = (short*)(smem + 8704);             // 128 * SW64
    float* sX = (float*)(smem + 8704 + 18432);     // 64
    float* sY = sX + 64;                           // 64
    const int tid = threadIdx.x;
    const int lane = tid & 63;
    const int w = tid >> 6;
    const int gidx = w >> 1;
    const int ch = w & 1;
    const int lm = lane & 15;
    const int lq = lane >> 4;
    const int g16 = gidx * 16;
    const int m0 = bid * 32;
    const int r0m = min(m0 + g16 + lm, M - 1);

    f32x4 acc[4];
#pragma unroll
    for (int i = 0; i < 4; ++i) acc[i] = (f32x4)(0.f);

    // -------- layer 0 --------
    if (MODE == 0) {
#pragma unroll
        for (int i = 0; i < 4; ++i) {
            int flat = tid + i * 256;
            int r = flat >> 5, k = flat & 31;
            int row = m0 + r;
            float v = (k < K0 && row < M) ? A0f[(size_t)row * K0 + k] : 0.f;
            sH[r * SH_STRIDE + k] = (short)f2bf(v);
        }
        {
            const short* src = Wt0 + (size_t)(tid >> 1) * 32 + (tid & 1) * 16;
            bf16x8 w0 = *(const bf16x8*)src;
            bf16x8 w1 = *(const bf16x8*)(src + 8);
            bar_lgkm();
            short* dst = sW + (tid >> 1) * SW64 + (tid & 1) * 16;
            *(bf16x8*)dst       = w0;
            *(bf16x8*)(dst + 8) = w1;
            bar_lgkm();
        }
        bf16x8 a0 = *(const bf16x8*)&sH[(g16 + lm) * SH_STRIDE + lq * 8];
        mfma_sweepNS(acc, a0, sW, ch, lq * 8, lm);
    } else {
        // node core: K=256 in 4 chunks of 64 (nfbf bf16, then agg fp32)
        WStage64 ws, wsn;
        FragNS cur, nxt;
        wload64(ws, Wt0, 256, 0, tid);
        load_fragNS(cur, 0, nfb, aggf, r0m, lq);
#pragma unroll
        for (int c = 0; c < 4; ++c) {
            if (c + 1 < 4) {
                wload64(wsn, Wt0, 256, (c + 1) * 64, tid);
                load_fragNS(nxt, c + 1, nfb, aggf, r0m, lq);
            }
            bar_lgkm();
            wstore64(ws, sW, tid);
            bar_lgkm();
            bf16x8 u0, u1;
            if (cur.isF) { u0 = pack8(cur.f0, cur.f1); u1 = pack8(cur.f2, cur.f3); }
            else         { u0 = cur.a0;                u1 = cur.a1; }
            mfma_sweepNS(acc, u0, sW, ch, lq * 8, lm);
            mfma_sweepNS(acc, u1, sW, ch, 32 + lq * 8, lm);
            ws = wsn; cur = nxt;
        }
    }
    bar_lgkm();
    parkNS(acc, b0, sH, g16, ch, lm, lq);
    bar_lgkm();

    // node MODE 2: zero this block's agg rows (all reads consumed above)
    if (MODE == 2 && aggOut) {
#pragma unroll
        for (int i = 0; i < 4; ++i) {
            int idx = tid + i * 256;
            int r = idx >> 5, c4 = idx & 31;
            int row = m0 + r;
            if (row < M)
                *(float4*)(aggOut + (size_t)row * 128 + c4 * 4) = make_float4(0.f, 0.f, 0.f, 0.f);
        }
    }

    // -------- layer 1: K=128, 2 chunks of 64 --------
#pragma unroll
    for (int i = 0; i < 4; ++i) acc[i] = (f32x4)(0.f);
    {
        WStage64 ws, wsn;
        wload64(ws, Wt1, 128, 0, tid);
#pragma unroll
        for (int c = 0; c < 2; ++c) {
            if (c == 0) wload64(wsn, Wt1, 128, 64, tid);
            bf16x8 a0 = *(const bf16x8*)&sH[(g16 + lm) * SH_STRIDE + c * 64 + lq * 8];
            bf16x8 a1 = *(const bf16x8*)&sH[(g16 + lm) * SH_STRIDE + c * 64 + 32 + lq * 8];
            bar_lgkm();
            wstore64(ws, sW, tid);
            bar_lgkm();
            mfma_sweepNS(acc, a0, sW, ch, lq * 8, lm);
            mfma_sweepNS(acc, a1, sW, ch, 32 + lq * 8, lm);
            ws = wsn;
        }
    }
    bar_lgkm();
    parkNS(acc, b1, sH, g16, ch, lm, lq);
    bar_lgkm();

    // -------- layer 2: K=128, 2 chunks of 64 --------
#pragma unroll
    for (int i = 0; i < 4; ++i) acc[i] = (f32x4)(0.f);
    {
        WStage64 ws, wsn;
        wload64(ws, Wt2, 128, 0, tid);
#pragma unroll
        for (int c = 0; c < 2; ++c) {
            if (c == 0) wload64(wsn, Wt2, 128, 64, tid);
            bf16x8 a0 = *(const bf16x8*)&sH[(g16 + lm) * SH_STRIDE + c * 64 + lq * 8];
            bf16x8 a1 = *(const bf16x8*)&sH[(g16 + lm) * SH_STRIDE + c * 64 + 32 + lq * 8];
            bar_lgkm();
            wstore64(ws, sW, tid);
            bar_lgkm();
            mfma_sweepNS(acc, a0, sW, ch, lq * 8, lm);
            mfma_sweepNS(acc, a1, sW, ch, 32 + lq * 8, lm);
            ws = wsn;
        }
    }

    // -------- epilogue: LN with cross-wave partial exchange --------
    float g_[4], be_[4], b2_[4];
#pragma unroll
    for (int i = 0; i < 4; ++i) {
        int ct = ch * 4 + i;
        g_[i] = g[ct * 16 + lm]; be_[i] = be[ct * 16 + lm]; b2_[i] = b2[ct * 16 + lm];
    }
    float v[4][4], mu[4], rs_[4];
#pragma unroll
    for (int reg = 0; reg < 4; ++reg) {
        float s = 0.f;
#pragma unroll
        for (int i = 0; i < 4; ++i) { v[i][reg] = acc[i][reg] + b2_[i]; s += v[i][reg]; }
        s += __shfl_xor(s, 1); s += __shfl_xor(s, 2);
        s += __shfl_xor(s, 4); s += __shfl_xor(s, 8);
        if (lm == 0) sX[ch * 32 + g16 + lq * 4 + reg] = s;
    }
    bar_lgkm();
#pragma unroll
    for (int reg = 0; reg < 4; ++reg)
        mu[reg] = (sX[g16 + lq * 4 + reg] + sX[32 + g16 + lq * 4 + reg]) * (1.f / 128.f);
#pragma unroll
    for (int reg = 0; reg < 4; ++reg) {
        float q = 0.f;
#pragma unroll
        for (int i = 0; i < 4; ++i) { v[i][reg] -= mu[reg]; q += v[i][reg] * v[i][reg]; }
        q += __shfl_xor(q, 1); q += __shfl_xor(q, 2);
        q += __shfl_xor(q, 4); q += __shfl_xor(q, 8);
        if (lm == 0) sY[ch * 32 + g16 + lq * 4 + reg] = q;
    }
    bar_lgkm();
#pragma unroll
    for (int reg = 0; reg < 4; ++reg)
        rs_[reg] = rsqrtf((sY[g16 + lq * 4 + reg] + sY[32 + g16 + lq * 4 + reg]) * (1.f / 128.f) + 1e-5f);

    if (MODE == 4) {
        // fused: park ns = nf + o (bf16 — identical bits to old nfbf) into sH
#pragma unroll
        for (int reg = 0; reg < 4; ++reg) {
            int row = m0 + g16 + lq * 4 + reg;
#pragma unroll
            for (int i = 0; i < 4; ++i) {
                float o = v[i][reg] * rs_[reg] * g_[i] + be_[i];
                size_t gi = (size_t)row * 128 + (size_t)(ch * 4 + i) * 16 + lm;
                float ns = outF[gi] + o;
                sH[(g16 + lq * 4 + reg) * SH_STRIDE + (ch * 4 + i) * 16 + lm] = (short)f2bf(ns);
            }
        }
        bar_lgkm();    // parked ns visible to both col-half waves

        // ---- dec L0: K=128 from sH, W=Wd0, bias db0 ----
#pragma unroll
        for (int i = 0; i < 4; ++i) acc[i] = (f32x4)(0.f);
        {
            WStage64 ws, wsn;
            wload64(ws, Wd0, 128, 0, tid);
#pragma unroll
            for (int c = 0; c < 2; ++c) {
                if (c == 0) wload64(wsn, Wd0, 128, 64, tid);
                bf16x8 a0 = *(const bf16x8*)&sH[(g16 + lm) * SH_STRIDE + c * 64 + lq * 8];
                bf16x8 a1 = *(const bf16x8*)&sH[(g16 + lm) * SH_STRIDE + c * 64 + 32 + lq * 8];
                bar_lgkm();
                wstore64(ws, sW, tid);
                bar_lgkm();
                mfma_sweepNS(acc, a0, sW, ch, lq * 8, lm);
                mfma_sweepNS(acc, a1, sW, ch, 32 + lq * 8, lm);
                ws = wsn;
            }
        }
        bar_lgkm();
        parkNS(acc, db0, sH, g16, ch, lm, lq);
        bar_lgkm();

        // ---- dec L1: W=Wd1, bias db1 ----
#pragma unroll
        for (int i = 0; i < 4; ++i) acc[i] = (f32x4)(0.f);
        {
            WStage64 ws, wsn;
            wload64(ws, Wd1, 128, 0, tid);
#pragma unroll
            for (int c = 0; c < 2; ++c) {
                if (c == 0) wload64(wsn, Wd1, 128, 64, tid);
                bf16x8 a0 = *(const bf16x8*)&sH[(g16 + lm) * SH_STRIDE + c * 64 + lq * 8];
                bf16x8 a1 = *(const bf16x8*)&sH[(g16 + lm) * SH_STRIDE + c * 64 + 32 + lq * 8];
                bar_lgkm();
                wstore64(ws, sW, tid);
                bar_lgkm();
                mfma_sweepNS(acc, a0, sW, ch, lq * 8, lm);
                mfma_sweepNS(acc, a1, sW, ch, 32 + lq * 8, lm);
                ws = wsn;
            }
        }
        bar_lgkm();
        parkNS(acc, db1, sH, g16, ch, lm, lq);
        bar_lgkm();

        // ---- dec tail: 128 -> 3, fp32 weights dW2f ----
        if (tid < 96) {
            int r = tid / 3, o = tid - r * 3;
            int row = m0 + r;
            if (row < M) {
                float s = db2[o];
#pragma unroll
                for (int kk = 0; kk < 16; ++kk) {
                    bf16x8 h8 = *(const bf16x8*)&sH[r * SH_STRIDE + kk * 8];
#pragma unroll
                    for (int j = 0; j < 8; ++j)
                        s += bf2f(h8[j]) * dW2f[(kk * 8 + j) * 3 + o];
                }
                decOut[(size_t)row * 3 + o] = s;
            }
        }
        return;
    }

    // MODE 0 / MODE 2: write out
#pragma unroll
    for (int reg = 0; reg < 4; ++reg) {
        int row = m0 + g16 + lq * 4 + reg;
        if (row < M) {
#pragma unroll
            for (int i = 0; i < 4; ++i) {
                float o = v[i][reg] * rs_[reg] * g_[i] + be_[i];
                size_t gi = (size_t)row * 128 + (size_t)(ch * 4 + i) * 16 + lm;
                if (resid) {
                    float ns = outF[gi] + o;
                    outF[gi] = ns;
                    if (outB) outB[gi] = (short)f2bf(ns);
                } else {
                    outF[gi] = o;
                    if (outB) outB[gi] = (short)f2bf(o);
                }
            }
        }
    }
}

// ---------------------------------------------------------------------------
// Edge-encoder body (device fn): 256 threads, 4 waves x 32 rows, K0=7 staged
// to 32, bf16 ef write. LDS layout: sH 34816 B | sW 14336 B = 49152 B.
// ---------------------------------------------------------------------------
__device__ __forceinline__ void ence_body(char* smem, int bid,
    const short* __restrict__ Wt0, const short* __restrict__ Wt1, const short* __restrict__ Wt2,
    const float* __restrict__ b0, const float* __restrict__ b1, const float* __restrict__ b2,
    const float* __restrict__ g, const float* __restrict__ be,
    const float* __restrict__ A0f, int K0,
    const int* __restrict__ eList,
    short* __restrict__ outB, int M)
{
    short* sH = (short*)smem;                 // 4*32*SH_STRIDE
    short* sW = (short*)(smem + 34816);       // 128*SW_STRIDE
    const int tid = threadIdx.x;
    const int lane = tid & 63;
    const int w = tid >> 6;
    const int lm = lane & 15;
    const int lq = lane >> 4;
    const int w32 = w * 32;
    const int m0 = bid * 128;

    f32x4 acc[2][8];
    zero_acc(acc);

    // -------- layer 0: stage input (K0 -> 32) + single 32-k chunk --------
#pragma unroll
    for (int i = 0; i < 16; ++i) {
        int flat = lane + i * 64;
        int r = flat >> 5, k = flat & 31;
        int row = m0 + w32 + r;
        float v = 0.f;
        if (k < K0 && row < M) {
            int src = eList ? eList[row] : row;
            v = A0f[(size_t)src * K0 + k];
        }
        sH[(w32 + r) * SH_STRIDE + k] = (short)f2bf(v);
    }
    {
        WStageE ws;
        wloadE(ws, Wt0, 32, 0, tid);
        bf16x8 a0 = *(const bf16x8*)&sH[(w32 + lm) * SH_STRIDE + lq * 8];
        bf16x8 a1 = *(const bf16x8*)&sH[(w32 + 16 + lm) * SH_STRIDE + lq * 8];
        bar_lgkm();
        wstoreE(ws, sW, tid);
        bar_lgkm();
        mfma_sweep_lds(acc, a0, a1, sW, lm, lq);
    }
    bar_lgkm();
    park(acc, b0, sH, w32, lm, lq);

    // -------- layer 1 --------
    zero_acc(acc);
    {
        WStageE ws, wsn;
        wloadE(ws, Wt1, 128, 0, tid);
#pragma unroll
        for (int c = 0; c < 4; ++c) {
            if (c + 1 < 4) wloadE(wsn, Wt1, 128, (c + 1) * 32, tid);
            bf16x8 a0 = *(const bf16x8*)&sH[(w32 + lm) * SH_STRIDE + c * 32 + lq * 8];
            bf16x8 a1 = *(const bf16x8*)&sH[(w32 + 16 + lm) * SH_STRIDE + c * 32 + lq * 8];
            bar_lgkm();
            wstoreE(ws, sW, tid);
            bar_lgkm();
            mfma_sweep_lds(acc, a0, a1, sW, lm, lq);
            ws = wsn;
        }
    }
    bar_lgkm();
    park(acc, b1, sH, w32, lm, lq);

    // -------- layer 2 --------
    zero_acc(acc);
    {
        WStageE ws, wsn;
        wloadE(ws, Wt2, 128, 0, tid);
#pragma unroll
        for (int c = 0; c < 4; ++c) {
            if (c + 1 < 4) wloadE(wsn, Wt2, 128, (c + 1) * 32, tid);
            bf16x8 a0 = *(const bf16x8*)&sH[(w32 + lm) * SH_STRIDE + c * 32 + lq * 8];
            bf16x8 a1 = *(const bf16x8*)&sH[(w32 + 16 + lm) * SH_STRIDE + c * 32 + lq * 8];
            bar_lgkm();
            wstoreE(ws, sW, tid);
            bar_lgkm();
            mfma_sweep_lds(acc, a0, a1, sW, lm, lq);
            ws = wsn;
        }
    }

    // -------- epilogue: LN + bf16 write --------
    float g_[8], be_[8], b2_[8];
#pragma unroll
    for (int ct = 0; ct < 8; ++ct) {
        g_[ct] = g[ct * 16 + lm]; be_[ct] = be[ct * 16 + lm]; b2_[ct] = b2[ct * 16 + lm];
    }
#pragma unroll
    for (int rt = 0; rt < 2; ++rt) {
#pragma unroll
        for (int reg = 0; reg < 4; ++reg) {
            int row = m0 + w32 + rt * 16 + lq * 4 + reg;
            float vv[8];
            float s = 0.f;
#pragma unroll
            for (int ct = 0; ct < 8; ++ct) { vv[ct] = acc[rt][ct][reg] + b2_[ct]; s += vv[ct]; }
            s += __shfl_xor(s, 1); s += __shfl_xor(s, 2);
            s += __shfl_xor(s, 4); s += __shfl_xor(s, 8);
            float mu = s * (1.f / 128.f);
            float q = 0.f;
#pragma unroll
            for (int ct = 0; ct < 8; ++ct) { vv[ct] -= mu; q += vv[ct] * vv[ct]; }
            q += __shfl_xor(q, 1); q += __shfl_xor(q, 2);
            q += __shfl_xor(q, 4); q += __shfl_xor(q, 8);
            float rs = rsqrtf(q * (1.f / 128.f) + 1e-5f);
            if (row < M) {
#pragma unroll
                for (int ct = 0; ct < 8; ++ct) {
                    float o = vv[ct] * rs * g_[ct] + be_[ct];
                    outB[(size_t)row * 128 + ct * 16 + lm] = (short)f2bf(o);
                }
            }
        }
    }
}

// ---------------------------------------------------------------------------
// SEPARATE encoder launches (round-8 merge reverted: concatenated-grid
// co-scheduling gave ~serial-sum time and hurt enc_n occupancy).
// ---------------------------------------------------------------------------
__global__ __launch_bounds__(256) void gnn_enc_n(
    const short* __restrict__ W0, const short* __restrict__ W1, const short* __restrict__ W2,
    const float* __restrict__ b0, const float* __restrict__ b1, const float* __restrict__ b2,
    const float* __restrict__ g, const float* __restrict__ be,
    const float* __restrict__ node_x, int K0,
    float* __restrict__ nf, short* __restrict__ nfbf, int M)
{
    __shared__ __align__(16) char smem[27648];
    ns_body<0>(smem, blockIdx.x, W0, W1, W2, b0, b1, b2, g, be,
               node_x, K0, nullptr, nullptr, nf, nfbf, nullptr, nullptr,
               nullptr, nullptr, nullptr, nullptr, nullptr, nullptr, M, 0);
}

__global__ __launch_bounds__(256) void gnn_enc_e(
    const short* __restrict__ W0, const short* __restrict__ W1, const short* __restrict__ W2,
    const float* __restrict__ b0, const float* __restrict__ b1, const float* __restrict__ b2,
    const float* __restrict__ g, const float* __restrict__ be,
    const float* __restrict__ edge_x, int K0,
    const int* __restrict__ eList, short* __restrict__ efB, int M)
{
    __shared__ __align__(16) char smem[49152];
    ence_body(smem, blockIdx.x, W0, W1, W2, b0, b1, b2, g, be,
              edge_x, K0, eList, efB, M);
}

__global__ __launch_bounds__(256) void gnn_nodeNS(
    const short* __restrict__ Wt0, const short* __restrict__ Wt1, const short* __restrict__ Wt2,
    const float* __restrict__ b0, const float* __restrict__ b1, const float* __restrict__ b2,
    const float* __restrict__ g, const float* __restrict__ be,
    const short* __restrict__ nfb, const float* __restrict__ aggf,
    float* __restrict__ outF, short* __restrict__ outB, float* __restrict__ aggOut, int M)
{
    __shared__ __align__(16) char smem[27648];
    ns_body<2>(smem, blockIdx.x, Wt0, Wt1, Wt2, b0, b1, b2, g, be,
               nullptr, 0, nfb, aggf, outF, outB, aggOut, nullptr,
               nullptr, nullptr, nullptr, nullptr, nullptr, nullptr, M, 1);
}

__global__ __launch_bounds__(256) void gnn_node_dec(
    const short* __restrict__ Wt0, const short* __restrict__ Wt1, const short* __restrict__ Wt2,
    const float* __restrict__ b0, const float* __restrict__ b1, const float* __restrict__ b2,
    const float* __restrict__ g, const float* __restrict__ be,
    const short* __restrict__ nfb, const float* __restrict__ aggf,
    float* __restrict__ nfF,
    const short* __restrict__ Wd0, const short* __restrict__ Wd1,
    const float* __restrict__ dW2f,
    const float* __restrict__ db0, const float* __restrict__ db1,
    const float* __restrict__ db2,
    float* __restrict__ decOut, int M)
{
    __shared__ __align__(16) char smem[27648];
    ns_body<4>(smem, blockIdx.x, Wt0, Wt1, Wt2, b0, b1, b2, g, be,
               nullptr, 0, nfb, aggf, nfF, nullptr, nullptr, decOut,
               Wd0, Wd1, dW2f, db0, db1, db2, M, 1);
}

// ---------------------------------------------------------------------------
__global__ void zero_i(int* __restrict__ p, int n)
{
    int i = blockIdx.x * 256 + threadIdx.x;
    if (i < n) p[i] = 0;
}
__global__ void csr_count(const int* __restrict__ recv, int* __restrict__ cnt, int E)
{
    int i = blockIdx.x * 256 + threadIdx.x;
    if (i < E) atomicAdd(&cnt[recv[i]], 1);
}
__global__ __launch_bounds__(256) void csr_scan(const int* __restrict__ cnt,
                                                int* __restrict__ cursor, int N)
{
    __shared__ int ssum[257];
    const int tid = threadIdx.x;
    const int per = (N + 255) / 256;
    const int lo = tid * per, hi = min(lo + per, N);
    int s = 0;
    for (int i = lo; i < hi; ++i) s += cnt[i];
    ssum[tid] = s;
    __syncthreads();
    if (tid == 0) {
        int run = 0;
        for (int i = 0; i < 256; ++i) { int t = ssum[i]; ssum[i] = run; run += t; }
        ssum[256] = run;
    }
    __syncthreads();
    int run = ssum[tid];
    for (int i = lo; i < hi; ++i) { int c = cnt[i]; cursor[i] = run; run += c; }
}
__global__ void csr_fill(const int* __restrict__ recv, int* __restrict__ cursor,
                         int* __restrict__ eList, int E)
{
    int i = blockIdx.x * 256 + threadIdx.x;
    if (i < E) {
        int pos = atomicAdd(&cursor[recv[i]], 1);
        eList[pos] = i;
    }
}

// ---------------------------------------------------------------------------
struct WtPrep { const float* src; int K; int Kpad; int dstOff; };
struct WtPrepAll { WtPrep m[26]; };

__global__ void wt_prep_kernel(WtPrepAll all, short* __restrict__ dst)
{
    const WtPrep p = all.m[blockIdx.y];
    int total = 128 * p.Kpad;
    int idx = blockIdx.x * 256 + threadIdx.x;
    if (idx >= total) return;
    int n = idx / p.Kpad, k = idx - n * p.Kpad;
    float v = (k < p.K) ? p.src[(size_t)k * 128 + n] : 0.f;
    dst[p.dstOff + idx] = (short)f2bf(v);
}

__global__ void zero_kernel(float4* __restrict__ p, long n4)
{
    long i = (long)blockIdx.x * blockDim.x + threadIdx.x;
    if (i < n4) p[i] = make_float4(0.f, 0.f, 0.f, 0.f);
}

// ---------------------------------------------------------------------------
extern "C" void kernel_launch(void* const* d_in, const int* in_sizes, int n_in,
                              void* d_out, int out_size, void* d_ws, size_t ws_size,
                              hipStream_t stream)
{
    const float* node_x   = (const float*)d_in[0];
    const float* edge_x   = (const float*)d_in[1];
    const float* enc_n_W0 = (const float*)d_in[2];
    const float* enc_n_b0 = (const float*)d_in[3];
    const float* enc_n_W1 = (const float*)d_in[4];
    const float* enc_n_b1 = (const float*)d_in[5];
    const float* enc_n_W2 = (const float*)d_in[6];
    const float* enc_n_b2 = (const float*)d_in[7];
    const float* enc_n_g  = (const float*)d_in[8];
    const float* enc_n_be = (const float*)d_in[9];
    const float* enc_e_W0 = (const float*)d_in[10];
    const float* enc_e_b0 = (const float*)d_in[11];
    const float* enc_e_W1 = (const float*)d_in[12];
    const float* enc_e_b1 = (const float*)d_in[13];
    const float* enc_e_W2 = (const float*)d_in[14];
    const float* enc_e_b2 = (const float*)d_in[15];
    const float* enc_e_g  = (const float*)d_in[16];
    const float* enc_e_be = (const float*)d_in[17];
    const float* gnb_e_W0 = (const float*)d_in[18];
    const float* gnb_e_b0 = (const float*)d_in[19];
    const float* gnb_e_W1 = (const float*)d_in[20];
    const float* gnb_e_b1 = (const float*)d_in[21];
    const float* gnb_e_W2 = (const float*)d_in[22];
    const float* gnb_e_b2 = (const float*)d_in[23];
    const float* gnb_e_g  = (const float*)d_in[24];
    const float* gnb_e_be = (const float*)d_in[25];
    const float* gnb_n_W0 = (const float*)d_in[26];
    const float* gnb_n_b0 = (const float*)d_in[27];
    const float* gnb_n_W1 = (const float*)d_in[28];
    const float* gnb_n_b1 = (const float*)d_in[29];
    const float* gnb_n_W2 = (const float*)d_in[30];
    const float* gnb_n_b2 = (const float*)d_in[31];
    const float* gnb_n_g  = (const float*)d_in[32];
    const float* gnb_n_be = (const float*)d_in[33];
    const float* dec_W0   = (const float*)d_in[34];
    const float* dec_b0   = (const float*)d_in[35];
    const float* dec_W1   = (const float*)d_in[36];
    const float* dec_b1   = (const float*)d_in[37];
    const float* dec_W2   = (const float*)d_in[38];
    const float* dec_b2   = (const float*)d_in[39];
    const int*   senders  = (const int*)d_in[40];
    const int*   receivers= (const int*)d_in[41];
    float* out = (float*)d_out;

    const int N = NN, E = EE;
    const int WT_TOTAL = (32 + 128 + 128 + 32 + 128 + 128 + 3 * (384 + 128 + 128 + 256 + 128 + 128)
                          + 128 + 128) * 128;

    // ---- workspace layout (efLo removed in round 6) ----
    float* nf   = (float*)d_ws;                      // N*128 f32
    float* agg  = nf + (size_t)N * 128;              // N*128 f32
    short* efHi = (short*)(agg + (size_t)N * 128);   // E*128 bf16 (slot order)
    short* nfbf = efHi + (size_t)E * 128;            // N*128 bf16
    short* wt   = nfbf + (size_t)N * 128;            // WT_TOTAL bf16
    int*   eList = (int*)(wt + WT_TOTAL);            // E ints
    size_t need_sorted = (size_t)((char*)(eList + E) - (char*)d_ws);
    int* cnt    = (int*)agg;                          // transient overlay on agg
    int* cursor = cnt + N;

    const bool useSorted = (ws_size >= need_sorted);
    const int* eL = useSorted ? eList : nullptr;

    WtPrepAll tbl;
    int nMat = 0, off = 0;
    int o_encn[3], o_ence[3], o_ge0[3], o_ge1[3], o_ge2[3], o_gn0[3], o_gn1[3], o_gn2[3], o_dec[2];
    auto add = [&](const float* src, int K, int Kpad) {
        tbl.m[nMat].src = src; tbl.m[nMat].K = K; tbl.m[nMat].Kpad = Kpad;
        tbl.m[nMat].dstOff = off;
        int r = off; off += 128 * Kpad; ++nMat; return r;
    };
    o_encn[0] = add(enc_n_W0, 12, 32);
    o_encn[1] = add(enc_n_W1, 128, 128);
    o_encn[2] = add(enc_n_W2, 128, 128);
    o_ence[0] = add(enc_e_W0, 7, 32);
    o_ence[1] = add(enc_e_W1, 128, 128);
    o_ence[2] = add(enc_e_W2, 128, 128);
    for (int s = 0; s < 3; ++s) {
        o_ge0[s] = add(gnb_e_W0 + (size_t)s * 384 * 128, 384, 384);
        o_ge1[s] = add(gnb_e_W1 + (size_t)s * 128 * 128, 128, 128);
        o_ge2[s] = add(gnb_e_W2 + (size_t)s * 128 * 128, 128, 128);
        o_gn0[s] = add(gnb_n_W0 + (size_t)s * 256 * 128, 256, 256);
        o_gn1[s] = add(gnb_n_W1 + (size_t)s * 128 * 128, 128, 128);
        o_gn2[s] = add(gnb_n_W2 + (size_t)s * 128 * 128, 128, 128);
    }
    o_dec[0] = add(dec_W0, 128, 128);
    o_dec[1] = add(dec_W1, 128, 128);

    wt_prep_kernel<<<dim3(192, 26), 256, 0, stream>>>(tbl, wt);

    if (useSorted) {
        zero_i<<<dim3((N + 255) / 256), 256, 0, stream>>>(cnt, N);
        csr_count<<<dim3((E + 255) / 256), 256, 0, stream>>>(receivers, cnt, E);
        csr_scan<<<dim3(1), 256, 0, stream>>>(cnt, cursor, N);
        csr_fill<<<dim3((E + 255) / 256), 256, 0, stream>>>(receivers, cursor, eList, E);
    }
    // zero agg once (after csr: cnt/cursor overlay agg); steps re-zero in node kernel
    zero_kernel<<<dim3((N * 32 + 255) / 256), 256, 0, stream>>>((float4*)agg, (long)N * 32);

    const dim3 gE(E / 128);                 // edge kernels: 1250 blocks x 256 thr
    const dim3 gNS(N / 32);                 // node kernels: 625 blocks x 256 thr

    // ---- encoders (separate dispatches; round-8 merge reverted) ----
    gnn_enc_n<<<gNS, 256, 0, stream>>>(
        wt + o_encn[0], wt + o_encn[1], wt + o_encn[2],
        enc_n_b0, enc_n_b1, enc_n_b2, enc_n_g, enc_n_be,
        node_x, 12, nf, nfbf, N);
    gnn_enc_e<<<gE, 256, 0, stream>>>(
        wt + o_ence[0], wt + o_ence[1], wt + o_ence[2],
        enc_e_b0, enc_e_b1, enc_e_b2, enc_e_g, enc_e_be,
        edge_x, 7, eL, efHi, E);

    // ---- 3 message-passing steps; node s=2 fused with decoder ----
    for (int s = 0; s < 3; ++s) {
        const float* eb0 = gnb_e_b0 + (size_t)s * 128;
        const float* eb1 = gnb_e_b1 + (size_t)s * 128;
        const float* eb2 = gnb_e_b2 + (size_t)s * 128;
        const float* eg  = gnb_e_g  + (size_t)s * 128;
        const float* ebe = gnb_e_be + (size_t)s * 128;
        const float* nb0 = gnb_n_b0 + (size_t)s * 128;
        const float* nb1 = gnb_n_b1 + (size_t)s * 128;
        const float* nb2 = gnb_n_b2 + (size_t)s * 128;
        const float* ng  = gnb_n_g  + (size_t)s * 128;
        const float* nbe = gnb_n_be + (size_t)s * 128;

        if (s < 2) {
            gnn_edge64<1><<<gE, 256, 0, stream>>>(wt + o_ge0[s], wt + o_ge1[s], wt + o_ge2[s],
                eb0, eb1, eb2, eg, ebe,
                nfbf, efHi, eL, senders, receivers, agg);
            gnn_nodeNS<<<gNS, 256, 0, stream>>>(wt + o_gn0[s], wt + o_gn1[s], wt + o_gn2[s],
                nb0, nb1, nb2, ng, nbe,
                nfbf, agg, nf, nfbf, agg, N);
        } else {
            gnn_edge64<0><<<gE, 256, 0, stream>>>(wt + o_ge0[s], wt + o_ge1[s], wt + o_ge2[s],
                eb0, eb1, eb2, eg, ebe,
                nfbf, efHi, eL, senders, receivers, agg);
            gnn_node_dec<<<gNS, 256, 0, stream>>>(wt + o_gn0[s], wt + o_gn1[s], wt + o_gn2[s],
                nb0, nb1, nb2, ng, nbe,
                nfbf, agg, nf,
                wt + o_dec[0], wt + o_dec[1], dec_W2,
                dec_b0, dec_b1, dec_b2,
                out, N);
        }
    }
}

// Round 10
// 519.244 us; speedup vs baseline: 1.1252x; 1.0146x over previous
//
#include <hip/hip_runtime.h>
#include <hip/hip_bf16.h>

#define NN 20000
#define EE 160000

typedef __attribute__((ext_vector_type(8))) short bf16x8;
typedef __attribute__((ext_vector_type(4))) float f32x4;

__device__ __forceinline__ unsigned short f2bf(float f) {
    unsigned int u = __float_as_uint(f);
    u += 0x7FFFu + ((u >> 16) & 1);   // RNE
    return (unsigned short)(u >> 16);
}
__device__ __forceinline__ float bf2f(short s) {
    return __uint_as_float(((unsigned int)(unsigned short)s) << 16);
}
__device__ __forceinline__ bf16x8 pack8(float4 a, float4 b) {
    bf16x8 r;
    r[0] = (short)f2bf(a.x); r[1] = (short)f2bf(a.y);
    r[2] = (short)f2bf(a.z); r[3] = (short)f2bf(a.w);
    r[4] = (short)f2bf(b.x); r[5] = (short)f2bf(b.y);
    r[6] = (short)f2bf(b.z); r[7] = (short)f2bf(b.w);
    return r;
}

#define SH_STRIDE 136
#define SW_STRIDE 56
// edge64 kernel strides (LDS = 33792 + 18432 + 1024 = 53248 B -> 3 blocks/CU)
#define SH64 132
#define SW64 72

// barrier that does NOT drain vmcnt (gathers stay in flight)
__device__ __forceinline__ void bar_lgkm() {
    asm volatile("s_waitcnt lgkmcnt(0)\n\ts_barrier" ::: "memory");
}

__device__ __forceinline__ void mfma_sweep_lds(f32x4 (&acc)[2][8], bf16x8 a0, bf16x8 a1,
                                               const short* sWb, int lm, int lq)
{
#pragma unroll
    for (int ct = 0; ct < 8; ++ct) {
        bf16x8 b = *(const bf16x8*)(sWb + (ct * 16 + lm) * SW_STRIDE + lq * 8);
        acc[0][ct] = __builtin_amdgcn_mfma_f32_16x16x32_bf16(a0, b, acc[0][ct], 0, 0, 0);
        acc[1][ct] = __builtin_amdgcn_mfma_f32_16x16x32_bf16(a1, b, acc[1][ct], 0, 0, 0);
    }
}

__device__ __forceinline__ void mfma_sweep64(f32x4 (&acc)[2][8], bf16x8 a0, bf16x8 a1,
                                             const short* sWb, int colOff, int lm)
{
#pragma unroll
    for (int ct = 0; ct < 8; ++ct) {
        bf16x8 b = *(const bf16x8*)(sWb + (ct * 16 + lm) * SW64 + colOff);
        acc[0][ct] = __builtin_amdgcn_mfma_f32_16x16x32_bf16(a0, b, acc[0][ct], 0, 0, 0);
        acc[1][ct] = __builtin_amdgcn_mfma_f32_16x16x32_bf16(a1, b, acc[1][ct], 0, 0, 0);
    }
}

// N-split sweep: one wave covers 4 col-tiles (ch selects which half of N=128)
__device__ __forceinline__ void mfma_sweepNS(f32x4 (&acc)[4], bf16x8 a,
                                             const short* sWb, int ch, int colOff, int lm)
{
#pragma unroll
    for (int i = 0; i < 4; ++i) {
        int ct = ch * 4 + i;
        bf16x8 b = *(const bf16x8*)(sWb + (ct * 16 + lm) * SW64 + colOff);
        acc[i] = __builtin_amdgcn_mfma_f32_16x16x32_bf16(a, b, acc[i], 0, 0, 0);
    }
}

// W-chunk pipeline (32-k chunks, enc_e): load regs early / ds_write later.
struct WStageE { bf16x8 v[2]; };
__device__ __forceinline__ void wloadE(WStageE& ws, const short* __restrict__ Wt,
                                       int Kpad, int k0, int tid)
{
    int r = tid >> 1, h = tid & 1;
    const short* src = Wt + (size_t)r * Kpad + k0 + h * 16;
    ws.v[0] = *(const bf16x8*)src;
    ws.v[1] = *(const bf16x8*)(src + 8);
}
__device__ __forceinline__ void wstoreE(const WStageE& ws, short* __restrict__ sW, int tid)
{
    int r = tid >> 1, h = tid & 1;
    short* dst = sW + r * SW_STRIDE + h * 16;
    *(bf16x8*)dst       = ws.v[0];
    *(bf16x8*)(dst + 8) = ws.v[1];
}

// 64-k W stage (NT=256): 128 rows x 64 k, 4 bf16x8/thread
struct WStage64 { bf16x8 v[4]; };
__device__ __forceinline__ void wload64(WStage64& ws, const short* __restrict__ Wt,
                                        int Kpad, int k0, int tid)
{
#pragma unroll
    for (int j = 0; j < 4; ++j) {
        int i = tid + j * 256;
        int r = i >> 3, h = i & 7;
        ws.v[j] = *(const bf16x8*)(Wt + (size_t)r * Kpad + k0 + h * 8);
    }
}
__device__ __forceinline__ void wstore64(const WStage64& ws, short* __restrict__ sW, int tid)
{
#pragma unroll
    for (int j = 0; j < 4; ++j) {
        int i = tid + j * 256;
        int r = i >> 3, h = i & 7;
        *(bf16x8*)(sW + r * SW64 + h * 8) = ws.v[j];
    }
}

__device__ __forceinline__ void zero_acc(f32x4 (&acc)[2][8]) {
#pragma unroll
    for (int i = 0; i < 2; ++i)
#pragma unroll
        for (int j = 0; j < 8; ++j) acc[i][j] = (f32x4)(0.f);
}

__device__ __forceinline__ void park(const f32x4 (&acc)[2][8], const float* __restrict__ bias,
                                     short* __restrict__ sH, int w32, int lm, int lq)
{
#pragma unroll
    for (int ct = 0; ct < 8; ++ct) {
        float bb = bias[ct * 16 + lm];
#pragma unroll
        for (int rt = 0; rt < 2; ++rt) {
            int rbase = w32 + rt * 16 + lq * 4;
#pragma unroll
            for (int reg = 0; reg < 4; ++reg) {
                float v = fmaxf(acc[rt][ct][reg] + bb, 0.f);
                sH[(rbase + reg) * SH_STRIDE + ct * 16 + lm] = (short)f2bf(v);
            }
        }
    }
}

// N-split park: 16 rows x 64 cols (this wave's half)
__device__ __forceinline__ void parkNS(const f32x4 (&acc)[4], const float* __restrict__ bias,
                                       short* __restrict__ sH, int g16, int ch, int lm, int lq)
{
#pragma unroll
    for (int i = 0; i < 4; ++i) {
        int ct = ch * 4 + i;
        float bb = bias[ct * 16 + lm];
#pragma unroll
        for (int reg = 0; reg < 4; ++reg) {
            float v = fmaxf(acc[i][reg] + bb, 0.f);
            sH[(g16 + lq * 4 + reg) * SH_STRIDE + ct * 16 + lm] = (short)f2bf(v);
        }
    }
}

__device__ __forceinline__ void park64(const f32x4 (&acc)[2][8], const float* __restrict__ bias,
                                       short* __restrict__ sH, int w32, int lm, int lq)
{
#pragma unroll
    for (int ct = 0; ct < 8; ++ct) {
        float bb = bias[ct * 16 + lm];
#pragma unroll
        for (int rt = 0; rt < 2; ++rt) {
            int rbase = w32 + rt * 16 + lq * 4;
#pragma unroll
            for (int reg = 0; reg < 4; ++reg) {
                float v = fmaxf(acc[rt][ct][reg] + bb, 0.f);
                sH[(rbase + reg) * SH64 + ct * 16 + lm] = (short)f2bf(v);
            }
        }
    }
}

// N-split 64-k fragment (node core): this lane's row, k [c*64, c*64+64).
struct FragNS {
    bf16x8 a0, a1;
    float4 f0, f1, f2, f3;
    int isF;
};
__device__ __forceinline__ void load_fragNS(FragNS& fr, int c,
    const short* __restrict__ nfb, const float* __restrict__ aggf, int r0m, int lq)
{
    fr.isF = 0;
    if (c >= 2) {
        const float* p = aggf + (size_t)r0m * 128 + (c - 2) * 64 + lq * 8;
        fr.f0 = *(const float4*)p;        fr.f1 = *(const float4*)(p + 4);
        fr.f2 = *(const float4*)(p + 32); fr.f3 = *(const float4*)(p + 36);
        fr.isF = 1;
    } else {
        const short* p = nfb + (size_t)r0m * 128 + c * 64 + lq * 8;
        fr.a0 = *(const bf16x8*)p;
        fr.a1 = *(const bf16x8*)(p + 32);
    }
}

// 64-k fragment (edge): [0]=r0 h0, [1]=r1 h0, [2]=r0 h1, [3]=r1 h1
struct Frag64 { bf16x8 a[4]; };

__device__ __forceinline__ void load_frag64(Frag64& fr, int c,
    const short* __restrict__ nfb, const short* __restrict__ efHi,
    int iS0, int iS1, int iR0, int iR1, size_t eO0, size_t eO1, int lq)
{
    int kb = (c & 1) * 64 + lq * 8;
    int seg = c >> 1;
    const short *base0, *base1;
    if (seg == 0)      { base0 = nfb + (size_t)iS0 * 128; base1 = nfb + (size_t)iS1 * 128; }
    else if (seg == 1) { base0 = nfb + (size_t)iR0 * 128; base1 = nfb + (size_t)iR1 * 128; }
    else               { base0 = efHi + eO0;              base1 = efHi + eO1; }
    fr.a[0] = *(const bf16x8*)(base0 + kb);
    fr.a[1] = *(const bf16x8*)(base1 + kb);
    fr.a[2] = *(const bf16x8*)(base0 + kb + 32);
    fr.a[3] = *(const bf16x8*)(base1 + kb + 32);
}

// ---------------------------------------------------------------------------
// Edge MLP kernel — UNCHANGED round-6 body (proven; latency floor ~71us).
// ef master is a single bf16 array. RESID=1: ef += new_ef (bf16 RMW).
// ---------------------------------------------------------------------------
template<int RESID>
__global__ __launch_bounds__(256) void gnn_edge64(
    const short* __restrict__ Wt0,
    const short* __restrict__ Wt1, const short* __restrict__ Wt2,
    const float* __restrict__ b0, const float* __restrict__ b1, const float* __restrict__ b2,
    const float* __restrict__ g, const float* __restrict__ be,
    const short* __restrict__ nfb,
    short* __restrict__ efHi,
    const int* __restrict__ eList,
    const int* __restrict__ senders, const int* __restrict__ receivers,
    float* __restrict__ aggOut)
{
    __shared__ short sH[128 * SH64];
    __shared__ short sW[128 * SW64];
    __shared__ int sRcv[128], sSnd[128];
    const int tid = threadIdx.x;
    const int lane = tid & 63;
    const int w = tid >> 6;
    const int lm = lane & 15;
    const int lq = lane >> 4;
    const int w32 = w * 32;
    const int m0 = blockIdx.x * 128;

    if (tid < 128) {
        int slot = m0 + tid;                       // grid exact: slot < E
        int e = eList ? eList[slot] : slot;
        sRcv[tid] = receivers[e];
        sSnd[tid] = senders[e];
    }
    bar_lgkm();

    f32x4 acc[2][8];
    zero_acc(acc);

    const int s0 = w32 + 2 * lm, s1 = s0 + 1;
    const int iS0 = sSnd[s0], iS1 = sSnd[s1];
    const int iR0 = sRcv[s0], iR1 = sRcv[s1];
    const size_t eO0 = (size_t)(m0 + s0) * 128;
    const size_t eO1 = (size_t)(m0 + s1) * 128;

    // -------- layer 0: K=384 in 6 chunks of 64 --------
    {
        WStage64 ws, wsn;
        Frag64 cur, nxt;
        wload64(ws, Wt0, 384, 0, tid);
        load_frag64(cur, 0, nfb, efHi, iS0, iS1, iR0, iR1, eO0, eO1, lq);
#pragma unroll
        for (int c = 0; c < 6; ++c) {
            if (c + 1 < 6) {
                wload64(wsn, Wt0, 384, (c + 1) * 64, tid);
                load_frag64(nxt, c + 1, nfb, efHi, iS0, iS1, iR0, iR1, eO0, eO1, lq);
            }
            bar_lgkm();
            wstore64(ws, sW, tid);
            bar_lgkm();
            mfma_sweep64(acc, cur.a[0], cur.a[1], sW, lq * 8, lm);
            mfma_sweep64(acc, cur.a[2], cur.a[3], sW, 32 + lq * 8, lm);
            ws = wsn; cur = nxt;
        }
    }
    bar_lgkm();
    park64(acc, b0, sH, w32, lm, lq);

    // -------- layer 1: 2 chunks of 64 --------
    zero_acc(acc);
    {
        WStage64 ws, wsn;
        wload64(ws, Wt1, 128, 0, tid);
#pragma unroll
        for (int c = 0; c < 2; ++c) {
            if (c == 0) wload64(wsn, Wt1, 128, 64, tid);
            bf16x8 a0h0 = *(const bf16x8*)&sH[(w32 + lm) * SH64 + c * 64 + lq * 8];
            bf16x8 a1h0 = *(const bf16x8*)&sH[(w32 + 16 + lm) * SH64 + c * 64 + lq * 8];
            bf16x8 a0h1 = *(const bf16x8*)&sH[(w32 + lm) * SH64 + c * 64 + 32 + lq * 8];
            bf16x8 a1h1 = *(const bf16x8*)&sH[(w32 + 16 + lm) * SH64 + c * 64 + 32 + lq * 8];
            bar_lgkm();
            wstore64(ws, sW, tid);
            bar_lgkm();
            mfma_sweep64(acc, a0h0, a1h0, sW, lq * 8, lm);
            mfma_sweep64(acc, a0h1, a1h1, sW, 32 + lq * 8, lm);
            ws = wsn;
        }
    }
    bar_lgkm();
    park64(acc, b1, sH, w32, lm, lq);

    // -------- layer 2: 2 chunks of 64 --------
    zero_acc(acc);
    {
        WStage64 ws, wsn;
        wload64(ws, Wt2, 128, 0, tid);
#pragma unroll
        for (int c = 0; c < 2; ++c) {
            if (c == 0) wload64(wsn, Wt2, 128, 64, tid);
            bf16x8 a0h0 = *(const bf16x8*)&sH[(w32 + lm) * SH64 + c * 64 + lq * 8];
            bf16x8 a1h0 = *(const bf16x8*)&sH[(w32 + 16 + lm) * SH64 + c * 64 + lq * 8];
            bf16x8 a0h1 = *(const bf16x8*)&sH[(w32 + lm) * SH64 + c * 64 + 32 + lq * 8];
            bf16x8 a1h1 = *(const bf16x8*)&sH[(w32 + 16 + lm) * SH64 + c * 64 + 32 + lq * 8];
            bar_lgkm();
            wstore64(ws, sW, tid);
            bar_lgkm();
            mfma_sweep64(acc, a0h0, a1h0, sW, lq * 8, lm);
            mfma_sweep64(acc, a0h1, a1h1, sW, 32 + lq * 8, lm);
            ws = wsn;
        }
    }

    // -------- epilogue: LN + (RESID ? bf16 ef RMW) + merged-run atomics
    float g_[8], be_[8], b2_[8];
#pragma unroll
    for (int ct = 0; ct < 8; ++ct) {
        g_[ct] = g[ct * 16 + lm]; be_[ct] = be[ct * 16 + lm]; b2_[ct] = b2[ct * 16 + lm];
    }
    float run[8];
    int curRcv = -1;
#pragma unroll
    for (int j = 0; j < 8; ++j) {
        int rt = j & 1, reg = j >> 1;
        int rloc = w32 + lq * 8 + j;
        float v[8];
        float s = 0.f;
#pragma unroll
        for (int ct = 0; ct < 8; ++ct) { v[ct] = acc[rt][ct][reg] + b2_[ct]; s += v[ct]; }
        s += __shfl_xor(s, 1); s += __shfl_xor(s, 2);
        s += __shfl_xor(s, 4); s += __shfl_xor(s, 8);
        float mu = s * (1.f / 128.f);
        float q = 0.f;
#pragma unroll
        for (int ct = 0; ct < 8; ++ct) { v[ct] -= mu; q += v[ct] * v[ct]; }
        q += __shfl_xor(q, 1); q += __shfl_xor(q, 2);
        q += __shfl_xor(q, 4); q += __shfl_xor(q, 8);
        float rs = rsqrtf(q * (1.f / 128.f) + 1e-5f);
        int rcv = sRcv[rloc];
        float o[8];
#pragma unroll
        for (int ct = 0; ct < 8; ++ct) {
            o[ct] = v[ct] * rs * g_[ct] + be_[ct];
            if (RESID) {
                size_t gi = (size_t)(m0 + rloc) * 128 + ct * 16 + lm;
                float x = bf2f(efHi[gi]) + o[ct];
                efHi[gi] = (short)f2bf(x);
            }
        }
        if (rcv != curRcv) {
            if (curRcv >= 0) {
#pragma unroll
                for (int ct = 0; ct < 8; ++ct)
                    atomicAdd(aggOut + (size_t)curRcv * 128 + ct * 16 + lm, run[ct]);
            }
            curRcv = rcv;
#pragma unroll
            for (int ct = 0; ct < 8; ++ct) run[ct] = o[ct];
        } else {
#pragma unroll
            for (int ct = 0; ct < 8; ++ct) run[ct] += o[ct];
        }
    }
    if (curRcv >= 0) {
#pragma unroll
        for (int ct = 0; ct < 8; ++ct)
            atomicAdd(aggOut + (size_t)curRcv * 128 + ct * 16 + lm, run[ct]);
    }
}

// ---------------------------------------------------------------------------
// N-split body. ROUND 10: nf fp32 master ELIMINATED — node features live
// only in nfbf (bf16), residual RMW done in bf16 (same treatment that worked
// for ef in round 6). MODE 0: enc_n (fresh write). MODE 2: node step
// (ns = bf16(nfb[row]) + o -> nfbf write + agg zero). MODE 4: node s=2 fused
// with decoder (ns parked to LDS only; writes just decOut).
// LDS layout: sH 8704 B | sW 18432 B | sX 256 B | sY 256 B = 27648 B.
// ---------------------------------------------------------------------------
template<int MODE>
__device__ __forceinline__ void ns_body(char* smem, int bid,
    const short* __restrict__ Wt0, const short* __restrict__ Wt1, const short* __restrict__ Wt2,
    const float* __restrict__ b0, const float* __restrict__ b1, const float* __restrict__ b2,
    const float* __restrict__ g, const float* __restrict__ be,
    const float* __restrict__ A0f, int K0,
    const short* __restrict__ nfb, const float* __restrict__ aggf,
    short* __restrict__ outB,
    float* __restrict__ aggOut, float* __restrict__ decOut,
    const short* __restrict__ Wd0, const short* __restrict__ Wd1,
    const float* __restrict__ dW2f,
    const float* __restrict__ db0, const float* __restrict__ db1,
    const float* __restrict__ db2,
    int M)
{
    short* sH = (short*)smem;                      // 32 * SH_STRIDE
    short* sW = (short*)(smem + 8704);             // 128 * SW64
    float* sX = (float*)(smem + 8704 + 18432);     // 64
    float* sY = sX + 64;                           // 64
    const int tid = threadIdx.x;
    const int lane = tid & 63;
    const int w = tid >> 6;
    const int gidx = w >> 1;
    const int ch = w & 1;
    const int lm = lane & 15;
    const int lq = lane >> 4;
    const int g16 = gidx * 16;
    const int m0 = bid * 32;
    const int r0m = min(m0 + g16 + lm, M - 1);

    f32x4 acc[4];
#pragma unroll
    for (int i = 0; i < 4; ++i) acc[i] = (f32x4)(0.f);

    // -------- layer 0 --------
    if (MODE == 0) {
#pragma unroll
        for (int i = 0; i < 4; ++i) {
            int flat = tid + i * 256;
            int r = flat >> 5, k = flat & 31;
            int row = m0 + r;
            float v = (k < K0 && row < M) ? A0f[(size_t)row * K0 + k] : 0.f;
            sH[r * SH_STRIDE + k] = (short)f2bf(v);
        }
        {
            const short* src = Wt0 + (size_t)(tid >> 1) * 32 + (tid & 1) * 16;
            bf16x8 w0 = *(const bf16x8*)src;
            bf16x8 w1 = *(const bf16x8*)(src + 8);
            bar_lgkm();
            short* dst = sW + (tid >> 1) * SW64 + (tid & 1) * 16;
            *(bf16x8*)dst       = w0;
            *(bf16x8*)(dst + 8) = w1;
            bar_lgkm();
        }
        bf16x8 a0 = *(const bf16x8*)&sH[(g16 + lm) * SH_STRIDE + lq * 8];
        mfma_sweepNS(acc, a0, sW, ch, lq * 8, lm);
    } else {
        // node core: K=256 in 4 chunks of 64 (nfbf bf16, then agg fp32)
        WStage64 ws, wsn;
        FragNS cur, nxt;
        wload64(ws, Wt0, 256, 0, tid);
        load_fragNS(cur, 0, nfb, aggf, r0m, lq);
#pragma unroll
        for (int c = 0; c < 4; ++c) {
            if (c + 1 < 4) {
                wload64(wsn, Wt0, 256, (c + 1) * 64, tid);
                load_fragNS(nxt, c + 1, nfb, aggf, r0m, lq);
            }
            bar_lgkm();
            wstore64(ws, sW, tid);
            bar_lgkm();
            bf16x8 u0, u1;
            if (cur.isF) { u0 = pack8(cur.f0, cur.f1); u1 = pack8(cur.f2, cur.f3); }
            else         { u0 = cur.a0;                u1 = cur.a1; }
            mfma_sweepNS(acc, u0, sW, ch, lq * 8, lm);
            mfma_sweepNS(acc, u1, sW, ch, 32 + lq * 8, lm);
            ws = wsn; cur = nxt;
        }
    }
    bar_lgkm();
    parkNS(acc, b0, sH, g16, ch, lm, lq);
    bar_lgkm();

    // node MODE 2: zero this block's agg rows (all reads consumed above)
    if (MODE == 2 && aggOut) {
#pragma unroll
        for (int i = 0; i < 4; ++i) {
            int idx = tid + i * 256;
            int r = idx >> 5, c4 = idx & 31;
            int row = m0 + r;
            if (row < M)
                *(float4*)(aggOut + (size_t)row * 128 + c4 * 4) = make_float4(0.f, 0.f, 0.f, 0.f);
        }
    }

    // -------- layer 1: K=128, 2 chunks of 64 --------
#pragma unroll
    for (int i = 0; i < 4; ++i) acc[i] = (f32x4)(0.f);
    {
        WStage64 ws, wsn;
        wload64(ws, Wt1, 128, 0, tid);
#pragma unroll
        for (int c = 0; c < 2; ++c) {
            if (c == 0) wload64(wsn, Wt1, 128, 64, tid);
            bf16x8 a0 = *(const bf16x8*)&sH[(g16 + lm) * SH_STRIDE + c * 64 + lq * 8];
            bf16x8 a1 = *(const bf16x8*)&sH[(g16 + lm) * SH_STRIDE + c * 64 + 32 + lq * 8];
            bar_lgkm();
            wstore64(ws, sW, tid);
            bar_lgkm();
            mfma_sweepNS(acc, a0, sW, ch, lq * 8, lm);
            mfma_sweepNS(acc, a1, sW, ch, 32 + lq * 8, lm);
            ws = wsn;
        }
    }
    bar_lgkm();
    parkNS(acc, b1, sH, g16, ch, lm, lq);
    bar_lgkm();

    // -------- layer 2: K=128, 2 chunks of 64 --------
#pragma unroll
    for (int i = 0; i < 4; ++i) acc[i] = (f32x4)(0.f);
    {
        WStage64 ws, wsn;
        wload64(ws, Wt2, 128, 0, tid);
#pragma unroll
        for (int c = 0; c < 2; ++c) {
            if (c == 0) wload64(wsn, Wt2, 128, 64, tid);
            bf16x8 a0 = *(const bf16x8*)&sH[(g16 + lm) * SH_STRIDE + c * 64 + lq * 8];
            bf16x8 a1 = *(const bf16x8*)&sH[(g16 + lm) * SH_STRIDE + c * 64 + 32 + lq * 8];
            bar_lgkm();
            wstore64(ws, sW, tid);
            bar_lgkm();
            mfma_sweepNS(acc, a0, sW, ch, lq * 8, lm);
            mfma_sweepNS(acc, a1, sW, ch, 32 + lq * 8, lm);
            ws = wsn;
        }
    }

    // -------- epilogue: LN with cross-wave partial exchange --------
    float g_[4], be_[4], b2_[4];
#pragma unroll
    for (int i = 0; i < 4; ++i) {
        int ct = ch * 4 + i;
        g_[i] = g[ct * 16 + lm]; be_[i] = be[ct * 16 + lm]; b2_[i] = b2[ct * 16 + lm];
    }
    float v[4][4], mu[4], rs_[4];
#pragma unroll
    for (int reg = 0; reg < 4; ++reg) {
        float s = 0.f;
#pragma unroll
        for (int i = 0; i < 4; ++i) { v[i][reg] = acc[i][reg] + b2_[i]; s += v[i][reg]; }
        s += __shfl_xor(s, 1); s += __shfl_xor(s, 2);
        s += __shfl_xor(s, 4); s += __shfl_xor(s, 8);
        if (lm == 0) sX[ch * 32 + g16 + lq * 4 + reg] = s;
    }
    bar_lgkm();
#pragma unroll
    for (int reg = 0; reg < 4; ++reg)
        mu[reg] = (sX[g16 + lq * 4 + reg] + sX[32 + g16 + lq * 4 + reg]) * (1.f / 128.f);
#pragma unroll
    for (int reg = 0; reg < 4; ++reg) {
        float q = 0.f;
#pragma unroll
        for (int i = 0; i < 4; ++i) { v[i][reg] -= mu[reg]; q += v[i][reg] * v[i][reg]; }
        q += __shfl_xor(q, 1); q += __shfl_xor(q, 2);
        q += __shfl_xor(q, 4); q += __shfl_xor(q, 8);
        if (lm == 0) sY[ch * 32 + g16 + lq * 4 + reg] = q;
    }
    bar_lgkm();
#pragma unroll
    for (int reg = 0; reg < 4; ++reg)
        rs_[reg] = rsqrtf((sY[g16 + lq * 4 + reg] + sY[32 + g16 + lq * 4 + reg]) * (1.f / 128.f) + 1e-5f);

    if (MODE == 4) {
        // fused: ns = bf16(nfb[row]) + o, parked bf16 into sH (LDS only)
#pragma unroll
        for (int reg = 0; reg < 4; ++reg) {
            int row = m0 + g16 + lq * 4 + reg;
#pragma unroll
            for (int i = 0; i < 4; ++i) {
                float o = v[i][reg] * rs_[reg] * g_[i] + be_[i];
                size_t gi = (size_t)row * 128 + (size_t)(ch * 4 + i) * 16 + lm;
                float ns = bf2f(nfb[gi]) + o;
                sH[(g16 + lq * 4 + reg) * SH_STRIDE + (ch * 4 + i) * 16 + lm] = (short)f2bf(ns);
            }
        }
        bar_lgkm();    // parked ns visible to both col-half waves

        // ---- dec L0: K=128 from sH, W=Wd0, bias db0 ----
#pragma unroll
        for (int i = 0; i < 4; ++i) acc[i] = (f32x4)(0.f);
        {
            WStage64 ws, wsn;
            wload64(ws, Wd0, 128, 0, tid);
#pragma unroll
            for (int c = 0; c < 2; ++c) {
                if (c == 0) wload64(wsn, Wd0, 128, 64, tid);
                bf16x8 a0 = *(const bf16x8*)&sH[(g16 + lm) * SH_STRIDE + c * 64 + lq * 8];
                bf16x8 a1 = *(const bf16x8*)&sH[(g16 + lm) * SH_STRIDE + c * 64 + 32 + lq * 8];
                bar_lgkm();
                wstore64(ws, sW, tid);
                bar_lgkm();
                mfma_sweepNS(acc, a0, sW, ch, lq * 8, lm);
                mfma_sweepNS(acc, a1, sW, ch, 32 + lq * 8, lm);
                ws = wsn;
            }
        }
        bar_lgkm();
        parkNS(acc, db0, sH, g16, ch, lm, lq);
        bar_lgkm();

        // ---- dec L1: W=Wd1, bias db1 ----
#pragma unroll
        for (int i = 0; i < 4; ++i) acc[i] = (f32x4)(0.f);
        {
            WStage64 ws, wsn;
            wload64(ws, Wd1, 128, 0, tid);
#pragma unroll
            for (int c = 0; c < 2; ++c) {
                if (c == 0) wload64(wsn, Wd1, 128, 64, tid);
                bf16x8 a0 = *(const bf16x8*)&sH[(g16 + lm) * SH_STRIDE + c * 64 + lq * 8];
                bf16x8 a1 = *(const bf16x8*)&sH[(g16 + lm) * SH_STRIDE + c * 64 + 32 + lq * 8];
                bar_lgkm();
                wstore64(ws, sW, tid);
                bar_lgkm();
                mfma_sweepNS(acc, a0, sW, ch, lq * 8, lm);
                mfma_sweepNS(acc, a1, sW, ch, 32 + lq * 8, lm);
                ws = wsn;
            }
        }
        bar_lgkm();
        parkNS(acc, db1, sH, g16, ch, lm, lq);
        bar_lgkm();

        // ---- dec tail: 128 -> 3, fp32 weights dW2f ----
        if (tid < 96) {
            int r = tid / 3, o = tid - r * 3;
            int row = m0 + r;
            if (row < M) {
                float s = db2[o];
#pragma unroll
                for (int kk = 0; kk < 16; ++kk) {
                    bf16x8 h8 = *(const bf16x8*)&sH[r * SH_STRIDE + kk * 8];
#pragma unroll
                    for (int j = 0; j < 8; ++j)
                        s += bf2f(h8[j]) * dW2f[(kk * 8 + j) * 3 + o];
                }
                decOut[(size_t)row * 3 + o] = s;
            }
        }
        return;
    }

    // MODE 0: fresh bf16 write. MODE 2: bf16 residual RMW (own rows only —
    // the A-frag reads of nfb for this block's rows all happened in layer 0).
#pragma unroll
    for (int reg = 0; reg < 4; ++reg) {
        int row = m0 + g16 + lq * 4 + reg;
        if (row < M) {
#pragma unroll
            for (int i = 0; i < 4; ++i) {
                float o = v[i][reg] * rs_[reg] * g_[i] + be_[i];
                size_t gi = (size_t)row * 128 + (size_t)(ch * 4 + i) * 16 + lm;
                if (MODE == 2) {
                    float ns = bf2f(nfb[gi]) + o;
                    outB[gi] = (short)f2bf(ns);
                } else {
                    outB[gi] = (short)f2bf(o);
                }
            }
        }
    }
}

// ---------------------------------------------------------------------------
// Edge-encoder body (device fn): 256 threads, 4 waves x 32 rows, K0=7 staged
// to 32, bf16 ef write. LDS layout: sH 34816 B | sW 14336 B = 49152 B.
// ---------------------------------------------------------------------------
__device__ __forceinline__ void ence_body(char* smem, int bid,
    const short* __restrict__ Wt0, const short* __restrict__ Wt1, const short* __restrict__ Wt2,
    const float* __restrict__ b0, const float* __restrict__ b1, const float* __restrict__ b2,
    const float* __restrict__ g, const float* __restrict__ be,
    const float* __restrict__ A0f, int K0,
    const int* __restrict__ eList,
    short* __restrict__ outB, int M)
{
    short* sH = (short*)smem;                 // 4*32*SH_STRIDE
    short* sW = (short*)(smem + 34816);       // 128*SW_STRIDE
    const int tid = threadIdx.x;
    const int lane = tid & 63;
    const int w = tid >> 6;
    const int lm = lane & 15;
    const int lq = lane >> 4;
    const int w32 = w * 32;
    const int m0 = bid * 128;

    f32x4 acc[2][8];
    zero_acc(acc);

    // -------- layer 0: stage input (K0 -> 32) + single 32-k chunk --------
#pragma unroll
    for (int i = 0; i < 16; ++i) {
        int flat = lane + i * 64;
        int r = flat >> 5, k = flat & 31;
        int row = m0 + w32 + r;
        float v = 0.f;
        if (k < K0 && row < M) {
            int src = eList ? eList[row] : row;
            v = A0f[(size_t)src * K0 + k];
        }
        sH[(w32 + r) * SH_STRIDE + k] = (short)f2bf(v);
    }
    {
        WStageE ws;
        wloadE(ws, Wt0, 32, 0, tid);
        bf16x8 a0 = *(const bf16x8*)&sH[(w32 + lm) * SH_STRIDE + lq * 8];
        bf16x8 a1 = *(const bf16x8*)&sH[(w32 + 16 + lm) * SH_STRIDE + lq * 8];
        bar_lgkm();
        wstoreE(ws, sW, tid);
        bar_lgkm();
        mfma_sweep_lds(acc, a0, a1, sW, lm, lq);
    }
    bar_lgkm();
    park(acc, b0, sH, w32, lm, lq);

    // -------- layer 1 --------
    zero_acc(acc);
    {
        WStageE ws, wsn;
        wloadE(ws, Wt1, 128, 0, tid);
#pragma unroll
        for (int c = 0; c < 4; ++c) {
            if (c + 1 < 4) wloadE(wsn, Wt1, 128, (c + 1) * 32, tid);
            bf16x8 a0 = *(const bf16x8*)&sH[(w32 + lm) * SH_STRIDE + c * 32 + lq * 8];
            bf16x8 a1 = *(const bf16x8*)&sH[(w32 + 16 + lm) * SH_STRIDE + c * 32 + lq * 8];
            bar_lgkm();
            wstoreE(ws, sW, tid);
            bar_lgkm();
            mfma_sweep_lds(acc, a0, a1, sW, lm, lq);
            ws = wsn;
        }
    }
    bar_lgkm();
    park(acc, b1, sH, w32, lm, lq);

    // -------- layer 2 --------
    zero_acc(acc);
    {
        WStageE ws, wsn;
        wloadE(ws, Wt2, 128, 0, tid);
#pragma unroll
        for (int c = 0; c < 4; ++c) {
            if (c + 1 < 4) wloadE(wsn, Wt2, 128, (c + 1) * 32, tid);
            bf16x8 a0 = *(const bf16x8*)&sH[(w32 + lm) * SH_STRIDE + c * 32 + lq * 8];
            bf16x8 a1 = *(const bf16x8*)&sH[(w32 + 16 + lm) * SH_STRIDE + c * 32 + lq * 8];
            bar_lgkm();
            wstoreE(ws, sW, tid);
            bar_lgkm();
            mfma_sweep_lds(acc, a0, a1, sW, lm, lq);
            ws = wsn;
        }
    }

    // -------- epilogue: LN + bf16 write --------
    float g_[8], be_[8], b2_[8];
#pragma unroll
    for (int ct = 0; ct < 8; ++ct) {
        g_[ct] = g[ct * 16 + lm]; be_[ct] = be[ct * 16 + lm]; b2_[ct] = b2[ct * 16 + lm];
    }
#pragma unroll
    for (int rt = 0; rt < 2; ++rt) {
#pragma unroll
        for (int reg = 0; reg < 4; ++reg) {
            int row = m0 + w32 + rt * 16 + lq * 4 + reg;
            float vv[8];
            float s = 0.f;
#pragma unroll
            for (int ct = 0; ct < 8; ++ct) { vv[ct] = acc[rt][ct][reg] + b2_[ct]; s += vv[ct]; }
            s += __shfl_xor(s, 1); s += __shfl_xor(s, 2);
            s += __shfl_xor(s, 4); s += __shfl_xor(s, 8);
            float mu = s * (1.f / 128.f);
            float q = 0.f;
#pragma unroll
            for (int ct = 0; ct < 8; ++ct) { vv[ct] -= mu; q += vv[ct] * vv[ct]; }
            q += __shfl_xor(q, 1); q += __shfl_xor(q, 2);
            q += __shfl_xor(q, 4); q += __shfl_xor(q, 8);
            float rs = rsqrtf(q * (1.f / 128.f) + 1e-5f);
            if (row < M) {
#pragma unroll
                for (int ct = 0; ct < 8; ++ct) {
                    float o = vv[ct] * rs * g_[ct] + be_[ct];
                    outB[(size_t)row * 128 + ct * 16 + lm] = (short)f2bf(o);
                }
            }
        }
    }
}

// ---------------------------------------------------------------------------
__global__ __launch_bounds__(256) void gnn_enc_n(
    const short* __restrict__ W0, const short* __restrict__ W1, const short* __restrict__ W2,
    const float* __restrict__ b0, const float* __restrict__ b1, const float* __restrict__ b2,
    const float* __restrict__ g, const float* __restrict__ be,
    const float* __restrict__ node_x, int K0,
    short* __restrict__ nfbf, int M)
{
    __shared__ __align__(16) char smem[27648];
    ns_body<0>(smem, blockIdx.x, W0, W1, W2, b0, b1, b2, g, be,
               node_x, K0, nullptr, nullptr, nfbf, nullptr, nullptr,
               nullptr, nullptr, nullptr, nullptr, nullptr, nullptr, M);
}

__global__ __launch_bounds__(256) void gnn_enc_e(
    const short* __restrict__ W0, const short* __restrict__ W1, const short* __restrict__ W2,
    const float* __restrict__ b0, const float* __restrict__ b1, const float* __restrict__ b2,
    const float* __restrict__ g, const float* __restrict__ be,
    const float* __restrict__ edge_x, int K0,
    const int* __restrict__ eList, short* __restrict__ efB, int M)
{
    __shared__ __align__(16) char smem[49152];
    ence_body(smem, blockIdx.x, W0, W1, W2, b0, b1, b2, g, be,
              edge_x, K0, eList, efB, M);
}

__global__ __launch_bounds__(256) void gnn_nodeNS(
    const short* __restrict__ Wt0, const short* __restrict__ Wt1, const short* __restrict__ Wt2,
    const float* __restrict__ b0, const float* __restrict__ b1, const float* __restrict__ b2,
    const float* __restrict__ g, const float* __restrict__ be,
    const short* __restrict__ nfb, const float* __restrict__ aggf,
    short* __restrict__ outB, float* __restrict__ aggOut, int M)
{
    __shared__ __align__(16) char smem[27648];
    ns_body<2>(smem, blockIdx.x, Wt0, Wt1, Wt2, b0, b1, b2, g, be,
               nullptr, 0, nfb, aggf, outB, aggOut, nullptr,
               nullptr, nullptr, nullptr, nullptr, nullptr, nullptr, M);
}

__global__ __launch_bounds__(256) void gnn_node_dec(
    const short* __restrict__ Wt0, const short* __restrict__ Wt1, const short* __restrict__ Wt2,
    const float* __restrict__ b0, const float* __restrict__ b1, const float* __restrict__ b2,
    const float* __restrict__ g, const float* __restrict__ be,
    const short* __restrict__ nfb, const float* __restrict__ aggf,
    const short* __restrict__ Wd0, const short* __restrict__ Wd1,
    const float* __restrict__ dW2f,
    const float* __restrict__ db0, const float* __restrict__ db1,
    const float* __restrict__ db2,
    float* __restrict__ decOut, int M)
{
    __shared__ __align__(16) char smem[27648];
    ns_body<4>(smem, blockIdx.x, Wt0, Wt1, Wt2, b0, b1, b2, g, be,
               nullptr, 0, nfb, aggf, nullptr, nullptr, decOut,
               Wd0, Wd1, dW2f, db0, db1, db2, M);
}

// ---------------------------------------------------------------------------
__global__ void zero_i(int* __restrict__ p, int n)
{
    int i = blockIdx.x * 256 + threadIdx.x;
    if (i < n) p[i] = 0;
}
__global__ void csr_count(const int* __restrict__ recv, int* __restrict__ cnt, int E)
{
    int i = blockIdx.x * 256 + threadIdx.x;
    if (i < E) atomicAdd(&cnt[recv[i]], 1);
}
__global__ __launch_bounds__(256) void csr_scan(const int* __restrict__ cnt,
                                                int* __restrict__ cursor, int N)
{
    __shared__ int ssum[257];
    const int tid = threadIdx.x;
    const int per = (N + 255) / 256;
    const int lo = tid * per, hi = min(lo + per, N);
    int s = 0;
    for (int i = lo; i < hi; ++i) s += cnt[i];
    ssum[tid] = s;
    __syncthreads();
    if (tid == 0) {
        int run = 0;
        for (int i = 0; i < 256; ++i) { int t = ssum[i]; ssum[i] = run; run += t; }
        ssum[256] = run;
    }
    __syncthreads();
    int run = ssum[tid];
    for (int i = lo; i < hi; ++i) { int c = cnt[i]; cursor[i] = run; run += c; }
}
__global__ void csr_fill(const int* __restrict__ recv, int* __restrict__ cursor,
                         int* __restrict__ eList, int E)
{
    int i = blockIdx.x * 256 + threadIdx.x;
    if (i < E) {
        int pos = atomicAdd(&cursor[recv[i]], 1);
        eList[pos] = i;
    }
}

// ---------------------------------------------------------------------------
struct WtPrep { const float* src; int K; int Kpad; int dstOff; };
struct WtPrepAll { WtPrep m[26]; };

__global__ void wt_prep_kernel(WtPrepAll all, short* __restrict__ dst)
{
    const WtPrep p = all.m[blockIdx.y];
    int total = 128 * p.Kpad;
    int idx = blockIdx.x * 256 + threadIdx.x;
    if (idx >= total) return;
    int n = idx / p.Kpad, k = idx - n * p.Kpad;
    float v = (k < p.K) ? p.src[(size_t)k * 128 + n] : 0.f;
    dst[p.dstOff + idx] = (short)f2bf(v);
}

__global__ void zero_kernel(float4* __restrict__ p, long n4)
{
    long i = (long)blockIdx.x * blockDim.x + threadIdx.x;
    if (i < n4) p[i] = make_float4(0.f, 0.f, 0.f, 0.f);
}

// ---------------------------------------------------------------------------
extern "C" void kernel_launch(void* const* d_in, const int* in_sizes, int n_in,
                              void* d_out, int out_size, void* d_ws, size_t ws_size,
                              hipStream_t stream)
{
    const float* node_x   = (const float*)d_in[0];
    const float* edge_x   = (const float*)d_in[1];
    const float* enc_n_W0 = (const float*)d_in[2];
    const float* enc_n_b0 = (const float*)d_in[3];
    const float* enc_n_W1 = (const float*)d_in[4];
    const float* enc_n_b1 = (const float*)d_in[5];
    const float* enc_n_W2 = (const float*)d_in[6];
    const float* enc_n_b2 = (const float*)d_in[7];
    const float* enc_n_g  = (const float*)d_in[8];
    const float* enc_n_be = (const float*)d_in[9];
    const float* enc_e_W0 = (const float*)d_in[10];
    const float* enc_e_b0 = (const float*)d_in[11];
    const float* enc_e_W1 = (const float*)d_in[12];
    const float* enc_e_b1 = (const float*)d_in[13];
    const float* enc_e_W2 = (const float*)d_in[14];
    const float* enc_e_b2 = (const float*)d_in[15];
    const float* enc_e_g  = (const float*)d_in[16];
    const float* enc_e_be = (const float*)d_in[17];
    const float* gnb_e_W0 = (const float*)d_in[18];
    const float* gnb_e_b0 = (const float*)d_in[19];
    const float* gnb_e_W1 = (const float*)d_in[20];
    const float* gnb_e_b1 = (const float*)d_in[21];
    const float* gnb_e_W2 = (const float*)d_in[22];
    const float* gnb_e_b2 = (const float*)d_in[23];
    const float* gnb_e_g  = (const float*)d_in[24];
    const float* gnb_e_be = (const float*)d_in[25];
    const float* gnb_n_W0 = (const float*)d_in[26];
    const float* gnb_n_b0 = (const float*)d_in[27];
    const float* gnb_n_W1 = (const float*)d_in[28];
    const float* gnb_n_b1 = (const float*)d_in[29];
    const float* gnb_n_W2 = (const float*)d_in[30];
    const float* gnb_n_b2 = (const float*)d_in[31];
    const float* gnb_n_g  = (const float*)d_in[32];
    const float* gnb_n_be = (const float*)d_in[33];
    const float* dec_W0   = (const float*)d_in[34];
    const float* dec_b0   = (const float*)d_in[35];
    const float* dec_W1   = (const float*)d_in[36];
    const float* dec_b1   = (const float*)d_in[37];
    const float* dec_W2   = (const float*)d_in[38];
    const float* dec_b2   = (const float*)d_in[39];
    const int*   senders  = (const int*)d_in[40];
    const int*   receivers= (const int*)d_in[41];
    float* out = (float*)d_out;

    const int N = NN, E = EE;
    const int WT_TOTAL = (32 + 128 + 128 + 32 + 128 + 128 + 3 * (384 + 128 + 128 + 256 + 128 + 128)
                          + 128 + 128) * 128;

    // ---- workspace layout: nf fp32 REMOVED (node master is bf16 nfbf) ----
    float* agg  = (float*)d_ws;                      // N*128 f32
    short* efHi = (short*)(agg + (size_t)N * 128);   // E*128 bf16 (slot order)
    short* nfbf = efHi + (size_t)E * 128;            // N*128 bf16
    short* wt   = nfbf + (size_t)N * 128;            // WT_TOTAL bf16
    int*   eList = (int*)(wt + WT_TOTAL);            // E ints
    size_t need_sorted = (size_t)((char*)(eList + E) - (char*)d_ws);
    int* cnt    = (int*)agg;                          // transient overlay on agg
    int* cursor = cnt + N;

    const bool useSorted = (ws_size >= need_sorted);
    const int* eL = useSorted ? eList : nullptr;

    WtPrepAll tbl;
    int nMat = 0, off = 0;
    int o_encn[3], o_ence[3], o_ge0[3], o_ge1[3], o_ge2[3], o_gn0[3], o_gn1[3], o_gn2[3], o_dec[2];
    auto add = [&](const float* src, int K, int Kpad) {
        tbl.m[nMat].src = src; tbl.m[nMat].K = K; tbl.m[nMat].Kpad = Kpad;
        tbl.m[nMat].dstOff = off;
        int r = off; off += 128 * Kpad; ++nMat; return r;
    };
    o_encn[0] = add(enc_n_W0, 12, 32);
    o_encn[1] = add(enc_n_W1, 128, 128);
    o_encn[2] = add(enc_n_W2, 128, 128);
    o_ence[0] = add(enc_e_W0, 7, 32);
    o_ence[1] = add(enc_e_W1, 128, 128);
    o_ence[2] = add(enc_e_W2, 128, 128);
    for (int s = 0; s < 3; ++s) {
        o_ge0[s] = add(gnb_e_W0 + (size_t)s * 384 * 128, 384, 384);
        o_ge1[s] = add(gnb_e_W1 + (size_t)s * 128 * 128, 128, 128);
        o_ge2[s] = add(gnb_e_W2 + (size_t)s * 128 * 128, 128, 128);
        o_gn0[s] = add(gnb_n_W0 + (size_t)s * 256 * 128, 256, 256);
        o_gn1[s] = add(gnb_n_W1 + (size_t)s * 128 * 128, 128, 128);
        o_gn2[s] = add(gnb_n_W2 + (size_t)s * 128 * 128, 128, 128);
    }
    o_dec[0] = add(dec_W0, 128, 128);
    o_dec[1] = add(dec_W1, 128, 128);

    wt_prep_kernel<<<dim3(192, 26), 256, 0, stream>>>(tbl, wt);

    if (useSorted) {
        zero_i<<<dim3((N + 255) / 256), 256, 0, stream>>>(cnt, N);
        csr_count<<<dim3((E + 255) / 256), 256, 0, stream>>>(receivers, cnt, E);
        csr_scan<<<dim3(1), 256, 0, stream>>>(cnt, cursor, N);
        csr_fill<<<dim3((E + 255) / 256), 256, 0, stream>>>(receivers, cursor, eList, E);
    }
    // zero agg once (after csr: cnt/cursor overlay agg); steps re-zero in node kernel
    zero_kernel<<<dim3((N * 32 + 255) / 256), 256, 0, stream>>>((float4*)agg, (long)N * 32);

    const dim3 gE(E / 128);                 // edge kernels: 1250 blocks x 256 thr
    const dim3 gNS(N / 32);                 // node kernels: 625 blocks x 256 thr

    // ---- encoders (separate dispatches) ----
    gnn_enc_n<<<gNS, 256, 0, stream>>>(
        wt + o_encn[0], wt + o_encn[1], wt + o_encn[2],
        enc_n_b0, enc_n_b1, enc_n_b2, enc_n_g, enc_n_be,
        node_x, 12, nfbf, N);
    gnn_enc_e<<<gE, 256, 0, stream>>>(
        wt + o_ence[0], wt + o_ence[1], wt + o_ence[2],
        enc_e_b0, enc_e_b1, enc_e_b2, enc_e_g, enc_e_be,
        edge_x, 7, eL, efHi, E);

    // ---- 3 message-passing steps; node s=2 fused with decoder ----
    for (int s = 0; s < 3; ++s) {
        const float* eb0 = gnb_e_b0 + (size_t)s * 128;
        const float* eb1 = gnb_e_b1 + (size_t)s * 128;
        const float* eb2 = gnb_e_b2 + (size_t)s * 128;
        const float* eg  = gnb_e_g  + (size_t)s * 128;
        const float* ebe = gnb_e_be + (size_t)s * 128;
        const float* nb0 = gnb_n_b0 + (size_t)s * 128;
        const float* nb1 = gnb_n_b1 + (size_t)s * 128;
        const float* nb2 = gnb_n_b2 + (size_t)s * 128;
        const float* ng  = gnb_n_g  + (size_t)s * 128;
        const float* nbe = gnb_n_be + (size_t)s * 128;

        if (s < 2) {
            gnn_edge64<1><<<gE, 256, 0, stream>>>(wt + o_ge0[s], wt + o_ge1[s], wt + o_ge2[s],
                eb0, eb1, eb2, eg, ebe,
                nfbf, efHi, eL, senders, receivers, agg);
            gnn_nodeNS<<<gNS, 256, 0, stream>>>(wt + o_gn0[s], wt + o_gn1[s], wt + o_gn2[s],
                nb0, nb1, nb2, ng, nbe,
                nfbf, agg, nfbf, agg, N);
        } else {
            gnn_edge64<0><<<gE, 256, 0, stream>>>(wt + o_ge0[s], wt + o_ge1[s], wt + o_ge2[s],
                eb0, eb1, eb2, eg, ebe,
                nfbf, efHi, eL, senders, receivers, agg);
            gnn_node_dec<<<gNS, 256, 0, stream>>>(wt + o_gn0[s], wt + o_gn1[s], wt + o_gn2[s],
                nb0, nb1, nb2, ng, nbe,
                nfbf, agg,
                wt + o_dec[0], wt + o_dec[1], dec_W2,
                dec_b0, dec_b1, dec_b2,
                out, N);
        }
    }
}

// Round 11
// 515.116 us; speedup vs baseline: 1.1342x; 1.0080x over previous
//
#include <hip/hip_runtime.h>
#include <hip/hip_bf16.h>

#define NN 20000
#define EE 160000

typedef __attribute__((ext_vector_type(8))) short bf16x8;
typedef __attribute__((ext_vector_type(4))) float f32x4;

__device__ __forceinline__ unsigned short f2bf(float f) {
    unsigned int u = __float_as_uint(f);
    u += 0x7FFFu + ((u >> 16) & 1);   // RNE
    return (unsigned short)(u >> 16);
}
__device__ __forceinline__ float bf2f(short s) {
    return __uint_as_float(((unsigned int)(unsigned short)s) << 16);
}
__device__ __forceinline__ bf16x8 pack8(float4 a, float4 b) {
    bf16x8 r;
    r[0] = (short)f2bf(a.x); r[1] = (short)f2bf(a.y);
    r[2] = (short)f2bf(a.z); r[3] = (short)f2bf(a.w);
    r[4] = (short)f2bf(b.x); r[5] = (short)f2bf(b.y);
    r[6] = (short)f2bf(b.z); r[7] = (short)f2bf(b.w);
    return r;
}

#define SH_STRIDE 136
#define SW_STRIDE 56
// edge64 kernel strides (LDS = 33792 + 18432 + 1024 = 53248 B -> 3 blocks/CU)
#define SH64 132
#define SW64 72

// barrier that does NOT drain vmcnt (gathers stay in flight)
__device__ __forceinline__ void bar_lgkm() {
    asm volatile("s_waitcnt lgkmcnt(0)\n\ts_barrier" ::: "memory");
}

__device__ __forceinline__ void mfma_sweep_lds(f32x4 (&acc)[2][8], bf16x8 a0, bf16x8 a1,
                                               const short* sWb, int lm, int lq)
{
#pragma unroll
    for (int ct = 0; ct < 8; ++ct) {
        bf16x8 b = *(const bf16x8*)(sWb + (ct * 16 + lm) * SW_STRIDE + lq * 8);
        acc[0][ct] = __builtin_amdgcn_mfma_f32_16x16x32_bf16(a0, b, acc[0][ct], 0, 0, 0);
        acc[1][ct] = __builtin_amdgcn_mfma_f32_16x16x32_bf16(a1, b, acc[1][ct], 0, 0, 0);
    }
}

__device__ __forceinline__ void mfma_sweep64(f32x4 (&acc)[2][8], bf16x8 a0, bf16x8 a1,
                                             const short* sWb, int colOff, int lm)
{
#pragma unroll
    for (int ct = 0; ct < 8; ++ct) {
        bf16x8 b = *(const bf16x8*)(sWb + (ct * 16 + lm) * SW64 + colOff);
        acc[0][ct] = __builtin_amdgcn_mfma_f32_16x16x32_bf16(a0, b, acc[0][ct], 0, 0, 0);
        acc[1][ct] = __builtin_amdgcn_mfma_f32_16x16x32_bf16(a1, b, acc[1][ct], 0, 0, 0);
    }
}

// N-split sweep: one wave covers 4 col-tiles (ch selects which half of N=128)
__device__ __forceinline__ void mfma_sweepNS(f32x4 (&acc)[4], bf16x8 a,
                                             const short* sWb, int ch, int colOff, int lm)
{
#pragma unroll
    for (int i = 0; i < 4; ++i) {
        int ct = ch * 4 + i;
        bf16x8 b = *(const bf16x8*)(sWb + (ct * 16 + lm) * SW64 + colOff);
        acc[i] = __builtin_amdgcn_mfma_f32_16x16x32_bf16(a, b, acc[i], 0, 0, 0);
    }
}

// W-chunk pipeline (32-k chunks, enc_e): load regs early / ds_write later.
struct WStageE { bf16x8 v[2]; };
__device__ __forceinline__ void wloadE(WStageE& ws, const short* __restrict__ Wt,
                                       int Kpad, int k0, int tid)
{
    int r = tid >> 1, h = tid & 1;
    const short* src = Wt + (size_t)r * Kpad + k0 + h * 16;
    ws.v[0] = *(const bf16x8*)src;
    ws.v[1] = *(const bf16x8*)(src + 8);
}
__device__ __forceinline__ void wstoreE(const WStageE& ws, short* __restrict__ sW, int tid)
{
    int r = tid >> 1, h = tid & 1;
    short* dst = sW + r * SW_STRIDE + h * 16;
    *(bf16x8*)dst       = ws.v[0];
    *(bf16x8*)(dst + 8) = ws.v[1];
}

// 64-k W stage (NT=256): 128 rows x 64 k, 4 bf16x8/thread
struct WStage64 { bf16x8 v[4]; };
__device__ __forceinline__ void wload64(WStage64& ws, const short* __restrict__ Wt,
                                        int Kpad, int k0, int tid)
{
#pragma unroll
    for (int j = 0; j < 4; ++j) {
        int i = tid + j * 256;
        int r = i >> 3, h = i & 7;
        ws.v[j] = *(const bf16x8*)(Wt + (size_t)r * Kpad + k0 + h * 8);
    }
}
__device__ __forceinline__ void wstore64(const WStage64& ws, short* __restrict__ sW, int tid)
{
#pragma unroll
    for (int j = 0; j < 4; ++j) {
        int i = tid + j * 256;
        int r = i >> 3, h = i & 7;
        *(bf16x8*)(sW + r * SW64 + h * 8) = ws.v[j];
    }
}

__device__ __forceinline__ void zero_acc(f32x4 (&acc)[2][8]) {
#pragma unroll
    for (int i = 0; i < 2; ++i)
#pragma unroll
        for (int j = 0; j < 8; ++j) acc[i][j] = (f32x4)(0.f);
}

__device__ __forceinline__ void park(const f32x4 (&acc)[2][8], const float* __restrict__ bias,
                                     short* __restrict__ sH, int w32, int lm, int lq)
{
#pragma unroll
    for (int ct = 0; ct < 8; ++ct) {
        float bb = bias[ct * 16 + lm];
#pragma unroll
        for (int rt = 0; rt < 2; ++rt) {
            int rbase = w32 + rt * 16 + lq * 4;
#pragma unroll
            for (int reg = 0; reg < 4; ++reg) {
                float v = fmaxf(acc[rt][ct][reg] + bb, 0.f);
                sH[(rbase + reg) * SH_STRIDE + ct * 16 + lm] = (short)f2bf(v);
            }
        }
    }
}

// N-split park: 16 rows x 64 cols (this wave's half)
__device__ __forceinline__ void parkNS(const f32x4 (&acc)[4], const float* __restrict__ bias,
                                       short* __restrict__ sH, int g16, int ch, int lm, int lq)
{
#pragma unroll
    for (int i = 0; i < 4; ++i) {
        int ct = ch * 4 + i;
        float bb = bias[ct * 16 + lm];
#pragma unroll
        for (int reg = 0; reg < 4; ++reg) {
            float v = fmaxf(acc[i][reg] + bb, 0.f);
            sH[(g16 + lq * 4 + reg) * SH_STRIDE + ct * 16 + lm] = (short)f2bf(v);
        }
    }
}

__device__ __forceinline__ void park64(const f32x4 (&acc)[2][8], const float* __restrict__ bias,
                                       short* __restrict__ sH, int w32, int lm, int lq)
{
#pragma unroll
    for (int ct = 0; ct < 8; ++ct) {
        float bb = bias[ct * 16 + lm];
#pragma unroll
        for (int rt = 0; rt < 2; ++rt) {
            int rbase = w32 + rt * 16 + lq * 4;
#pragma unroll
            for (int reg = 0; reg < 4; ++reg) {
                float v = fmaxf(acc[rt][ct][reg] + bb, 0.f);
                sH[(rbase + reg) * SH64 + ct * 16 + lm] = (short)f2bf(v);
            }
        }
    }
}

// N-split 64-k fragment (node core): this lane's row, k [c*64, c*64+64).
struct FragNS {
    bf16x8 a0, a1;
    float4 f0, f1, f2, f3;
    int isF;
};
__device__ __forceinline__ void load_fragNS(FragNS& fr, int c,
    const short* __restrict__ nfb, const float* __restrict__ aggf, int r0m, int lq)
{
    fr.isF = 0;
    if (c >= 2) {
        const float* p = aggf + (size_t)r0m * 128 + (c - 2) * 64 + lq * 8;
        fr.f0 = *(const float4*)p;        fr.f1 = *(const float4*)(p + 4);
        fr.f2 = *(const float4*)(p + 32); fr.f3 = *(const float4*)(p + 36);
        fr.isF = 1;
    } else {
        const short* p = nfb + (size_t)r0m * 128 + c * 64 + lq * 8;
        fr.a0 = *(const bf16x8*)p;
        fr.a1 = *(const bf16x8*)(p + 32);
    }
}

// 64-k fragment (edge): [0]=r0 h0, [1]=r1 h0, [2]=r0 h1, [3]=r1 h1
struct Frag64 { bf16x8 a[4]; };

__device__ __forceinline__ void load_frag64(Frag64& fr, int c,
    const short* __restrict__ nfb, const short* __restrict__ efHi,
    int iS0, int iS1, int iR0, int iR1, size_t eO0, size_t eO1, int lq)
{
    int kb = (c & 1) * 64 + lq * 8;
    int seg = c >> 1;
    const short *base0, *base1;
    if (seg == 0)      { base0 = nfb + (size_t)iS0 * 128; base1 = nfb + (size_t)iS1 * 128; }
    else if (seg == 1) { base0 = nfb + (size_t)iR0 * 128; base1 = nfb + (size_t)iR1 * 128; }
    else               { base0 = efHi + eO0;              base1 = efHi + eO1; }
    fr.a[0] = *(const bf16x8*)(base0 + kb);
    fr.a[1] = *(const bf16x8*)(base1 + kb);
    fr.a[2] = *(const bf16x8*)(base0 + kb + 32);
    fr.a[3] = *(const bf16x8*)(base1 + kb + 32);
}

// ---------------------------------------------------------------------------
// Edge MLP kernel — round-6 body + ROUND 11: XCD-aware bijective block
// swizzle (8 XCDs). Default dispatch round-robins blockIdx across XCDs, so
// each XCD's 4MB L2 sees the whole 5MB nfbf. Swizzle gives each XCD a
// CONTIGUOUS receiver-sorted slot range (~640KB of nfbf receiver rows) ->
// per-XCD L2 residency for the reused gathers. Order-only change; per-block
// computation identical (m204 bijective form since 1250 % 8 != 0).
// ---------------------------------------------------------------------------
template<int RESID>
__global__ __launch_bounds__(256) void gnn_edge64(
    const short* __restrict__ Wt0,
    const short* __restrict__ Wt1, const short* __restrict__ Wt2,
    const float* __restrict__ b0, const float* __restrict__ b1, const float* __restrict__ b2,
    const float* __restrict__ g, const float* __restrict__ be,
    const short* __restrict__ nfb,
    short* __restrict__ efHi,
    const int* __restrict__ eList,
    const int* __restrict__ senders, const int* __restrict__ receivers,
    float* __restrict__ aggOut)
{
    __shared__ short sH[128 * SH64];
    __shared__ short sW[128 * SW64];
    __shared__ int sRcv[128], sSnd[128];
    const int tid = threadIdx.x;
    const int lane = tid & 63;
    const int w = tid >> 6;
    const int lm = lane & 15;
    const int lq = lane >> 4;
    const int w32 = w * 32;

    // bijective XCD swizzle: blockIdx%8 = XCD -> contiguous slot-chunk range
    const int nwg = (int)gridDim.x;
    const int q = nwg >> 3, r = nwg & 7;
    const int xcd = (int)blockIdx.x & 7, idx = (int)blockIdx.x >> 3;
    const int bid = (xcd < r) ? xcd * (q + 1) + idx
                              : r * (q + 1) + (xcd - r) * q + idx;
    const int m0 = bid * 128;

    if (tid < 128) {
        int slot = m0 + tid;                       // grid exact: slot < E
        int e = eList ? eList[slot] : slot;
        sRcv[tid] = receivers[e];
        sSnd[tid] = senders[e];
    }
    bar_lgkm();

    f32x4 acc[2][8];
    zero_acc(acc);

    const int s0 = w32 + 2 * lm, s1 = s0 + 1;
    const int iS0 = sSnd[s0], iS1 = sSnd[s1];
    const int iR0 = sRcv[s0], iR1 = sRcv[s1];
    const size_t eO0 = (size_t)(m0 + s0) * 128;
    const size_t eO1 = (size_t)(m0 + s1) * 128;

    // -------- layer 0: K=384 in 6 chunks of 64 --------
    {
        WStage64 ws, wsn;
        Frag64 cur, nxt;
        wload64(ws, Wt0, 384, 0, tid);
        load_frag64(cur, 0, nfb, efHi, iS0, iS1, iR0, iR1, eO0, eO1, lq);
#pragma unroll
        for (int c = 0; c < 6; ++c) {
            if (c + 1 < 6) {
                wload64(wsn, Wt0, 384, (c + 1) * 64, tid);
                load_frag64(nxt, c + 1, nfb, efHi, iS0, iS1, iR0, iR1, eO0, eO1, lq);
            }
            bar_lgkm();
            wstore64(ws, sW, tid);
            bar_lgkm();
            mfma_sweep64(acc, cur.a[0], cur.a[1], sW, lq * 8, lm);
            mfma_sweep64(acc, cur.a[2], cur.a[3], sW, 32 + lq * 8, lm);
            ws = wsn; cur = nxt;
        }
    }
    bar_lgkm();
    park64(acc, b0, sH, w32, lm, lq);

    // -------- layer 1: 2 chunks of 64 --------
    zero_acc(acc);
    {
        WStage64 ws, wsn;
        wload64(ws, Wt1, 128, 0, tid);
#pragma unroll
        for (int c = 0; c < 2; ++c) {
            if (c == 0) wload64(wsn, Wt1, 128, 64, tid);
            bf16x8 a0h0 = *(const bf16x8*)&sH[(w32 + lm) * SH64 + c * 64 + lq * 8];
            bf16x8 a1h0 = *(const bf16x8*)&sH[(w32 + 16 + lm) * SH64 + c * 64 + lq * 8];
            bf16x8 a0h1 = *(const bf16x8*)&sH[(w32 + lm) * SH64 + c * 64 + 32 + lq * 8];
            bf16x8 a1h1 = *(const bf16x8*)&sH[(w32 + 16 + lm) * SH64 + c * 64 + 32 + lq * 8];
            bar_lgkm();
            wstore64(ws, sW, tid);
            bar_lgkm();
            mfma_sweep64(acc, a0h0, a1h0, sW, lq * 8, lm);
            mfma_sweep64(acc, a0h1, a1h1, sW, 32 + lq * 8, lm);
            ws = wsn;
        }
    }
    bar_lgkm();
    park64(acc, b1, sH, w32, lm, lq);

    // -------- layer 2: 2 chunks of 64 --------
    zero_acc(acc);
    {
        WStage64 ws, wsn;
        wload64(ws, Wt2, 128, 0, tid);
#pragma unroll
        for (int c = 0; c < 2; ++c) {
            if (c == 0) wload64(wsn, Wt2, 128, 64, tid);
            bf16x8 a0h0 = *(const bf16x8*)&sH[(w32 + lm) * SH64 + c * 64 + lq * 8];
            bf16x8 a1h0 = *(const bf16x8*)&sH[(w32 + 16 + lm) * SH64 + c * 64 + lq * 8];
            bf16x8 a0h1 = *(const bf16x8*)&sH[(w32 + lm) * SH64 + c * 64 + 32 + lq * 8];
            bf16x8 a1h1 = *(const bf16x8*)&sH[(w32 + 16 + lm) * SH64 + c * 64 + 32 + lq * 8];
            bar_lgkm();
            wstore64(ws, sW, tid);
            bar_lgkm();
            mfma_sweep64(acc, a0h0, a1h0, sW, lq * 8, lm);
            mfma_sweep64(acc, a0h1, a1h1, sW, 32 + lq * 8, lm);
            ws = wsn;
        }
    }

    // -------- epilogue: LN + (RESID ? bf16 ef RMW) + merged-run atomics
    float g_[8], be_[8], b2_[8];
#pragma unroll
    for (int ct = 0; ct < 8; ++ct) {
        g_[ct] = g[ct * 16 + lm]; be_[ct] = be[ct * 16 + lm]; b2_[ct] = b2[ct * 16 + lm];
    }
    float run[8];
    int curRcv = -1;
#pragma unroll
    for (int j = 0; j < 8; ++j) {
        int rt = j & 1, reg = j >> 1;
        int rloc = w32 + lq * 8 + j;
        float v[8];
        float s = 0.f;
#pragma unroll
        for (int ct = 0; ct < 8; ++ct) { v[ct] = acc[rt][ct][reg] + b2_[ct]; s += v[ct]; }
        s += __shfl_xor(s, 1); s += __shfl_xor(s, 2);
        s += __shfl_xor(s, 4); s += __shfl_xor(s, 8);
        float mu = s * (1.f / 128.f);
        float q2 = 0.f;
#pragma unroll
        for (int ct = 0; ct < 8; ++ct) { v[ct] -= mu; q2 += v[ct] * v[ct]; }
        q2 += __shfl_xor(q2, 1); q2 += __shfl_xor(q2, 2);
        q2 += __shfl_xor(q2, 4); q2 += __shfl_xor(q2, 8);
        float rs = rsqrtf(q2 * (1.f / 128.f) + 1e-5f);
        int rcv = sRcv[rloc];
        float o[8];
#pragma unroll
        for (int ct = 0; ct < 8; ++ct) {
            o[ct] = v[ct] * rs * g_[ct] + be_[ct];
            if (RESID) {
                size_t gi = (size_t)(m0 + rloc) * 128 + ct * 16 + lm;
                float x = bf2f(efHi[gi]) + o[ct];
                efHi[gi] = (short)f2bf(x);
            }
        }
        if (rcv != curRcv) {
            if (curRcv >= 0) {
#pragma unroll
                for (int ct = 0; ct < 8; ++ct)
                    atomicAdd(aggOut + (size_t)curRcv * 128 + ct * 16 + lm, run[ct]);
            }
            curRcv = rcv;
#pragma unroll
            for (int ct = 0; ct < 8; ++ct) run[ct] = o[ct];
        } else {
#pragma unroll
            for (int ct = 0; ct < 8; ++ct) run[ct] += o[ct];
        }
    }
    if (curRcv >= 0) {
#pragma unroll
        for (int ct = 0; ct < 8; ++ct)
            atomicAdd(aggOut + (size_t)curRcv * 128 + ct * 16 + lm, run[ct]);
    }
}

// ---------------------------------------------------------------------------
// N-split body. nf fp32 master eliminated (round 10) — node features live
// only in nfbf (bf16), residual RMW in bf16. MODE 0: enc_n (fresh write).
// MODE 2: node step (ns = bf16(nfb[row]) + o -> nfbf write + agg zero).
// MODE 4: node s=2 fused with decoder (ns parked to LDS; writes decOut).
// LDS layout: sH 8704 B | sW 18432 B | sX 256 B | sY 256 B = 27648 B.
// ---------------------------------------------------------------------------
template<int MODE>
__device__ __forceinline__ void ns_body(char* smem, int bid,
    const short* __restrict__ Wt0, const short* __restrict__ Wt1, const short* __restrict__ Wt2,
    const float* __restrict__ b0, const float* __restrict__ b1, const float* __restrict__ b2,
    const float* __restrict__ g, const float* __restrict__ be,
    const float* __restrict__ A0f, int K0,
    const short* __restrict__ nfb, const float* __restrict__ aggf,
    short* __restrict__ outB,
    float* __restrict__ aggOut, float* __restrict__ decOut,
    const short* __restrict__ Wd0, const short* __restrict__ Wd1,
    const float* __restrict__ dW2f,
    const float* __restrict__ db0, const float* __restrict__ db1,
    const float* __restrict__ db2,
    int M)
{
    short* sH = (short*)smem;                      // 32 * SH_STRIDE
    short* sW = (short*)(smem + 8704);             // 128 * SW64
    float* sX = (float*)(smem + 8704 + 18432);     // 64
    float* sY = sX + 64;                           // 64
    const int tid = threadIdx.x;
    const int lane = tid & 63;
    const int w = tid >> 6;
    const int gidx = w >> 1;
    const int ch = w & 1;
    const int lm = lane & 15;
    const int lq = lane >> 4;
    const int g16 = gidx * 16;
    const int m0 = bid * 32;
    const int r0m = min(m0 + g16 + lm, M - 1);

    f32x4 acc[4];
#pragma unroll
    for (int i = 0; i < 4; ++i) acc[i] = (f32x4)(0.f);

    // -------- layer 0 --------
    if (MODE == 0) {
#pragma unroll
        for (int i = 0; i < 4; ++i) {
            int flat = tid + i * 256;
            int r = flat >> 5, k = flat & 31;
            int row = m0 + r;
            float v = (k < K0 && row < M) ? A0f[(size_t)row * K0 + k] : 0.f;
            sH[r * SH_STRIDE + k] = (short)f2bf(v);
        }
        {
            const short* src = Wt0 + (size_t)(tid >> 1) * 32 + (tid & 1) * 16;
            bf16x8 w0 = *(const bf16x8*)src;
            bf16x8 w1 = *(const bf16x8*)(src + 8);
            bar_lgkm();
            short* dst = sW + (tid >> 1) * SW64 + (tid & 1) * 16;
            *(bf16x8*)dst       = w0;
            *(bf16x8*)(dst + 8) = w1;
            bar_lgkm();
        }
        bf16x8 a0 = *(const bf16x8*)&sH[(g16 + lm) * SH_STRIDE + lq * 8];
        mfma_sweepNS(acc, a0, sW, ch, lq * 8, lm);
    } else {
        // node core: K=256 in 4 chunks of 64 (nfbf bf16, then agg fp32)
        WStage64 ws, wsn;
        FragNS cur, nxt;
        wload64(ws, Wt0, 256, 0, tid);
        load_fragNS(cur, 0, nfb, aggf, r0m, lq);
#pragma unroll
        for (int c = 0; c < 4; ++c) {
            if (c + 1 < 4) {
                wload64(wsn, Wt0, 256, (c + 1) * 64, tid);
                load_fragNS(nxt, c + 1, nfb, aggf, r0m, lq);
            }
            bar_lgkm();
            wstore64(ws, sW, tid);
            bar_lgkm();
            bf16x8 u0, u1;
            if (cur.isF) { u0 = pack8(cur.f0, cur.f1); u1 = pack8(cur.f2, cur.f3); }
            else         { u0 = cur.a0;                u1 = cur.a1; }
            mfma_sweepNS(acc, u0, sW, ch, lq * 8, lm);
            mfma_sweepNS(acc, u1, sW, ch, 32 + lq * 8, lm);
            ws = wsn; cur = nxt;
        }
    }
    bar_lgkm();
    parkNS(acc, b0, sH, g16, ch, lm, lq);
    bar_lgkm();

    // node MODE 2: zero this block's agg rows (all reads consumed above)
    if (MODE == 2 && aggOut) {
#pragma unroll
        for (int i = 0; i < 4; ++i) {
            int idx = tid + i * 256;
            int r = idx >> 5, c4 = idx & 31;
            int row = m0 + r;
            if (row < M)
                *(float4*)(aggOut + (size_t)row * 128 + c4 * 4) = make_float4(0.f, 0.f, 0.f, 0.f);
        }
    }

    // -------- layer 1: K=128, 2 chunks of 64 --------
#pragma unroll
    for (int i = 0; i < 4; ++i) acc[i] = (f32x4)(0.f);
    {
        WStage64 ws, wsn;
        wload64(ws, Wt1, 128, 0, tid);
#pragma unroll
        for (int c = 0; c < 2; ++c) {
            if (c == 0) wload64(wsn, Wt1, 128, 64, tid);
            bf16x8 a0 = *(const bf16x8*)&sH[(g16 + lm) * SH_STRIDE + c * 64 + lq * 8];
            bf16x8 a1 = *(const bf16x8*)&sH[(g16 + lm) * SH_STRIDE + c * 64 + 32 + lq * 8];
            bar_lgkm();
            wstore64(ws, sW, tid);
            bar_lgkm();
            mfma_sweepNS(acc, a0, sW, ch, lq * 8, lm);
            mfma_sweepNS(acc, a1, sW, ch, 32 + lq * 8, lm);
            ws = wsn;
        }
    }
    bar_lgkm();
    parkNS(acc, b1, sH, g16, ch, lm, lq);
    bar_lgkm();

    // -------- layer 2: K=128, 2 chunks of 64 --------
#pragma unroll
    for (int i = 0; i < 4; ++i) acc[i] = (f32x4)(0.f);
    {
        WStage64 ws, wsn;
        wload64(ws, Wt2, 128, 0, tid);
#pragma unroll
        for (int c = 0; c < 2; ++c) {
            if (c == 0) wload64(wsn, Wt2, 128, 64, tid);
            bf16x8 a0 = *(const bf16x8*)&sH[(g16 + lm) * SH_STRIDE + c * 64 + lq * 8];
            bf16x8 a1 = *(const bf16x8*)&sH[(g16 + lm) * SH_STRIDE + c * 64 + 32 + lq * 8];
            bar_lgkm();
            wstore64(ws, sW, tid);
            bar_lgkm();
            mfma_sweepNS(acc, a0, sW, ch, lq * 8, lm);
            mfma_sweepNS(acc, a1, sW, ch, 32 + lq * 8, lm);
            ws = wsn;
        }
    }

    // -------- epilogue: LN with cross-wave partial exchange --------
    float g_[4], be_[4], b2_[4];
#pragma unroll
    for (int i = 0; i < 4; ++i) {
        int ct = ch * 4 + i;
        g_[i] = g[ct * 16 + lm]; be_[i] = be[ct * 16 + lm]; b2_[i] = b2[ct * 16 + lm];
    }
    float v[4][4], mu[4], rs_[4];
#pragma unroll
    for (int reg = 0; reg < 4; ++reg) {
        float s = 0.f;
#pragma unroll
        for (int i = 0; i < 4; ++i) { v[i][reg] = acc[i][reg] + b2_[i]; s += v[i][reg]; }
        s += __shfl_xor(s, 1); s += __shfl_xor(s, 2);
        s += __shfl_xor(s, 4); s += __shfl_xor(s, 8);
        if (lm == 0) sX[ch * 32 + g16 + lq * 4 + reg] = s;
    }
    bar_lgkm();
#pragma unroll
    for (int reg = 0; reg < 4; ++reg)
        mu[reg] = (sX[g16 + lq * 4 + reg] + sX[32 + g16 + lq * 4 + reg]) * (1.f / 128.f);
#pragma unroll
    for (int reg = 0; reg < 4; ++reg) {
        float q = 0.f;
#pragma unroll
        for (int i = 0; i < 4; ++i) { v[i][reg] -= mu[reg]; q += v[i][reg] * v[i][reg]; }
        q += __shfl_xor(q, 1); q += __shfl_xor(q, 2);
        q += __shfl_xor(q, 4); q += __shfl_xor(q, 8);
        if (lm == 0) sY[ch * 32 + g16 + lq * 4 + reg] = q;
    }
    bar_lgkm();
#pragma unroll
    for (int reg = 0; reg < 4; ++reg)
        rs_[reg] = rsqrtf((sY[g16 + lq * 4 + reg] + sY[32 + g16 + lq * 4 + reg]) * (1.f / 128.f) + 1e-5f);

    if (MODE == 4) {
        // fused: ns = bf16(nfb[row]) + o, parked bf16 into sH (LDS only)
#pragma unroll
        for (int reg = 0; reg < 4; ++reg) {
            int row = m0 + g16 + lq * 4 + reg;
#pragma unroll
            for (int i = 0; i < 4; ++i) {
                float o = v[i][reg] * rs_[reg] * g_[i] + be_[i];
                size_t gi = (size_t)row * 128 + (size_t)(ch * 4 + i) * 16 + lm;
                float ns = bf2f(nfb[gi]) + o;
                sH[(g16 + lq * 4 + reg) * SH_STRIDE + (ch * 4 + i) * 16 + lm] = (short)f2bf(ns);
            }
        }
        bar_lgkm();    // parked ns visible to both col-half waves

        // ---- dec L0: K=128 from sH, W=Wd0, bias db0 ----
#pragma unroll
        for (int i = 0; i < 4; ++i) acc[i] = (f32x4)(0.f);
        {
            WStage64 ws, wsn;
            wload64(ws, Wd0, 128, 0, tid);
#pragma unroll
            for (int c = 0; c < 2; ++c) {
                if (c == 0) wload64(wsn, Wd0, 128, 64, tid);
                bf16x8 a0 = *(const bf16x8*)&sH[(g16 + lm) * SH_STRIDE + c * 64 + lq * 8];
                bf16x8 a1 = *(const bf16x8*)&sH[(g16 + lm) * SH_STRIDE + c * 64 + 32 + lq * 8];
                bar_lgkm();
                wstore64(ws, sW, tid);
                bar_lgkm();
                mfma_sweepNS(acc, a0, sW, ch, lq * 8, lm);
                mfma_sweepNS(acc, a1, sW, ch, 32 + lq * 8, lm);
                ws = wsn;
            }
        }
        bar_lgkm();
        parkNS(acc, db0, sH, g16, ch, lm, lq);
        bar_lgkm();

        // ---- dec L1: W=Wd1, bias db1 ----
#pragma unroll
        for (int i = 0; i < 4; ++i) acc[i] = (f32x4)(0.f);
        {
            WStage64 ws, wsn;
            wload64(ws, Wd1, 128, 0, tid);
#pragma unroll
            for (int c = 0; c < 2; ++c) {
                if (c == 0) wload64(wsn, Wd1, 128, 64, tid);
                bf16x8 a0 = *(const bf16x8*)&sH[(g16 + lm) * SH_STRIDE + c * 64 + lq * 8];
                bf16x8 a1 = *(const bf16x8*)&sH[(g16 + lm) * SH_STRIDE + c * 64 + 32 + lq * 8];
                bar_lgkm();
                wstore64(ws, sW, tid);
                bar_lgkm();
                mfma_sweepNS(acc, a0, sW, ch, lq * 8, lm);
                mfma_sweepNS(acc, a1, sW, ch, 32 + lq * 8, lm);
                ws = wsn;
            }
        }
        bar_lgkm();
        parkNS(acc, db1, sH, g16, ch, lm, lq);
        bar_lgkm();

        // ---- dec tail: 128 -> 3, fp32 weights dW2f ----
        if (tid < 96) {
            int r = tid / 3, o = tid - r * 3;
            int row = m0 + r;
            if (row < M) {
                float s = db2[o];
#pragma unroll
                for (int kk = 0; kk < 16; ++kk) {
                    bf16x8 h8 = *(const bf16x8*)&sH[r * SH_STRIDE + kk * 8];
#pragma unroll
                    for (int j = 0; j < 8; ++j)
                        s += bf2f(h8[j]) * dW2f[(kk * 8 + j) * 3 + o];
                }
                decOut[(size_t)row * 3 + o] = s;
            }
        }
        return;
    }

    // MODE 0: fresh bf16 write. MODE 2: bf16 residual RMW (own rows only —
    // the A-frag reads of nfb for this block's rows all happened in layer 0).
#pragma unroll
    for (int reg = 0; reg < 4; ++reg) {
        int row = m0 + g16 + lq * 4 + reg;
        if (row < M) {
#pragma unroll
            for (int i = 0; i < 4; ++i) {
                float o = v[i][reg] * rs_[reg] * g_[i] + be_[i];
                size_t gi = (size_t)row * 128 + (size_t)(ch * 4 + i) * 16 + lm;
                if (MODE == 2) {
                    float ns = bf2f(nfb[gi]) + o;
                    outB[gi] = (short)f2bf(ns);
                } else {
                    outB[gi] = (short)f2bf(o);
                }
            }
        }
    }
}

// ---------------------------------------------------------------------------
// Edge-encoder body (device fn): 256 threads, 4 waves x 32 rows, K0=7 staged
// to 32, bf16 ef write. LDS layout: sH 34816 B | sW 14336 B = 49152 B.
// ---------------------------------------------------------------------------
__device__ __forceinline__ void ence_body(char* smem, int bid,
    const short* __restrict__ Wt0, const short* __restrict__ Wt1, const short* __restrict__ Wt2,
    const float* __restrict__ b0, const float* __restrict__ b1, const float* __restrict__ b2,
    const float* __restrict__ g, const float* __restrict__ be,
    const float* __restrict__ A0f, int K0,
    const int* __restrict__ eList,
    short* __restrict__ outB, int M)
{
    short* sH = (short*)smem;                 // 4*32*SH_STRIDE
    short* sW = (short*)(smem + 34816);       // 128*SW_STRIDE
    const int tid = threadIdx.x;
    const int lane = tid & 63;
    const int w = tid >> 6;
    const int lm = lane & 15;
    const int lq = lane >> 4;
    const int w32 = w * 32;
    const int m0 = bid * 128;

    f32x4 acc[2][8];
    zero_acc(acc);

    // -------- layer 0: stage input (K0 -> 32) + single 32-k chunk --------
#pragma unroll
    for (int i = 0; i < 16; ++i) {
        int flat = lane + i * 64;
        int r = flat >> 5, k = flat & 31;
        int row = m0 + w32 + r;
        float v = 0.f;
        if (k < K0 && row < M) {
            int src = eList ? eList[row] : row;
            v = A0f[(size_t)src * K0 + k];
        }
        sH[(w32 + r) * SH_STRIDE + k] = (short)f2bf(v);
    }
    {
        WStageE ws;
        wloadE(ws, Wt0, 32, 0, tid);
        bf16x8 a0 = *(const bf16x8*)&sH[(w32 + lm) * SH_STRIDE + lq * 8];
        bf16x8 a1 = *(const bf16x8*)&sH[(w32 + 16 + lm) * SH_STRIDE + lq * 8];
        bar_lgkm();
        wstoreE(ws, sW, tid);
        bar_lgkm();
        mfma_sweep_lds(acc, a0, a1, sW, lm, lq);
    }
    bar_lgkm();
    park(acc, b0, sH, w32, lm, lq);

    // -------- layer 1 --------
    zero_acc(acc);
    {
        WStageE ws, wsn;
        wloadE(ws, Wt1, 128, 0, tid);
#pragma unroll
        for (int c = 0; c < 4; ++c) {
            if (c + 1 < 4) wloadE(wsn, Wt1, 128, (c + 1) * 32, tid);
            bf16x8 a0 = *(const bf16x8*)&sH[(w32 + lm) * SH_STRIDE + c * 32 + lq * 8];
            bf16x8 a1 = *(const bf16x8*)&sH[(w32 + 16 + lm) * SH_STRIDE + c * 32 + lq * 8];
            bar_lgkm();
            wstoreE(ws, sW, tid);
            bar_lgkm();
            mfma_sweep_lds(acc, a0, a1, sW, lm, lq);
            ws = wsn;
        }
    }
    bar_lgkm();
    park(acc, b1, sH, w32, lm, lq);

    // -------- layer 2 --------
    zero_acc(acc);
    {
        WStageE ws, wsn;
        wloadE(ws, Wt2, 128, 0, tid);
#pragma unroll
        for (int c = 0; c < 4; ++c) {
            if (c + 1 < 4) wloadE(wsn, Wt2, 128, (c + 1) * 32, tid);
            bf16x8 a0 = *(const bf16x8*)&sH[(w32 + lm) * SH_STRIDE + c * 32 + lq * 8];
            bf16x8 a1 = *(const bf16x8*)&sH[(w32 + 16 + lm) * SH_STRIDE + c * 32 + lq * 8];
            bar_lgkm();
            wstoreE(ws, sW, tid);
            bar_lgkm();
            mfma_sweep_lds(acc, a0, a1, sW, lm, lq);
            ws = wsn;
        }
    }

    // -------- epilogue: LN + bf16 write --------
    float g_[8], be_[8], b2_[8];
#pragma unroll
    for (int ct = 0; ct < 8; ++ct) {
        g_[ct] = g[ct * 16 + lm]; be_[ct] = be[ct * 16 + lm]; b2_[ct] = b2[ct * 16 + lm];
    }
#pragma unroll
    for (int rt = 0; rt < 2; ++rt) {
#pragma unroll
        for (int reg = 0; reg < 4; ++reg) {
            int row = m0 + w32 + rt * 16 + lq * 4 + reg;
            float vv[8];
            float s = 0.f;
#pragma unroll
            for (int ct = 0; ct < 8; ++ct) { vv[ct] = acc[rt][ct][reg] + b2_[ct]; s += vv[ct]; }
            s += __shfl_xor(s, 1); s += __shfl_xor(s, 2);
            s += __shfl_xor(s, 4); s += __shfl_xor(s, 8);
            float mu = s * (1.f / 128.f);
            float q = 0.f;
#pragma unroll
            for (int ct = 0; ct < 8; ++ct) { vv[ct] -= mu; q += vv[ct] * vv[ct]; }
            q += __shfl_xor(q, 1); q += __shfl_xor(q, 2);
            q += __shfl_xor(q, 4); q += __shfl_xor(q, 8);
            float rs = rsqrtf(q * (1.f / 128.f) + 1e-5f);
            if (row < M) {
#pragma unroll
                for (int ct = 0; ct < 8; ++ct) {
                    float o = vv[ct] * rs * g_[ct] + be_[ct];
                    outB[(size_t)row * 128 + ct * 16 + lm] = (short)f2bf(o);
                }
            }
        }
    }
}

// ---------------------------------------------------------------------------
__global__ __launch_bounds__(256) void gnn_enc_n(
    const short* __restrict__ W0, const short* __restrict__ W1, const short* __restrict__ W2,
    const float* __restrict__ b0, const float* __restrict__ b1, const float* __restrict__ b2,
    const float* __restrict__ g, const float* __restrict__ be,
    const float* __restrict__ node_x, int K0,
    short* __restrict__ nfbf, int M)
{
    __shared__ __align__(16) char smem[27648];
    ns_body<0>(smem, blockIdx.x, W0, W1, W2, b0, b1, b2, g, be,
               node_x, K0, nullptr, nullptr, nfbf, nullptr, nullptr,
               nullptr, nullptr, nullptr, nullptr, nullptr, nullptr, M);
}

__global__ __launch_bounds__(256) void gnn_enc_e(
    const short* __restrict__ W0, const short* __restrict__ W1, const short* __restrict__ W2,
    const float* __restrict__ b0, const float* __restrict__ b1, const float* __restrict__ b2,
    const float* __restrict__ g, const float* __restrict__ be,
    const float* __restrict__ edge_x, int K0,
    const int* __restrict__ eList, short* __restrict__ efB, int M)
{
    __shared__ __align__(16) char smem[49152];
    ence_body(smem, blockIdx.x, W0, W1, W2, b0, b1, b2, g, be,
              edge_x, K0, eList, efB, M);
}

__global__ __launch_bounds__(256) void gnn_nodeNS(
    const short* __restrict__ Wt0, const short* __restrict__ Wt1, const short* __restrict__ Wt2,
    const float* __restrict__ b0, const float* __restrict__ b1, const float* __restrict__ b2,
    const float* __restrict__ g, const float* __restrict__ be,
    const short* __restrict__ nfb, const float* __restrict__ aggf,
    short* __restrict__ outB, float* __restrict__ aggOut, int M)
{
    __shared__ __align__(16) char smem[27648];
    ns_body<2>(smem, blockIdx.x, Wt0, Wt1, Wt2, b0, b1, b2, g, be,
               nullptr, 0, nfb, aggf, outB, aggOut, nullptr,
               nullptr, nullptr, nullptr, nullptr, nullptr, nullptr, M);
}

__global__ __launch_bounds__(256) void gnn_node_dec(
    const short* __restrict__ Wt0, const short* __restrict__ Wt1, const short* __restrict__ Wt2,
    const float* __restrict__ b0, const float* __restrict__ b1, const float* __restrict__ b2,
    const float* __restrict__ g, const float* __restrict__ be,
    const short* __restrict__ nfb, const float* __restrict__ aggf,
    const short* __restrict__ Wd0, const short* __restrict__ Wd1,
    const float* __restrict__ dW2f,
    const float* __restrict__ db0, const float* __restrict__ db1,
    const float* __restrict__ db2,
    float* __restrict__ decOut, int M)
{
    __shared__ __align__(16) char smem[27648];
    ns_body<4>(smem, blockIdx.x, Wt0, Wt1, Wt2, b0, b1, b2, g, be,
               nullptr, 0, nfb, aggf, nullptr, nullptr, decOut,
               Wd0, Wd1, dW2f, db0, db1, db2, M);
}

// ---------------------------------------------------------------------------
__global__ void zero_i(int* __restrict__ p, int n)
{
    int i = blockIdx.x * 256 + threadIdx.x;
    if (i < n) p[i] = 0;
}
__global__ void csr_count(const int* __restrict__ recv, int* __restrict__ cnt, int E)
{
    int i = blockIdx.x * 256 + threadIdx.x;
    if (i < E) atomicAdd(&cnt[recv[i]], 1);
}
__global__ __launch_bounds__(256) void csr_scan(const int* __restrict__ cnt,
                                                int* __restrict__ cursor, int N)
{
    __shared__ int ssum[257];
    const int tid = threadIdx.x;
    const int per = (N + 255) / 256;
    const int lo = tid * per, hi = min(lo + per, N);
    int s = 0;
    for (int i = lo; i < hi; ++i) s += cnt[i];
    ssum[tid] = s;
    __syncthreads();
    if (tid == 0) {
        int run = 0;
        for (int i = 0; i < 256; ++i) { int t = ssum[i]; ssum[i] = run; run += t; }
        ssum[256] = run;
    }
    __syncthreads();
    int run = ssum[tid];
    for (int i = lo; i < hi; ++i) { int c = cnt[i]; cursor[i] = run; run += c; }
}
__global__ void csr_fill(const int* __restrict__ recv, int* __restrict__ cursor,
                         int* __restrict__ eList, int E)
{
    int i = blockIdx.x * 256 + threadIdx.x;
    if (i < E) {
        int pos = atomicAdd(&cursor[recv[i]], 1);
        eList[pos] = i;
    }
}

// ---------------------------------------------------------------------------
struct WtPrep { const float* src; int K; int Kpad; int dstOff; };
struct WtPrepAll { WtPrep m[26]; };

__global__ void wt_prep_kernel(WtPrepAll all, short* __restrict__ dst)
{
    const WtPrep p = all.m[blockIdx.y];
    int total = 128 * p.Kpad;
    int idx = blockIdx.x * 256 + threadIdx.x;
    if (idx >= total) return;
    int n = idx / p.Kpad, k = idx - n * p.Kpad;
    float v = (k < p.K) ? p.src[(size_t)k * 128 + n] : 0.f;
    dst[p.dstOff + idx] = (short)f2bf(v);
}

__global__ void zero_kernel(float4* __restrict__ p, long n4)
{
    long i = (long)blockIdx.x * blockDim.x + threadIdx.x;
    if (i < n4) p[i] = make_float4(0.f, 0.f, 0.f, 0.f);
}

// ---------------------------------------------------------------------------
extern "C" void kernel_launch(void* const* d_in, const int* in_sizes, int n_in,
                              void* d_out, int out_size, void* d_ws, size_t ws_size,
                              hipStream_t stream)
{
    const float* node_x   = (const float*)d_in[0];
    const float* edge_x   = (const float*)d_in[1];
    const float* enc_n_W0 = (const float*)d_in[2];
    const float* enc_n_b0 = (const float*)d_in[3];
    const float* enc_n_W1 = (const float*)d_in[4];
    const float* enc_n_b1 = (const float*)d_in[5];
    const float* enc_n_W2 = (const float*)d_in[6];
    const float* enc_n_b2 = (const float*)d_in[7];
    const float* enc_n_g  = (const float*)d_in[8];
    const float* enc_n_be = (const float*)d_in[9];
    const float* enc_e_W0 = (const float*)d_in[10];
    const float* enc_e_b0 = (const float*)d_in[11];
    const float* enc_e_W1 = (const float*)d_in[12];
    const float* enc_e_b1 = (const float*)d_in[13];
    const float* enc_e_W2 = (const float*)d_in[14];
    const float* enc_e_b2 = (const float*)d_in[15];
    const float* enc_e_g  = (const float*)d_in[16];
    const float* enc_e_be = (const float*)d_in[17];
    const float* gnb_e_W0 = (const float*)d_in[18];
    const float* gnb_e_b0 = (const float*)d_in[19];
    const float* gnb_e_W1 = (const float*)d_in[20];
    const float* gnb_e_b1 = (const float*)d_in[21];
    const float* gnb_e_W2 = (const float*)d_in[22];
    const float* gnb_e_b2 = (const float*)d_in[23];
    const float* gnb_e_g  = (const float*)d_in[24];
    const float* gnb_e_be = (const float*)d_in[25];
    const float* gnb_n_W0 = (const float*)d_in[26];
    const float* gnb_n_b0 = (const float*)d_in[27];
    const float* gnb_n_W1 = (const float*)d_in[28];
    const float* gnb_n_b1 = (const float*)d_in[29];
    const float* gnb_n_W2 = (const float*)d_in[30];
    const float* gnb_n_b2 = (const float*)d_in[31];
    const float* gnb_n_g  = (const float*)d_in[32];
    const float* gnb_n_be = (const float*)d_in[33];
    const float* dec_W0   = (const float*)d_in[34];
    const float* dec_b0   = (const float*)d_in[35];
    const float* dec_W1   = (const float*)d_in[36];
    const float* dec_b1   = (const float*)d_in[37];
    const float* dec_W2   = (const float*)d_in[38];
    const float* dec_b2   = (const float*)d_in[39];
    const int*   senders  = (const int*)d_in[40];
    const int*   receivers= (const int*)d_in[41];
    float* out = (float*)d_out;

    const int N = NN, E = EE;
    const int WT_TOTAL = (32 + 128 + 128 + 32 + 128 + 128 + 3 * (384 + 128 + 128 + 256 + 128 + 128)
                          + 128 + 128) * 128;

    // ---- workspace layout: nf fp32 removed (node master is bf16 nfbf) ----
    float* agg  = (float*)d_ws;                      // N*128 f32
    short* efHi = (short*)(agg + (size_t)N * 128);   // E*128 bf16 (slot order)
    short* nfbf = efHi + (size_t)E * 128;            // N*128 bf16
    short* wt   = nfbf + (size_t)N * 128;            // WT_TOTAL bf16
    int*   eList = (int*)(wt + WT_TOTAL);            // E ints
    size_t need_sorted = (size_t)((char*)(eList + E) - (char*)d_ws);
    int* cnt    = (int*)agg;                          // transient overlay on agg
    int* cursor = cnt + N;

    const bool useSorted = (ws_size >= need_sorted);
    const int* eL = useSorted ? eList : nullptr;

    WtPrepAll tbl;
    int nMat = 0, off = 0;
    int o_encn[3], o_ence[3], o_ge0[3], o_ge1[3], o_ge2[3], o_gn0[3], o_gn1[3], o_gn2[3], o_dec[2];
    auto add = [&](const float* src, int K, int Kpad) {
        tbl.m[nMat].src = src; tbl.m[nMat].K = K; tbl.m[nMat].Kpad = Kpad;
        tbl.m[nMat].dstOff = off;
        int r = off; off += 128 * Kpad; ++nMat; return r;
    };
    o_encn[0] = add(enc_n_W0, 12, 32);
    o_encn[1] = add(enc_n_W1, 128, 128);
    o_encn[2] = add(enc_n_W2, 128, 128);
    o_ence[0] = add(enc_e_W0, 7, 32);
    o_ence[1] = add(enc_e_W1, 128, 128);
    o_ence[2] = add(enc_e_W2, 128, 128);
    for (int s = 0; s < 3; ++s) {
        o_ge0[s] = add(gnb_e_W0 + (size_t)s * 384 * 128, 384, 384);
        o_ge1[s] = add(gnb_e_W1 + (size_t)s * 128 * 128, 128, 128);
        o_ge2[s] = add(gnb_e_W2 + (size_t)s * 128 * 128, 128, 128);
        o_gn0[s] = add(gnb_n_W0 + (size_t)s * 256 * 128, 256, 256);
        o_gn1[s] = add(gnb_n_W1 + (size_t)s * 128 * 128, 128, 128);
        o_gn2[s] = add(gnb_n_W2 + (size_t)s * 128 * 128, 128, 128);
    }
    o_dec[0] = add(dec_W0, 128, 128);
    o_dec[1] = add(dec_W1, 128, 128);

    wt_prep_kernel<<<dim3(192, 26), 256, 0, stream>>>(tbl, wt);

    if (useSorted) {
        zero_i<<<dim3((N + 255) / 256), 256, 0, stream>>>(cnt, N);
        csr_count<<<dim3((E + 255) / 256), 256, 0, stream>>>(receivers, cnt, E);
        csr_scan<<<dim3(1), 256, 0, stream>>>(cnt, cursor, N);
        csr_fill<<<dim3((E + 255) / 256), 256, 0, stream>>>(receivers, cursor, eList, E);
    }
    // zero agg once (after csr: cnt/cursor overlay agg); steps re-zero in node kernel
    zero_kernel<<<dim3((N * 32 + 255) / 256), 256, 0, stream>>>((float4*)agg, (long)N * 32);

    const dim3 gE(E / 128);                 // edge kernels: 1250 blocks x 256 thr
    const dim3 gNS(N / 32);                 // node kernels: 625 blocks x 256 thr

    // ---- encoders (separate dispatches) ----
    gnn_enc_n<<<gNS, 256, 0, stream>>>(
        wt + o_encn[0], wt + o_encn[1], wt + o_encn[2],
        enc_n_b0, enc_n_b1, enc_n_b2, enc_n_g, enc_n_be,
        node_x, 12, nfbf, N);
    gnn_enc_e<<<gE, 256, 0, stream>>>(
        wt + o_ence[0], wt + o_ence[1], wt + o_ence[2],
        enc_e_b0, enc_e_b1, enc_e_b2, enc_e_g, enc_e_be,
        edge_x, 7, eL, efHi, E);

    // ---- 3 message-passing steps; node s=2 fused with decoder ----
    for (int s = 0; s < 3; ++s) {
        const float* eb0 = gnb_e_b0 + (size_t)s * 128;
        const float* eb1 = gnb_e_b1 + (size_t)s * 128;
        const float* eb2 = gnb_e_b2 + (size_t)s * 128;
        const float* eg  = gnb_e_g  + (size_t)s * 128;
        const float* ebe = gnb_e_be + (size_t)s * 128;
        const float* nb0 = gnb_n_b0 + (size_t)s * 128;
        const float* nb1 = gnb_n_b1 + (size_t)s * 128;
        const float* nb2 = gnb_n_b2 + (size_t)s * 128;
        const float* ng  = gnb_n_g  + (size_t)s * 128;
        const float* nbe = gnb_n_be + (size_t)s * 128;

        if (s < 2) {
            gnn_edge64<1><<<gE, 256, 0, stream>>>(wt + o_ge0[s], wt + o_ge1[s], wt + o_ge2[s],
                eb0, eb1, eb2, eg, ebe,
                nfbf, efHi, eL, senders, receivers, agg);
            gnn_nodeNS<<<gNS, 256, 0, stream>>>(wt + o_gn0[s], wt + o_gn1[s], wt + o_gn2[s],
                nb0, nb1, nb2, ng, nbe,
                nfbf, agg, nfbf, agg, N);
        } else {
            gnn_edge64<0><<<gE, 256, 0, stream>>>(wt + o_ge0[s], wt + o_ge1[s], wt + o_ge2[s],
                eb0, eb1, eb2, eg, ebe,
                nfbf, efHi, eL, senders, receivers, agg);
            gnn_node_dec<<<gNS, 256, 0, stream>>>(wt + o_gn0[s], wt + o_gn1[s], wt + o_gn2[s],
                nb0, nb1, nb2, ng, nbe,
                nfbf, agg,
                wt + o_dec[0], wt + o_dec[1], dec_W2,
                dec_b0, dec_b1, dec_b2,
                out, N);
        }
    }
}